// Round 5
// baseline (552.898 us; speedup 1.0000x reference)
//
#include <hip/hip_runtime.h>
#include <math.h>

// PNANet on MI355X, round 5:
//  * b2: LDS <=40KB -> 4 blocks/CU (occupancy was the round-4 limiter).
//    agg-only rows [32][261]; interleaved K-chunks (G = h + 8*gi) -> branch-free
//    pure-a1 / pure-agg sub-loops; 4 nodes x 8 cols per thread; shfl h-fold.
//  * BN stats: per-block partials + fin1 kernel (no atomics, no memset).
//  * knn: unroll 4 (latency hiding at 1 wave/SIMD).

#define NGRAPH 128
#define NPG    512
#define NN     (NGRAPH*NPG)   // 65536
#define KNB    7

constexpr double AVG_DEG_LOG_D = 2.0239670479173344;  // (100*ln6+200*ln7+700*ln8)/1000
constexpr double LOG8_D        = 2.0794415416798357;

#define FMA4(A_, P_, W_) { (A_).x += (P_)*(W_).x; (A_).y += (P_)*(W_).y; (A_).z += (P_)*(W_).z; (A_).w += (P_)*(W_).w; }

// ---------------------------------------------------------------- weight prep
__global__ __launch_bounds__(256) void prep_kernel(
    const float* __restrict__ Wpost1, const float* __restrict__ Wpost2,
    const float* __restrict__ Wpre2,
    float* __restrict__ Weff1, float* __restrict__ Weff2,
    float* __restrict__ W2u, float* __restrict__ W2v)
{
    const float AMP = (float)(LOG8_D / AVG_DEG_LOG_D);
    const float ATT = (float)(AVG_DEG_LOG_D / LOG8_D);
    for (int i = blockIdx.x*256 + threadIdx.x; i < 76288; i += gridDim.x*256) {
        if (i < 2560) {
            // Weff1 [4][40][16]; g<8 = x part, g>=8 = agg part (mean,min,max,std x8)
            int t = i / 640, r = i % 640, g = r >> 4, fo = r & 15;
            float val;
            if (g < 8) val = Wpost1[(t*104 + g)*16 + fo];
            else {
                int g2 = g - 8;
                val = Wpost1[(t*104 +  8 + g2)*16 + fo]
                    + AMP*Wpost1[(t*104 + 40 + g2)*16 + fo]
                    + ATT*Wpost1[(t*104 + 72 + g2)*16 + fo];
            }
            Weff1[i] = val;
        } else if (i < 43520) {
            // Weff2 [4][320][32]; g<64 = x part, g>=64 = agg (mean,min,max,std x64)
            int j = i - 2560;
            int t = j / 10240, r = j % 10240, g = r >> 5, fo = r & 31;
            float val;
            if (g < 64) val = Wpost2[(t*832 + g)*32 + fo];
            else {
                int g2 = g - 64;
                val = Wpost2[(t*832 +  64 + g2)*32 + fo]
                    + AMP*Wpost2[(t*832 + 320 + g2)*32 + fo]
                    + ATT*Wpost2[(t*832 + 576 + g2)*32 + fo];
            }
            Weff2[j] = val;
        } else {
            // W2u/W2v: [k=64][tf=256]; u rows = W_pre2[t][k], v rows = W_pre2[t][64+k]
            int j = i - 43520;
            int half = j >> 14, j2 = j & 16383;
            int k = j2 >> 8, tf = j2 & 255, t = tf >> 6, f = tf & 63;
            if (half == 0) W2u[j2] = Wpre2[(t*128 +      k)*64 + f];
            else           W2v[j2] = Wpre2[(t*128 + 64 + k)*64 + f];
        }
    }
}

// ---------------------------------------------------------------- kNN (k=7); 2 blocks per graph
__global__ __launch_bounds__(256) void knn_kernel(const float* __restrict__ pos, int* __restrict__ nbr)
{
    __shared__ float4 posS[NPG];
    const int g    = blockIdx.x >> 1;
    const int half = blockIdx.x & 1;
    const int gb   = g * NPG;
    for (int j = threadIdx.x; j < NPG; j += 256)
        posS[j] = make_float4(pos[(gb+j)*3+0], pos[(gb+j)*3+1], pos[(gb+j)*3+2], 0.f);
    __syncthreads();
    const int i = half*256 + threadIdx.x;
    const float4 pi = posS[i];
    float bd[KNB]; int bi[KNB];
#pragma unroll
    for (int e = 0; e < KNB; ++e) { bd[e] = 3.0e38f; bi[e] = -1; }
#pragma unroll 4
    for (int j = 0; j < NPG; ++j) {
        float4 pj = posS[j];
        float dx = pi.x - pj.x, dy = pi.y - pj.y, dz = pi.z - pj.z;
        float d2 = __fadd_rn(__fadd_rn(__fmul_rn(dx,dx), __fmul_rn(dy,dy)), __fmul_rn(dz,dz));
        if (j == i) d2 = __builtin_inff();
        bool cmp[KNB];
#pragma unroll
        for (int e = 0; e < KNB; ++e) cmp[e] = d2 < bd[e];
#pragma unroll
        for (int e = KNB-1; e >= 1; --e) {
            bd[e] = cmp[e-1] ? bd[e-1] : (cmp[e] ? d2 : bd[e]);
            bi[e] = cmp[e-1] ? bi[e-1] : (cmp[e] ? j  : bi[e]);
        }
        bd[0] = cmp[0] ? d2 : bd[0];
        bi[0] = cmp[0] ? j  : bi[0];
    }
#pragma unroll
    for (int e = 0; e < KNB; ++e) nbr[(gb+i)*KNB + e] = gb + bi[e];
}

// ---------------------------------------------------------------- layer1: u1,v1 [N,32]
__global__ __launch_bounds__(256) void a1_kernel(
    const float* __restrict__ x, const float* __restrict__ Wpre1, const float* __restrict__ bpre1,
    float* __restrict__ u1, float* __restrict__ v1)
{
    __shared__ float wS[512];
    __shared__ float bS[32];
    const int tid = threadIdx.x;
    wS[tid] = Wpre1[tid]; wS[tid+256] = Wpre1[tid+256];
    if (tid < 32) bS[tid] = bpre1[tid];
    __syncthreads();
    const int n  = blockIdx.x*8 + (tid>>5);
    const int tf = tid & 31;
    const int t = tf >> 3, f = tf & 7;
    float u = bS[tf], v = 0.f;
#pragma unroll
    for (int e = 0; e < 8; ++e) {
        float xv = x[n*8+e];
        u += xv * wS[(t*16 + e)*8 + f];
        v += xv * wS[(t*16 + 8 + e)*8 + f];
    }
    u1[n*32+tf] = u;
    v1[n*32+tf] = v;
}

// ---------------------------------------------------------------- layer1 fused: agg + post + lin -> y1 [N,64]
__global__ __launch_bounds__(256) void b1_kernel(
    const float* __restrict__ x, const int* __restrict__ nbr,
    const float* __restrict__ u1, const float* __restrict__ v1,
    const float* __restrict__ Weff1, const float* __restrict__ bpost1,
    const float* __restrict__ Wlin1, const float* __restrict__ blin1,
    float* __restrict__ y1)
{
    __shared__ int   nbrsS[16*7];
    __shared__ float xsS[16*8];
    __shared__ float aggS[64*41];
    __shared__ float postS[16*68];
    const int tid  = threadIdx.x;
    const int base = blockIdx.x * 16;
    if (tid < 112) nbrsS[tid] = nbr[base*7 + tid];
    if (tid < 128) xsS[tid]   = x[base*8 + tid];
    __syncthreads();
#pragma unroll
    for (int it = 0; it < 2; ++it) {
        int task = tid + 256*it;
        int ln = task >> 5, tf = task & 31;
        float u = u1[(base+ln)*32 + tf];
        float s = 0.f, s2 = 0.f, mn = 3e38f, mx = -3e38f;
#pragma unroll
        for (int e = 0; e < 7; ++e) {
            float vv = v1[nbrsS[ln*7+e]*32 + tf];
            s += vv; s2 += vv*vv; mn = fminf(mn, vv); mx = fmaxf(mx, vv);
        }
        float mean = s * (1.f/7.f);
        float var  = s2 * (1.f/7.f) - mean*mean;
        float sd   = sqrtf(fmaxf(var, 0.f) + 1e-5f);
        int t = tf >> 3, f = tf & 7;
        int bo = (ln*4 + t)*41 + f;
        aggS[bo]    = u + mean;
        aggS[bo+8]  = u + mn;
        aggS[bo+16] = u + mx;
        aggS[bo+24] = sd;
    }
    __syncthreads();
    {   // post-MLP: 16 nodes x 64 outputs
        int ln = tid >> 4, q = tid & 15;
        int t = q >> 2, fo4 = (q & 3) * 4;
        float4 acc = *(const float4*)&bpost1[t*16 + fo4];
#pragma unroll
        for (int g = 0; g < 8; ++g) {
            float p = xsS[ln*8+g];
            float4 wv4 = *(const float4*)&Weff1[(t*40 + g)*16 + fo4];
            FMA4(acc, p, wv4)
        }
#pragma unroll 8
        for (int g = 0; g < 32; ++g) {
            float p = aggS[(ln*4 + t)*41 + g];
            float4 wv4 = *(const float4*)&Weff1[(t*40 + 8 + g)*16 + fo4];
            FMA4(acc, p, wv4)
        }
        *(float4*)&postS[ln*68 + t*16 + fo4] = acc;
    }
    __syncthreads();
    {   // mixing linear
        int ln = tid >> 4, q = tid & 15;
        int c4 = q*4;
        float4 acc = *(const float4*)&blin1[c4];
#pragma unroll 8
        for (int o = 0; o < 64; ++o) {
            float p = postS[ln*68 + o];
            float4 wv4 = *(const float4*)&Wlin1[o*64 + c4];
            FMA4(acc, p, wv4)
        }
        *(float4*)&y1[(base+ln)*64 + c4] = acc;
    }
}

// ---------------------------------------------------------------- BN stats partials (no atomics)
template<int C, int LOGC>
__global__ __launch_bounds__(256) void bn_stats_kernel(
    const float* __restrict__ y, float* __restrict__ Ps, float* __restrict__ Pq)
{
    __shared__ float sS[256], qS[256];
    const int tid = threadIdx.x;
    const int c  = tid & (C-1);
    const int rg = tid >> LOGC;
    const int G  = 256 >> LOGC;
    const int ROWS = NN/128;
    const int rowBase = blockIdx.x * ROWS;
    float s = 0.f, q = 0.f;
    for (int r = rg; r < ROWS; r += G) {
        float v = y[(rowBase + r)*C + c];
        s += v; q += v*v;
    }
    sS[tid] = s; qS[tid] = q;
    __syncthreads();
    if (rg == 0) {
        for (int g2 = 1; g2 < G; ++g2) { s += sS[g2*C + c]; q += qS[g2*C + c]; }
        Ps[blockIdx.x*C + c] = s;
        Pq[blockIdx.x*C + c] = q;
    }
}

// ---------------------------------------------------------------- finalize BN1 -> scale/shift
__global__ __launch_bounds__(64) void fin1_kernel(
    const float* __restrict__ P1s, const float* __restrict__ P1q,
    const float* __restrict__ g, const float* __restrict__ b,
    float* __restrict__ sc1, float* __restrict__ sh1)
{
    const int c = threadIdx.x;   // 64
    float s = 0.f, q = 0.f;
    for (int i = 0; i < 128; ++i) { s += P1s[i*64 + c]; q += P1q[i*64 + c]; }
    const float inv = 1.f/(float)NN;
    float mu  = s*inv;
    float var = q*inv - mu*mu;
    float sc  = g[c]*rsqrtf(var + 1e-5f);
    sc1[c] = sc;
    sh1[c] = b[c] - mu*sc;
}

// ---------------------------------------------------------------- layer2 pre: u2,v2 [N,256]; BN1+relu fused
__global__ __launch_bounds__(256) void a2_kernel(
    const float* __restrict__ y1raw, const float* __restrict__ sc1, const float* __restrict__ sh1,
    const float* __restrict__ W2u, const float* __restrict__ W2v,
    const float* __restrict__ bpre2,
    float* __restrict__ u2, float* __restrict__ v2)
{
    __shared__ float4 As4[512];     // 32 nodes x 16 float4
    const int tid = threadIdx.x;
    for (int i = tid; i < 512; i += 256) {
        float4 vv = ((const float4*)y1raw)[blockIdx.x*512 + i];
        int c0 = (i & 15) * 4;
        float comp[4] = {vv.x, vv.y, vv.z, vv.w};
#pragma unroll
        for (int j = 0; j < 4; ++j) {
            int c = c0 + j;
            comp[j] = fmaxf(comp[j]*sc1[c] + sh1[c], 0.f);
        }
        As4[i] = make_float4(comp[0], comp[1], comp[2], comp[3]);
    }
    __syncthreads();
    const int q = tid & 63, r = tid >> 6;
    const int nodeBase = blockIdx.x*32 + r*8;
    float4 accu[8], accv[8];
    const float4 bias = ((const float4*)bpre2)[q];
#pragma unroll
    for (int i = 0; i < 8; ++i) { accu[i] = bias; accv[i] = make_float4(0.f,0.f,0.f,0.f); }
    const float4* W2u4 = (const float4*)W2u;
    const float4* W2v4 = (const float4*)W2v;
#pragma unroll 2
    for (int kk = 0; kk < 16; ++kk) {
        float4 a4[8];
#pragma unroll
        for (int i = 0; i < 8; ++i) a4[i] = As4[(r*8+i)*16 + kk];
#pragma unroll
        for (int ks = 0; ks < 4; ++ks) {
            const int k = kk*4 + ks;
            const float4 wu4 = W2u4[k*64 + q];
            const float4 wv4 = W2v4[k*64 + q];
#pragma unroll
            for (int i = 0; i < 8; ++i) {
                const float av = (ks==0) ? a4[i].x : (ks==1) ? a4[i].y : (ks==2) ? a4[i].z : a4[i].w;
                FMA4(accu[i], av, wu4)
                FMA4(accv[i], av, wv4)
            }
        }
    }
#pragma unroll
    for (int i = 0; i < 8; ++i) {
        ((float4*)u2)[(nodeBase+i)*64 + q] = accu[i];
        ((float4*)v2)[(nodeBase+i)*64 + q] = accv[i];
    }
}

// ---------------------------------------------------------------- b2 reduce over K-chunks h: shfl fold + 2-level LDS tree
__device__ __forceinline__ void hreduce(float4 (&acc)[8], float4* redS, int h, int qq)
{
#pragma unroll
    for (int j = 0; j < 8; ++j) {   // fold h parity within the wave
        acc[j].x += __shfl_xor(acc[j].x, 32);
        acc[j].y += __shfl_xor(acc[j].y, 32);
        acc[j].z += __shfl_xor(acc[j].z, 32);
        acc[j].w += __shfl_xor(acc[j].w, 32);
    }
    const int w = h >> 1;           // wave id 0..3
#pragma unroll
    for (int step = 2; step >= 1; step >>= 1) {
        if (w >= step && w < 2*step) {
            const int slot = (w-step)*32 + qq;
#pragma unroll
            for (int j = 0; j < 8; ++j) redS[slot*9 + j] = acc[j];
        }
        __syncthreads();
        if (w < step) {
            const int slot = w*32 + qq;
#pragma unroll
            for (int j = 0; j < 8; ++j) {
                float4 r = redS[slot*9 + j];
                acc[j].x += r.x; acc[j].y += r.y; acc[j].z += r.z; acc[j].w += r.w;
            }
        }
        __syncthreads();
    }
}

// ---------------------------------------------------------------- layer2 fused: agg + post + lin -> y2 [N,128]
// thread = (n2: node half, q: 8-col group, h: K-chunk). Interleaved K (G = h+8*gi):
// sub-loop A (8 iters, a1 part) / sub-loop B (32 iters, agg part) — branch-free.
__global__ __launch_bounds__(256) void b2_kernel(
    const int* __restrict__ nbr, const float* __restrict__ y1raw,
    const float* __restrict__ sc1, const float* __restrict__ sh1,
    const float* __restrict__ u2, const float* __restrict__ v2,
    const float* __restrict__ Weff2, const float* __restrict__ bpost2,
    const float* __restrict__ Wlin2, const float* __restrict__ blin2,
    float* __restrict__ y2)
{
    __shared__ int   nbrsS[56];
    __shared__ float a1S[512];                       // 8 nodes x 64 post-BN acts
    __shared__ __align__(16) float actS[32*261];     // agg rows (node*4+t), pitch 261
    __shared__ float postS[8*132];
    float4* redS = (float4*)actS;                    // alias (used when actS dead / between phases)

    const int tid  = threadIdx.x;
    const int base = blockIdx.x * 8;
    if (tid < 56) nbrsS[tid] = nbr[base*7 + tid];
    for (int i = tid; i < 512; i += 256) {
        int c = i & 63;
        a1S[i] = fmaxf(y1raw[base*64 + i]*sc1[c] + sh1[c], 0.f);
    }
    __syncthreads();
    // ---- aggregation: 7-neighbor mean/min/max/std over 256 feats per node
    {
        const int t = tid >> 6, f = tid & 63;
        for (int ln = 0; ln < 8; ++ln) {
            float u = u2[(base+ln)*256 + tid];
            float s = 0.f, s2 = 0.f, mn = 3e38f, mx = -3e38f;
#pragma unroll
            for (int e = 0; e < 7; ++e) {
                float vv = v2[nbrsS[ln*7+e]*256 + tid];
                s += vv; s2 += vv*vv; mn = fminf(mn, vv); mx = fmaxf(mx, vv);
            }
            float mean = s * (1.f/7.f);
            float var  = s2 * (1.f/7.f) - mean*mean;
            float sd   = sqrtf(fmaxf(var, 0.f) + 1e-5f);
            const int ro = (ln*4 + t)*261;
            actS[ro +       f] = u + mean;
            actS[ro +  64 + f] = u + mn;
            actS[ro + 128 + f] = u + mx;
            actS[ro + 192 + f] = sd;
        }
    }
    __syncthreads();
    const int n2 = tid & 1, q = (tid >> 1) & 15, h = tid >> 5;
    const int qq = tid & 31;
    const int t  = q >> 2;
    const int c8 = q * 8;                 // output col (post & lin), = t*32 + (q&3)*8
    // ---- post-MLP: per tower K=320 = 64 (a1, shared) + 256 (agg)
    float4 acc[8];
#pragma unroll
    for (int j = 0; j < 8; ++j) acc[j] = make_float4(0.f,0.f,0.f,0.f);
    {   // sub-loop A: G = h + 8*gi  (0..63), acts from a1S (tower-independent)
        const float* wp = Weff2 + (t*320 + h)*32 + (q&3)*8;
        const float* ap = a1S + n2*256 + h;
#pragma unroll
        for (int gi = 0; gi < 8; ++gi) {
            const float4 w0 = *(const float4*)(wp);
            const float4 w1 = *(const float4*)(wp+4);
            wp += 256;
#pragma unroll
            for (int i = 0; i < 4; ++i) {
                float p = ap[i*64 + gi*8];
                FMA4(acc[i*2],   p, w0)
                FMA4(acc[i*2+1], p, w1)
            }
        }
    }
    {   // sub-loop B: G = 64 + h + 8*gi (64..319), acts from actS rows
        const float* wp = Weff2 + (t*320 + 64 + h)*32 + (q&3)*8;
        const float* ap = actS + (n2*16 + t)*261 + h;
#pragma unroll 8
        for (int gi = 0; gi < 32; ++gi) {
            const float4 w0 = *(const float4*)(wp);
            const float4 w1 = *(const float4*)(wp+4);
            wp += 256;
#pragma unroll
            for (int i = 0; i < 4; ++i) {
                float p = ap[i*1044 + gi*8];
                FMA4(acc[i*2],   p, w0)
                FMA4(acc[i*2+1], p, w1)
            }
        }
    }
    __syncthreads();                 // actS reads done; redS alias safe
    hreduce(acc, redS, h, qq);
    if (h == 0) {
        const float4 b0 = *(const float4*)&bpost2[c8];
        const float4 b1 = *(const float4*)&bpost2[c8+4];
#pragma unroll
        for (int i = 0; i < 4; ++i) {
            const int ln = n2*4 + i;
            float4 a0 = acc[i*2], a1v = acc[i*2+1];
            a0.x += b0.x; a0.y += b0.y; a0.z += b0.z; a0.w += b0.w;
            a1v.x += b1.x; a1v.y += b1.y; a1v.z += b1.z; a1v.w += b1.w;
            *(float4*)&postS[ln*132 + c8]     = a0;
            *(float4*)&postS[ln*132 + c8 + 4] = a1v;
        }
    }
    __syncthreads();
    // ---- mixing linear: K=128 interleaved (o = h + 8*oi)
    float4 acc2[8];
#pragma unroll
    for (int j = 0; j < 8; ++j) acc2[j] = make_float4(0.f,0.f,0.f,0.f);
    {
        const float* wp = Wlin2 + h*128 + c8;
        const float* pp = postS + n2*4*132 + h;
#pragma unroll 8
        for (int oi = 0; oi < 16; ++oi) {
            const float4 w0 = *(const float4*)(wp);
            const float4 w1 = *(const float4*)(wp+4);
            wp += 1024;
#pragma unroll
            for (int i = 0; i < 4; ++i) {
                float p = pp[i*132 + oi*8];
                FMA4(acc2[i*2],   p, w0)
                FMA4(acc2[i*2+1], p, w1)
            }
        }
    }
    hreduce(acc2, redS, h, qq);
    if (h == 0) {
        const float4 b0 = *(const float4*)&blin2[c8];
        const float4 b1 = *(const float4*)&blin2[c8+4];
#pragma unroll
        for (int i = 0; i < 4; ++i) {
            const int ln = n2*4 + i;
            float4 a0 = acc2[i*2], a1v = acc2[i*2+1];
            a0.x += b0.x; a0.y += b0.y; a0.z += b0.z; a0.w += b0.w;
            a1v.x += b1.x; a1v.y += b1.y; a1v.z += b1.z; a1v.w += b1.w;
            *(float4*)&y2[(base+ln)*128 + c8]     = a0;
            *(float4*)&y2[(base+ln)*128 + c8 + 4] = a1v;
        }
    }
}

// ---------------------------------------------------------------- BN2 + relu + per-graph mean pool -> out [128,128]
__global__ __launch_bounds__(128) void pool_kernel(
    const float* __restrict__ y2, const float* __restrict__ P2s, const float* __restrict__ P2q,
    const float* __restrict__ gamma, const float* __restrict__ beta, float* __restrict__ out)
{
    const int c = threadIdx.x;
    const int g = blockIdx.x;
    float s = 0.f, q = 0.f;
    for (int i = 0; i < 128; ++i) { s += P2s[i*128 + c]; q += P2q[i*128 + c]; }
    const float inv = 1.f/(float)NN;
    const float mu  = s*inv;
    const float var = q*inv - mu*mu;
    const float sc  = gamma[c]*rsqrtf(var + 1e-5f);
    const float sh  = beta[c] - mu*sc;
    float acc = 0.f;
    const int baseIdx = g*NPG*128 + c;
#pragma unroll 4
    for (int i = 0; i < NPG; ++i) {
        float v = y2[baseIdx + i*128];
        acc += fmaxf(v*sc + sh, 0.f);
    }
    out[g*128 + c] = acc * (1.f/(float)NPG);
}

// ---------------------------------------------------------------- launcher
extern "C" void kernel_launch(void* const* d_in, const int* in_sizes, int n_in,
                              void* d_out, int out_size, void* d_ws, size_t ws_size,
                              hipStream_t stream)
{
    const float* x      = (const float*)d_in[0];
    const float* pos    = (const float*)d_in[1];
    const float* Wpre1  = (const float*)d_in[2];
    const float* bpre1  = (const float*)d_in[3];
    const float* Wpost1 = (const float*)d_in[4];
    const float* bpost1 = (const float*)d_in[5];
    const float* Wlin1  = (const float*)d_in[6];
    const float* blin1  = (const float*)d_in[7];
    const float* bn1g   = (const float*)d_in[8];
    const float* bn1b   = (const float*)d_in[9];
    const float* Wpre2  = (const float*)d_in[10];
    const float* bpre2  = (const float*)d_in[11];
    const float* Wpost2 = (const float*)d_in[12];
    const float* bpost2 = (const float*)d_in[13];
    const float* Wlin2  = (const float*)d_in[14];
    const float* blin2  = (const float*)d_in[15];
    const float* bn2g   = (const float*)d_in[16];
    const float* bn2b   = (const float*)d_in[17];
    float* out = (float*)d_out;

    char* ws = (char*)d_ws;
    size_t off = 0;
    auto alloc = [&](size_t bytes) { void* p = ws + off; off += (bytes + 255) & ~(size_t)255; return p; };
    int*   nbr   = (int*)  alloc((size_t)NN*7*4);
    float* u1    = (float*)alloc((size_t)NN*32*4);
    float* v1    = (float*)alloc((size_t)NN*32*4);
    float* y1    = (float*)alloc((size_t)NN*64*4);     // raw (pre-BN)
    float* u2    = (float*)alloc((size_t)NN*256*4);
    float* v2    = (float*)alloc((size_t)NN*256*4);
    float* y2    = (float*)alloc((size_t)NN*128*4);    // raw (pre-BN)
    float* Weff1 = (float*)alloc(2560*4);
    float* Weff2 = (float*)alloc(40960*4);
    float* W2u   = (float*)alloc(16384*4);
    float* W2v   = (float*)alloc(16384*4);
    float* P1s   = (float*)alloc(128*64*4);
    float* P1q   = (float*)alloc(128*64*4);
    float* sc1   = (float*)alloc(64*4);
    float* sh1   = (float*)alloc(64*4);
    float* P2s   = (float*)alloc(128*128*4);
    float* P2q   = (float*)alloc(128*128*4);

    prep_kernel<<<128, 256, 0, stream>>>(Wpost1, Wpost2, Wpre2, Weff1, Weff2, W2u, W2v);
    knn_kernel<<<NGRAPH*2, 256, 0, stream>>>(pos, nbr);
    a1_kernel<<<NN/8, 256, 0, stream>>>(x, Wpre1, bpre1, u1, v1);
    b1_kernel<<<NN/16, 256, 0, stream>>>(x, nbr, u1, v1, Weff1, bpost1, Wlin1, blin1, y1);
    bn_stats_kernel<64,6><<<128, 256, 0, stream>>>(y1, P1s, P1q);
    fin1_kernel<<<1, 64, 0, stream>>>(P1s, P1q, bn1g, bn1b, sc1, sh1);
    a2_kernel<<<NN/32, 256, 0, stream>>>(y1, sc1, sh1, W2u, W2v, bpre2, u2, v2);
    b2_kernel<<<NN/8, 256, 0, stream>>>(nbr, y1, sc1, sh1, u2, v2, Weff2, bpost2, Wlin2, blin2, y2);
    bn_stats_kernel<128,7><<<128, 256, 0, stream>>>(y2, P2s, P2q);
    pool_kernel<<<NGRAPH, 128, 0, stream>>>(y2, P2s, P2q, bn2g, bn2b, out);
}

// Round 6
// 552.703 us; speedup vs baseline: 1.0004x; 1.0004x over previous
//
#include <hip/hip_runtime.h>
#include <math.h>

// PNANet on MI355X, round 6:
//  * b2 = round-4 mapping (8 nodes/thread, each weight read ONCE per block)
//         + round-5 LDS diet (<=40KB -> 4 blocks/CU)
//         + interleaved K (G = h + 8*gi) -> branch-free a1/agg sub-loops
//         + shfl h-fold + 2-level stride-33 tree (8 barriers).
//  * fin2 kernel: BN2 scale/shift precomputed once (pool was redoing it 128x).

#define NGRAPH 128
#define NPG    512
#define NN     (NGRAPH*NPG)   // 65536
#define KNB    7

constexpr double AVG_DEG_LOG_D = 2.0239670479173344;  // (100*ln6+200*ln7+700*ln8)/1000
constexpr double LOG8_D        = 2.0794415416798357;

#define FMA4(A_, P_, W_) { (A_).x += (P_)*(W_).x; (A_).y += (P_)*(W_).y; (A_).z += (P_)*(W_).z; (A_).w += (P_)*(W_).w; }

// ---------------------------------------------------------------- weight prep
__global__ __launch_bounds__(256) void prep_kernel(
    const float* __restrict__ Wpost1, const float* __restrict__ Wpost2,
    const float* __restrict__ Wpre2,
    float* __restrict__ Weff1, float* __restrict__ Weff2,
    float* __restrict__ W2u, float* __restrict__ W2v)
{
    const float AMP = (float)(LOG8_D / AVG_DEG_LOG_D);
    const float ATT = (float)(AVG_DEG_LOG_D / LOG8_D);
    for (int i = blockIdx.x*256 + threadIdx.x; i < 76288; i += gridDim.x*256) {
        if (i < 2560) {
            // Weff1 [4][40][16]
            int t = i / 640, r = i % 640, g = r >> 4, fo = r & 15;
            float val;
            if (g < 8) val = Wpost1[(t*104 + g)*16 + fo];
            else {
                int g2 = g - 8;
                val = Wpost1[(t*104 +  8 + g2)*16 + fo]
                    + AMP*Wpost1[(t*104 + 40 + g2)*16 + fo]
                    + ATT*Wpost1[(t*104 + 72 + g2)*16 + fo];
            }
            Weff1[i] = val;
        } else if (i < 43520) {
            // Weff2 [4][320][32]
            int j = i - 2560;
            int t = j / 10240, r = j % 10240, g = r >> 5, fo = r & 31;
            float val;
            if (g < 64) val = Wpost2[(t*832 + g)*32 + fo];
            else {
                int g2 = g - 64;
                val = Wpost2[(t*832 +  64 + g2)*32 + fo]
                    + AMP*Wpost2[(t*832 + 320 + g2)*32 + fo]
                    + ATT*Wpost2[(t*832 + 576 + g2)*32 + fo];
            }
            Weff2[j] = val;
        } else {
            // W2u/W2v: [k=64][tf=256]
            int j = i - 43520;
            int half = j >> 14, j2 = j & 16383;
            int k = j2 >> 8, tf = j2 & 255, t = tf >> 6, f = tf & 63;
            if (half == 0) W2u[j2] = Wpre2[(t*128 +      k)*64 + f];
            else           W2v[j2] = Wpre2[(t*128 + 64 + k)*64 + f];
        }
    }
}

// ---------------------------------------------------------------- kNN (k=7); 2 blocks per graph
__global__ __launch_bounds__(256) void knn_kernel(const float* __restrict__ pos, int* __restrict__ nbr)
{
    __shared__ float4 posS[NPG];
    const int g    = blockIdx.x >> 1;
    const int half = blockIdx.x & 1;
    const int gb   = g * NPG;
    for (int j = threadIdx.x; j < NPG; j += 256)
        posS[j] = make_float4(pos[(gb+j)*3+0], pos[(gb+j)*3+1], pos[(gb+j)*3+2], 0.f);
    __syncthreads();
    const int i = half*256 + threadIdx.x;
    const float4 pi = posS[i];
    float bd[KNB]; int bi[KNB];
#pragma unroll
    for (int e = 0; e < KNB; ++e) { bd[e] = 3.0e38f; bi[e] = -1; }
#pragma unroll 4
    for (int j = 0; j < NPG; ++j) {
        float4 pj = posS[j];
        float dx = pi.x - pj.x, dy = pi.y - pj.y, dz = pi.z - pj.z;
        float d2 = __fadd_rn(__fadd_rn(__fmul_rn(dx,dx), __fmul_rn(dy,dy)), __fmul_rn(dz,dz));
        if (j == i) d2 = __builtin_inff();
        bool cmp[KNB];
#pragma unroll
        for (int e = 0; e < KNB; ++e) cmp[e] = d2 < bd[e];
#pragma unroll
        for (int e = KNB-1; e >= 1; --e) {
            bd[e] = cmp[e-1] ? bd[e-1] : (cmp[e] ? d2 : bd[e]);
            bi[e] = cmp[e-1] ? bi[e-1] : (cmp[e] ? j  : bi[e]);
        }
        bd[0] = cmp[0] ? d2 : bd[0];
        bi[0] = cmp[0] ? j  : bi[0];
    }
#pragma unroll
    for (int e = 0; e < KNB; ++e) nbr[(gb+i)*KNB + e] = gb + bi[e];
}

// ---------------------------------------------------------------- layer1: u1,v1 [N,32]
__global__ __launch_bounds__(256) void a1_kernel(
    const float* __restrict__ x, const float* __restrict__ Wpre1, const float* __restrict__ bpre1,
    float* __restrict__ u1, float* __restrict__ v1)
{
    __shared__ float wS[512];
    __shared__ float bS[32];
    const int tid = threadIdx.x;
    wS[tid] = Wpre1[tid]; wS[tid+256] = Wpre1[tid+256];
    if (tid < 32) bS[tid] = bpre1[tid];
    __syncthreads();
    const int n  = blockIdx.x*8 + (tid>>5);
    const int tf = tid & 31;
    const int t = tf >> 3, f = tf & 7;
    float u = bS[tf], v = 0.f;
#pragma unroll
    for (int e = 0; e < 8; ++e) {
        float xv = x[n*8+e];
        u += xv * wS[(t*16 + e)*8 + f];
        v += xv * wS[(t*16 + 8 + e)*8 + f];
    }
    u1[n*32+tf] = u;
    v1[n*32+tf] = v;
}

// ---------------------------------------------------------------- layer1 fused: agg + post + lin -> y1 [N,64]
__global__ __launch_bounds__(256) void b1_kernel(
    const float* __restrict__ x, const int* __restrict__ nbr,
    const float* __restrict__ u1, const float* __restrict__ v1,
    const float* __restrict__ Weff1, const float* __restrict__ bpost1,
    const float* __restrict__ Wlin1, const float* __restrict__ blin1,
    float* __restrict__ y1)
{
    __shared__ int   nbrsS[16*7];
    __shared__ float xsS[16*8];
    __shared__ float aggS[64*41];
    __shared__ float postS[16*68];
    const int tid  = threadIdx.x;
    const int base = blockIdx.x * 16;
    if (tid < 112) nbrsS[tid] = nbr[base*7 + tid];
    if (tid < 128) xsS[tid]   = x[base*8 + tid];
    __syncthreads();
#pragma unroll
    for (int it = 0; it < 2; ++it) {
        int task = tid + 256*it;
        int ln = task >> 5, tf = task & 31;
        float u = u1[(base+ln)*32 + tf];
        float s = 0.f, s2 = 0.f, mn = 3e38f, mx = -3e38f;
#pragma unroll
        for (int e = 0; e < 7; ++e) {
            float vv = v1[nbrsS[ln*7+e]*32 + tf];
            s += vv; s2 += vv*vv; mn = fminf(mn, vv); mx = fmaxf(mx, vv);
        }
        float mean = s * (1.f/7.f);
        float var  = s2 * (1.f/7.f) - mean*mean;
        float sd   = sqrtf(fmaxf(var, 0.f) + 1e-5f);
        int t = tf >> 3, f = tf & 7;
        int bo = (ln*4 + t)*41 + f;
        aggS[bo]    = u + mean;
        aggS[bo+8]  = u + mn;
        aggS[bo+16] = u + mx;
        aggS[bo+24] = sd;
    }
    __syncthreads();
    {   // post-MLP
        int ln = tid >> 4, q = tid & 15;
        int t = q >> 2, fo4 = (q & 3) * 4;
        float4 acc = *(const float4*)&bpost1[t*16 + fo4];
#pragma unroll
        for (int g = 0; g < 8; ++g) {
            float p = xsS[ln*8+g];
            float4 wv4 = *(const float4*)&Weff1[(t*40 + g)*16 + fo4];
            FMA4(acc, p, wv4)
        }
#pragma unroll 8
        for (int g = 0; g < 32; ++g) {
            float p = aggS[(ln*4 + t)*41 + g];
            float4 wv4 = *(const float4*)&Weff1[(t*40 + 8 + g)*16 + fo4];
            FMA4(acc, p, wv4)
        }
        *(float4*)&postS[ln*68 + t*16 + fo4] = acc;
    }
    __syncthreads();
    {   // mixing linear
        int ln = tid >> 4, q = tid & 15;
        int c4 = q*4;
        float4 acc = *(const float4*)&blin1[c4];
#pragma unroll 8
        for (int o = 0; o < 64; ++o) {
            float p = postS[ln*68 + o];
            float4 wv4 = *(const float4*)&Wlin1[o*64 + c4];
            FMA4(acc, p, wv4)
        }
        *(float4*)&y1[(base+ln)*64 + c4] = acc;
    }
}

// ---------------------------------------------------------------- BN stats partials (no atomics)
template<int C, int LOGC>
__global__ __launch_bounds__(256) void bn_stats_kernel(
    const float* __restrict__ y, float* __restrict__ Ps, float* __restrict__ Pq)
{
    __shared__ float sS[256], qS[256];
    const int tid = threadIdx.x;
    const int c  = tid & (C-1);
    const int rg = tid >> LOGC;
    const int G  = 256 >> LOGC;
    const int ROWS = NN/128;
    const int rowBase = blockIdx.x * ROWS;
    float s = 0.f, q = 0.f;
    for (int r = rg; r < ROWS; r += G) {
        float v = y[(rowBase + r)*C + c];
        s += v; q += v*v;
    }
    sS[tid] = s; qS[tid] = q;
    __syncthreads();
    if (rg == 0) {
        for (int g2 = 1; g2 < G; ++g2) { s += sS[g2*C + c]; q += qS[g2*C + c]; }
        Ps[blockIdx.x*C + c] = s;
        Pq[blockIdx.x*C + c] = q;
    }
}

// ---------------------------------------------------------------- finalize BN -> scale/shift (C threads)
template<int C>
__global__ __launch_bounds__(C) void fin_kernel(
    const float* __restrict__ Ps, const float* __restrict__ Pq,
    const float* __restrict__ g, const float* __restrict__ b,
    float* __restrict__ scO, float* __restrict__ shO)
{
    const int c = threadIdx.x;
    float s = 0.f, q = 0.f;
#pragma unroll 8
    for (int i = 0; i < 128; ++i) { s += Ps[i*C + c]; q += Pq[i*C + c]; }
    const float inv = 1.f/(float)NN;
    float mu  = s*inv;
    float var = q*inv - mu*mu;
    float sc  = g[c]*rsqrtf(var + 1e-5f);
    scO[c] = sc;
    shO[c] = b[c] - mu*sc;
}

// ---------------------------------------------------------------- layer2 pre: u2,v2 [N,256]; BN1+relu fused
__global__ __launch_bounds__(256) void a2_kernel(
    const float* __restrict__ y1raw, const float* __restrict__ sc1, const float* __restrict__ sh1,
    const float* __restrict__ W2u, const float* __restrict__ W2v,
    const float* __restrict__ bpre2,
    float* __restrict__ u2, float* __restrict__ v2)
{
    __shared__ float4 As4[512];     // 32 nodes x 16 float4
    const int tid = threadIdx.x;
    for (int i = tid; i < 512; i += 256) {
        float4 vv = ((const float4*)y1raw)[blockIdx.x*512 + i];
        int c0 = (i & 15) * 4;
        float comp[4] = {vv.x, vv.y, vv.z, vv.w};
#pragma unroll
        for (int j = 0; j < 4; ++j) {
            int c = c0 + j;
            comp[j] = fmaxf(comp[j]*sc1[c] + sh1[c], 0.f);
        }
        As4[i] = make_float4(comp[0], comp[1], comp[2], comp[3]);
    }
    __syncthreads();
    const int q = tid & 63, r = tid >> 6;
    const int nodeBase = blockIdx.x*32 + r*8;
    float4 accu[8], accv[8];
    const float4 bias = ((const float4*)bpre2)[q];
#pragma unroll
    for (int i = 0; i < 8; ++i) { accu[i] = bias; accv[i] = make_float4(0.f,0.f,0.f,0.f); }
    const float4* W2u4 = (const float4*)W2u;
    const float4* W2v4 = (const float4*)W2v;
#pragma unroll 2
    for (int kk = 0; kk < 16; ++kk) {
        float4 a4[8];
#pragma unroll
        for (int i = 0; i < 8; ++i) a4[i] = As4[(r*8+i)*16 + kk];
#pragma unroll
        for (int ks = 0; ks < 4; ++ks) {
            const int k = kk*4 + ks;
            const float4 wu4 = W2u4[k*64 + q];
            const float4 wv4 = W2v4[k*64 + q];
#pragma unroll
            for (int i = 0; i < 8; ++i) {
                const float av = (ks==0) ? a4[i].x : (ks==1) ? a4[i].y : (ks==2) ? a4[i].z : a4[i].w;
                FMA4(accu[i], av, wu4)
                FMA4(accv[i], av, wv4)
            }
        }
    }
#pragma unroll
    for (int i = 0; i < 8; ++i) {
        ((float4*)u2)[(nodeBase+i)*64 + q] = accu[i];
        ((float4*)v2)[(nodeBase+i)*64 + q] = accv[i];
    }
}

// ---------------------------------------------------------------- b2 reduce over K-chunks h: shfl parity fold + 2-level tree
__device__ __forceinline__ void hreduce(float4 (&acc)[8], float4* redS, int h, int q)
{
#pragma unroll
    for (int j = 0; j < 8; ++j) {   // fold h parity (lane ^ 32) in-register
        acc[j].x += __shfl_xor(acc[j].x, 32);
        acc[j].y += __shfl_xor(acc[j].y, 32);
        acc[j].z += __shfl_xor(acc[j].z, 32);
        acc[j].w += __shfl_xor(acc[j].w, 32);
    }
    const int w = h >> 1;           // wave id 0..3
#pragma unroll
    for (int step = 2; step >= 1; step >>= 1) {
        if (w >= step && w < 2*step) {
            const int s = w - step;
#pragma unroll
            for (int j = 0; j < 8; ++j) redS[(s*8 + j)*33 + q] = acc[j];
        }
        __syncthreads();
        if (w < step) {
#pragma unroll
            for (int j = 0; j < 8; ++j) {
                float4 r = redS[(w*8 + j)*33 + q];
                acc[j].x += r.x; acc[j].y += r.y; acc[j].z += r.z; acc[j].w += r.w;
            }
        }
        __syncthreads();
    }
}

// ---------------------------------------------------------------- layer2 fused: agg + post + lin -> y2 [N,128]
// thread = (q: 4-col group in [0,32), h: K-chunk in [0,8)); 8 nodes per thread.
// Interleaved K: G = h + 8*gi -> sub-loop A (gi<8, a1 part) / B (gi<32, agg part).
__global__ __launch_bounds__(256) void b2_kernel(
    const int* __restrict__ nbr, const float* __restrict__ y1raw,
    const float* __restrict__ sc1, const float* __restrict__ sh1,
    const float* __restrict__ u2, const float* __restrict__ v2,
    const float* __restrict__ Weff2, const float* __restrict__ bpost2,
    const float* __restrict__ Wlin2, const float* __restrict__ blin2,
    float* __restrict__ y2)
{
    __shared__ int   nbrsS[56];
    __shared__ float a1S[512];                       // 8 nodes x 64 post-BN acts
    __shared__ __align__(16) float actS[32*261];     // agg rows (node*4+t), pitch 261
    __shared__ float postS[8*132];
    float4* redS = (float4*)actS;                    // alias; live only after actS reads done

    const int tid  = threadIdx.x;
    const int base = blockIdx.x * 8;
    if (tid < 56) nbrsS[tid] = nbr[base*7 + tid];
    for (int i = tid; i < 512; i += 256) {
        int c = i & 63;
        a1S[i] = fmaxf(y1raw[base*64 + i]*sc1[c] + sh1[c], 0.f);
    }
    __syncthreads();
    // ---- aggregation: 7-neighbor mean/min/max/std over 256 feats per node
    {
        const int t = tid >> 6, f = tid & 63;
        for (int ln = 0; ln < 8; ++ln) {
            float u = u2[(base+ln)*256 + tid];
            float s = 0.f, s2 = 0.f, mn = 3e38f, mx = -3e38f;
#pragma unroll
            for (int e = 0; e < 7; ++e) {
                float vv = v2[nbrsS[ln*7+e]*256 + tid];
                s += vv; s2 += vv*vv; mn = fminf(mn, vv); mx = fmaxf(mx, vv);
            }
            float mean = s * (1.f/7.f);
            float var  = s2 * (1.f/7.f) - mean*mean;
            float sd   = sqrtf(fmaxf(var, 0.f) + 1e-5f);
            const int ro = (ln*4 + t)*261;
            actS[ro +       f] = u + mean;
            actS[ro +  64 + f] = u + mn;
            actS[ro + 128 + f] = u + mx;
            actS[ro + 192 + f] = sd;
        }
    }
    __syncthreads();
    const int q = tid & 31, h = tid >> 5;
    const int t = q >> 3, c4 = q * 4;        // output col = t*32 + (q&7)*4 = 4q
    // ---- post-MLP: per tower K=320 = 64 (a1) + 256 (agg); weights read once per block
    float4 acc[8];
#pragma unroll
    for (int j = 0; j < 8; ++j) acc[j] = make_float4(0.f,0.f,0.f,0.f);
    {   // sub-loop A: G = h + 8*gi (0..63), acts from a1S
        const float* wp = Weff2 + (t*320 + h)*32 + (q&7)*4;
        const float* ap = a1S + h;
#pragma unroll
        for (int gi = 0; gi < 8; ++gi) {
            const float4 w4 = *(const float4*)wp; wp += 256;
#pragma unroll
            for (int nn = 0; nn < 8; ++nn) {
                float p = ap[nn*64 + gi*8];
                FMA4(acc[nn], p, w4)
            }
        }
    }
    {   // sub-loop B: G = 64 + h + 8*gi (64..319), acts from actS rows (node*4+t)
        const float* wp = Weff2 + (t*320 + 64 + h)*32 + (q&7)*4;
        const float* ap = actS + t*261 + h;
#pragma unroll 8
        for (int gi = 0; gi < 32; ++gi) {
            const float4 w4 = *(const float4*)wp; wp += 256;
#pragma unroll
            for (int nn = 0; nn < 8; ++nn) {
                float p = ap[nn*1044 + gi*8];
                FMA4(acc[nn], p, w4)
            }
        }
    }
    __syncthreads();                 // actS reads done; redS alias safe
    hreduce(acc, redS, h, q);
    if (h == 0) {
        const float4 bb = *(const float4*)&bpost2[c4];
#pragma unroll
        for (int nn = 0; nn < 8; ++nn) {
            float4 a = acc[nn];
            a.x += bb.x; a.y += bb.y; a.z += bb.z; a.w += bb.w;
            *(float4*)&postS[nn*132 + c4] = a;
        }
    }
    __syncthreads();
    // ---- mixing linear: K=128 interleaved (o = h + 8*oi)
    float4 acc2[8];
#pragma unroll
    for (int j = 0; j < 8; ++j) acc2[j] = make_float4(0.f,0.f,0.f,0.f);
    {
        const float* wp = Wlin2 + h*128 + c4;
        const float* pp = postS + h;
#pragma unroll 8
        for (int oi = 0; oi < 16; ++oi) {
            const float4 w4 = *(const float4*)wp; wp += 1024;
#pragma unroll
            for (int nn = 0; nn < 8; ++nn) {
                float p = pp[nn*132 + oi*8];
                FMA4(acc2[nn], p, w4)
            }
        }
    }
    hreduce(acc2, redS, h, q);
    if (h == 0) {
        const float4 bb = *(const float4*)&blin2[c4];
#pragma unroll
        for (int nn = 0; nn < 8; ++nn) {
            float4 a = acc2[nn];
            a.x += bb.x; a.y += bb.y; a.z += bb.z; a.w += bb.w;
            *(float4*)&y2[(base+nn)*128 + c4] = a;
        }
    }
}

// ---------------------------------------------------------------- BN2(precomputed) + relu + per-graph mean pool
__global__ __launch_bounds__(128) void pool_kernel(
    const float* __restrict__ y2, const float* __restrict__ sc2, const float* __restrict__ sh2,
    float* __restrict__ out)
{
    const int c = threadIdx.x;
    const int g = blockIdx.x;
    const float sc = sc2[c];
    const float sh = sh2[c];
    float acc = 0.f;
    const int baseIdx = g*NPG*128 + c;
#pragma unroll 4
    for (int i = 0; i < NPG; ++i) {
        float v = y2[baseIdx + i*128];
        acc += fmaxf(v*sc + sh, 0.f);
    }
    out[g*128 + c] = acc * (1.f/(float)NPG);
}

// ---------------------------------------------------------------- launcher
extern "C" void kernel_launch(void* const* d_in, const int* in_sizes, int n_in,
                              void* d_out, int out_size, void* d_ws, size_t ws_size,
                              hipStream_t stream)
{
    const float* x      = (const float*)d_in[0];
    const float* pos    = (const float*)d_in[1];
    const float* Wpre1  = (const float*)d_in[2];
    const float* bpre1  = (const float*)d_in[3];
    const float* Wpost1 = (const float*)d_in[4];
    const float* bpost1 = (const float*)d_in[5];
    const float* Wlin1  = (const float*)d_in[6];
    const float* blin1  = (const float*)d_in[7];
    const float* bn1g   = (const float*)d_in[8];
    const float* bn1b   = (const float*)d_in[9];
    const float* Wpre2  = (const float*)d_in[10];
    const float* bpre2  = (const float*)d_in[11];
    const float* Wpost2 = (const float*)d_in[12];
    const float* bpost2 = (const float*)d_in[13];
    const float* Wlin2  = (const float*)d_in[14];
    const float* blin2  = (const float*)d_in[15];
    const float* bn2g   = (const float*)d_in[16];
    const float* bn2b   = (const float*)d_in[17];
    float* out = (float*)d_out;

    char* ws = (char*)d_ws;
    size_t off = 0;
    auto alloc = [&](size_t bytes) { void* p = ws + off; off += (bytes + 255) & ~(size_t)255; return p; };
    int*   nbr   = (int*)  alloc((size_t)NN*7*4);
    float* u1    = (float*)alloc((size_t)NN*32*4);
    float* v1    = (float*)alloc((size_t)NN*32*4);
    float* y1    = (float*)alloc((size_t)NN*64*4);     // raw (pre-BN)
    float* u2    = (float*)alloc((size_t)NN*256*4);
    float* v2    = (float*)alloc((size_t)NN*256*4);
    float* y2    = (float*)alloc((size_t)NN*128*4);    // raw (pre-BN)
    float* Weff1 = (float*)alloc(2560*4);
    float* Weff2 = (float*)alloc(40960*4);
    float* W2u   = (float*)alloc(16384*4);
    float* W2v   = (float*)alloc(16384*4);
    float* P1s   = (float*)alloc(128*64*4);
    float* P1q   = (float*)alloc(128*64*4);
    float* sc1   = (float*)alloc(64*4);
    float* sh1   = (float*)alloc(64*4);
    float* P2s   = (float*)alloc(128*128*4);
    float* P2q   = (float*)alloc(128*128*4);
    float* sc2   = (float*)alloc(128*4);
    float* sh2   = (float*)alloc(128*4);

    prep_kernel<<<128, 256, 0, stream>>>(Wpost1, Wpost2, Wpre2, Weff1, Weff2, W2u, W2v);
    knn_kernel<<<NGRAPH*2, 256, 0, stream>>>(pos, nbr);
    a1_kernel<<<NN/8, 256, 0, stream>>>(x, Wpre1, bpre1, u1, v1);
    b1_kernel<<<NN/16, 256, 0, stream>>>(x, nbr, u1, v1, Weff1, bpost1, Wlin1, blin1, y1);
    bn_stats_kernel<64,6><<<128, 256, 0, stream>>>(y1, P1s, P1q);
    fin_kernel<64><<<1, 64, 0, stream>>>(P1s, P1q, bn1g, bn1b, sc1, sh1);
    a2_kernel<<<NN/32, 256, 0, stream>>>(y1, sc1, sh1, W2u, W2v, bpre2, u2, v2);
    b2_kernel<<<NN/8, 256, 0, stream>>>(nbr, y1, sc1, sh1, u2, v2, Weff2, bpost2, Wlin2, blin2, y2);
    bn_stats_kernel<128,7><<<128, 256, 0, stream>>>(y2, P2s, P2q);
    fin_kernel<128><<<1, 128, 0, stream>>>(P2s, P2q, bn2g, bn2b, sc2, sh2);
    pool_kernel<<<NGRAPH, 128, 0, stream>>>(y2, sc2, sh2, out);
}

// Round 7
// 520.576 us; speedup vs baseline: 1.0621x; 1.0617x over previous
//
#include <hip/hip_runtime.h>
#include <math.h>

// PNANet on MI355X, round 7: b2 rework =
//   contiguous per-h K-chunks (128B weight stride, L1-friendly)  [round-4 locality]
// + branch-free pure-a1/pure-agg sub-loops                       [round-6 structure]
// + float4 activation reads (4 G per group: 4 wloads + 8 b128 + 32 FMA4)
// + XCD-affine swizzle (graph -> one XCD: v2 gather becomes L2-local)

#define NGRAPH 128
#define NPG    512
#define NN     (NGRAPH*NPG)   // 65536
#define KNB    7

constexpr double AVG_DEG_LOG_D = 2.0239670479173344;  // (100*ln6+200*ln7+700*ln8)/1000
constexpr double LOG8_D        = 2.0794415416798357;

#define FMA4(A_, P_, W_) { (A_).x += (P_)*(W_).x; (A_).y += (P_)*(W_).y; (A_).z += (P_)*(W_).z; (A_).w += (P_)*(W_).w; }

// ---------------------------------------------------------------- weight prep
__global__ __launch_bounds__(256) void prep_kernel(
    const float* __restrict__ Wpost1, const float* __restrict__ Wpost2,
    const float* __restrict__ Wpre2,
    float* __restrict__ Weff1, float* __restrict__ Weff2,
    float* __restrict__ W2u, float* __restrict__ W2v)
{
    const float AMP = (float)(LOG8_D / AVG_DEG_LOG_D);
    const float ATT = (float)(AVG_DEG_LOG_D / LOG8_D);
    for (int i = blockIdx.x*256 + threadIdx.x; i < 76288; i += gridDim.x*256) {
        if (i < 2560) {
            // Weff1 [4][40][16]
            int t = i / 640, r = i % 640, g = r >> 4, fo = r & 15;
            float val;
            if (g < 8) val = Wpost1[(t*104 + g)*16 + fo];
            else {
                int g2 = g - 8;
                val = Wpost1[(t*104 +  8 + g2)*16 + fo]
                    + AMP*Wpost1[(t*104 + 40 + g2)*16 + fo]
                    + ATT*Wpost1[(t*104 + 72 + g2)*16 + fo];
            }
            Weff1[i] = val;
        } else if (i < 43520) {
            // Weff2 [4][320][32]
            int j = i - 2560;
            int t = j / 10240, r = j % 10240, g = r >> 5, fo = r & 31;
            float val;
            if (g < 64) val = Wpost2[(t*832 + g)*32 + fo];
            else {
                int g2 = g - 64;
                val = Wpost2[(t*832 +  64 + g2)*32 + fo]
                    + AMP*Wpost2[(t*832 + 320 + g2)*32 + fo]
                    + ATT*Wpost2[(t*832 + 576 + g2)*32 + fo];
            }
            Weff2[j] = val;
        } else {
            // W2u/W2v: [k=64][tf=256]
            int j = i - 43520;
            int half = j >> 14, j2 = j & 16383;
            int k = j2 >> 8, tf = j2 & 255, t = tf >> 6, f = tf & 63;
            if (half == 0) W2u[j2] = Wpre2[(t*128 +      k)*64 + f];
            else           W2v[j2] = Wpre2[(t*128 + 64 + k)*64 + f];
        }
    }
}

// ---------------------------------------------------------------- kNN (k=7); 2 blocks per graph
__global__ __launch_bounds__(256) void knn_kernel(const float* __restrict__ pos, int* __restrict__ nbr)
{
    __shared__ float4 posS[NPG];
    const int g    = blockIdx.x >> 1;
    const int half = blockIdx.x & 1;
    const int gb   = g * NPG;
    for (int j = threadIdx.x; j < NPG; j += 256)
        posS[j] = make_float4(pos[(gb+j)*3+0], pos[(gb+j)*3+1], pos[(gb+j)*3+2], 0.f);
    __syncthreads();
    const int i = half*256 + threadIdx.x;
    const float4 pi = posS[i];
    float bd[KNB]; int bi[KNB];
#pragma unroll
    for (int e = 0; e < KNB; ++e) { bd[e] = 3.0e38f; bi[e] = -1; }
#pragma unroll 4
    for (int j = 0; j < NPG; ++j) {
        float4 pj = posS[j];
        float dx = pi.x - pj.x, dy = pi.y - pj.y, dz = pi.z - pj.z;
        float d2 = __fadd_rn(__fadd_rn(__fmul_rn(dx,dx), __fmul_rn(dy,dy)), __fmul_rn(dz,dz));
        if (j == i) d2 = __builtin_inff();
        bool cmp[KNB];
#pragma unroll
        for (int e = 0; e < KNB; ++e) cmp[e] = d2 < bd[e];
#pragma unroll
        for (int e = KNB-1; e >= 1; --e) {
            bd[e] = cmp[e-1] ? bd[e-1] : (cmp[e] ? d2 : bd[e]);
            bi[e] = cmp[e-1] ? bi[e-1] : (cmp[e] ? j  : bi[e]);
        }
        bd[0] = cmp[0] ? d2 : bd[0];
        bi[0] = cmp[0] ? j  : bi[0];
    }
#pragma unroll
    for (int e = 0; e < KNB; ++e) nbr[(gb+i)*KNB + e] = gb + bi[e];
}

// ---------------------------------------------------------------- layer1: u1,v1 [N,32]
__global__ __launch_bounds__(256) void a1_kernel(
    const float* __restrict__ x, const float* __restrict__ Wpre1, const float* __restrict__ bpre1,
    float* __restrict__ u1, float* __restrict__ v1)
{
    __shared__ float wS[512];
    __shared__ float bS[32];
    const int tid = threadIdx.x;
    wS[tid] = Wpre1[tid]; wS[tid+256] = Wpre1[tid+256];
    if (tid < 32) bS[tid] = bpre1[tid];
    __syncthreads();
    const int n  = blockIdx.x*8 + (tid>>5);
    const int tf = tid & 31;
    const int t = tf >> 3, f = tf & 7;
    float u = bS[tf], v = 0.f;
#pragma unroll
    for (int e = 0; e < 8; ++e) {
        float xv = x[n*8+e];
        u += xv * wS[(t*16 + e)*8 + f];
        v += xv * wS[(t*16 + 8 + e)*8 + f];
    }
    u1[n*32+tf] = u;
    v1[n*32+tf] = v;
}

// ---------------------------------------------------------------- layer1 fused: agg + post + lin -> y1 [N,64]
__global__ __launch_bounds__(256) void b1_kernel(
    const float* __restrict__ x, const int* __restrict__ nbr,
    const float* __restrict__ u1, const float* __restrict__ v1,
    const float* __restrict__ Weff1, const float* __restrict__ bpost1,
    const float* __restrict__ Wlin1, const float* __restrict__ blin1,
    float* __restrict__ y1)
{
    __shared__ int   nbrsS[16*7];
    __shared__ float xsS[16*8];
    __shared__ float aggS[64*41];
    __shared__ float postS[16*68];
    const int tid  = threadIdx.x;
    const int base = blockIdx.x * 16;
    if (tid < 112) nbrsS[tid] = nbr[base*7 + tid];
    if (tid < 128) xsS[tid]   = x[base*8 + tid];
    __syncthreads();
#pragma unroll
    for (int it = 0; it < 2; ++it) {
        int task = tid + 256*it;
        int ln = task >> 5, tf = task & 31;
        float u = u1[(base+ln)*32 + tf];
        float s = 0.f, s2 = 0.f, mn = 3e38f, mx = -3e38f;
#pragma unroll
        for (int e = 0; e < 7; ++e) {
            float vv = v1[nbrsS[ln*7+e]*32 + tf];
            s += vv; s2 += vv*vv; mn = fminf(mn, vv); mx = fmaxf(mx, vv);
        }
        float mean = s * (1.f/7.f);
        float var  = s2 * (1.f/7.f) - mean*mean;
        float sd   = sqrtf(fmaxf(var, 0.f) + 1e-5f);
        int t = tf >> 3, f = tf & 7;
        int bo = (ln*4 + t)*41 + f;
        aggS[bo]    = u + mean;
        aggS[bo+8]  = u + mn;
        aggS[bo+16] = u + mx;
        aggS[bo+24] = sd;
    }
    __syncthreads();
    {   // post-MLP
        int ln = tid >> 4, q = tid & 15;
        int t = q >> 2, fo4 = (q & 3) * 4;
        float4 acc = *(const float4*)&bpost1[t*16 + fo4];
#pragma unroll
        for (int g = 0; g < 8; ++g) {
            float p = xsS[ln*8+g];
            float4 wv4 = *(const float4*)&Weff1[(t*40 + g)*16 + fo4];
            FMA4(acc, p, wv4)
        }
#pragma unroll 8
        for (int g = 0; g < 32; ++g) {
            float p = aggS[(ln*4 + t)*41 + g];
            float4 wv4 = *(const float4*)&Weff1[(t*40 + 8 + g)*16 + fo4];
            FMA4(acc, p, wv4)
        }
        *(float4*)&postS[ln*68 + t*16 + fo4] = acc;
    }
    __syncthreads();
    {   // mixing linear
        int ln = tid >> 4, q = tid & 15;
        int c4 = q*4;
        float4 acc = *(const float4*)&blin1[c4];
#pragma unroll 8
        for (int o = 0; o < 64; ++o) {
            float p = postS[ln*68 + o];
            float4 wv4 = *(const float4*)&Wlin1[o*64 + c4];
            FMA4(acc, p, wv4)
        }
        *(float4*)&y1[(base+ln)*64 + c4] = acc;
    }
}

// ---------------------------------------------------------------- BN stats partials (no atomics)
template<int C, int LOGC>
__global__ __launch_bounds__(256) void bn_stats_kernel(
    const float* __restrict__ y, float* __restrict__ Ps, float* __restrict__ Pq)
{
    __shared__ float sS[256], qS[256];
    const int tid = threadIdx.x;
    const int c  = tid & (C-1);
    const int rg = tid >> LOGC;
    const int G  = 256 >> LOGC;
    const int ROWS = NN/128;
    const int rowBase = blockIdx.x * ROWS;
    float s = 0.f, q = 0.f;
    for (int r = rg; r < ROWS; r += G) {
        float v = y[(rowBase + r)*C + c];
        s += v; q += v*v;
    }
    sS[tid] = s; qS[tid] = q;
    __syncthreads();
    if (rg == 0) {
        for (int g2 = 1; g2 < G; ++g2) { s += sS[g2*C + c]; q += qS[g2*C + c]; }
        Ps[blockIdx.x*C + c] = s;
        Pq[blockIdx.x*C + c] = q;
    }
}

// ---------------------------------------------------------------- finalize BN -> scale/shift
template<int C>
__global__ __launch_bounds__(C) void fin_kernel(
    const float* __restrict__ Ps, const float* __restrict__ Pq,
    const float* __restrict__ g, const float* __restrict__ b,
    float* __restrict__ scO, float* __restrict__ shO)
{
    const int c = threadIdx.x;
    float s = 0.f, q = 0.f;
#pragma unroll 8
    for (int i = 0; i < 128; ++i) { s += Ps[i*C + c]; q += Pq[i*C + c]; }
    const float inv = 1.f/(float)NN;
    float mu  = s*inv;
    float var = q*inv - mu*mu;
    float sc  = g[c]*rsqrtf(var + 1e-5f);
    scO[c] = sc;
    shO[c] = b[c] - mu*sc;
}

// ---------------------------------------------------------------- layer2 pre: u2,v2 [N,256]; BN1+relu fused
__global__ __launch_bounds__(256) void a2_kernel(
    const float* __restrict__ y1raw, const float* __restrict__ sc1, const float* __restrict__ sh1,
    const float* __restrict__ W2u, const float* __restrict__ W2v,
    const float* __restrict__ bpre2,
    float* __restrict__ u2, float* __restrict__ v2)
{
    __shared__ float4 As4[512];     // 32 nodes x 16 float4
    const int tid = threadIdx.x;
    for (int i = tid; i < 512; i += 256) {
        float4 vv = ((const float4*)y1raw)[blockIdx.x*512 + i];
        int c0 = (i & 15) * 4;
        float comp[4] = {vv.x, vv.y, vv.z, vv.w};
#pragma unroll
        for (int j = 0; j < 4; ++j) {
            int c = c0 + j;
            comp[j] = fmaxf(comp[j]*sc1[c] + sh1[c], 0.f);
        }
        As4[i] = make_float4(comp[0], comp[1], comp[2], comp[3]);
    }
    __syncthreads();
    const int q = tid & 63, r = tid >> 6;
    const int nodeBase = blockIdx.x*32 + r*8;
    float4 accu[8], accv[8];
    const float4 bias = ((const float4*)bpre2)[q];
#pragma unroll
    for (int i = 0; i < 8; ++i) { accu[i] = bias; accv[i] = make_float4(0.f,0.f,0.f,0.f); }
    const float4* W2u4 = (const float4*)W2u;
    const float4* W2v4 = (const float4*)W2v;
#pragma unroll 2
    for (int kk = 0; kk < 16; ++kk) {
        float4 a4[8];
#pragma unroll
        for (int i = 0; i < 8; ++i) a4[i] = As4[(r*8+i)*16 + kk];
#pragma unroll
        for (int ks = 0; ks < 4; ++ks) {
            const int k = kk*4 + ks;
            const float4 wu4 = W2u4[k*64 + q];
            const float4 wv4 = W2v4[k*64 + q];
#pragma unroll
            for (int i = 0; i < 8; ++i) {
                const float av = (ks==0) ? a4[i].x : (ks==1) ? a4[i].y : (ks==2) ? a4[i].z : a4[i].w;
                FMA4(accu[i], av, wu4)
                FMA4(accv[i], av, wv4)
            }
        }
    }
#pragma unroll
    for (int i = 0; i < 8; ++i) {
        ((float4*)u2)[(nodeBase+i)*64 + q] = accu[i];
        ((float4*)v2)[(nodeBase+i)*64 + q] = accv[i];
    }
}

// ---------------------------------------------------------------- b2 reduce over K-chunks h
__device__ __forceinline__ void hreduce(float4 (&acc)[8], float4* redS, int h, int q)
{
#pragma unroll
    for (int j = 0; j < 8; ++j) {   // fold h parity (lane ^ 32) in-register
        acc[j].x += __shfl_xor(acc[j].x, 32);
        acc[j].y += __shfl_xor(acc[j].y, 32);
        acc[j].z += __shfl_xor(acc[j].z, 32);
        acc[j].w += __shfl_xor(acc[j].w, 32);
    }
    const int w = h >> 1;           // wave id 0..3
#pragma unroll
    for (int step = 2; step >= 1; step >>= 1) {
        if (w >= step && w < 2*step) {
            const int s = w - step;
#pragma unroll
            for (int j = 0; j < 8; ++j) redS[(s*8 + j)*33 + q] = acc[j];
        }
        __syncthreads();
        if (w < step) {
#pragma unroll
            for (int j = 0; j < 8; ++j) {
                float4 r = redS[(w*8 + j)*33 + q];
                acc[j].x += r.x; acc[j].y += r.y; acc[j].z += r.z; acc[j].w += r.w;
            }
        }
        __syncthreads();
    }
}

// ---------------------------------------------------------------- layer2 fused: agg + post + lin -> y2 [N,128]
// thread = (q in [0,32): 4-col group, h in [0,8): K-chunk); 8 nodes/thread.
// Chunks contiguous: a1 G in [8h,8h+8), agg G in [64+32h, 64+32h+32).
// float4 act reads: per 4 G's = 4 weight loads + 8 ds_read_b128 + 32 FMA4.
__global__ __launch_bounds__(256) void b2_kernel(
    const int* __restrict__ nbr, const float* __restrict__ y1raw,
    const float* __restrict__ sc1, const float* __restrict__ sh1,
    const float* __restrict__ u2, const float* __restrict__ v2,
    const float* __restrict__ Weff2, const float* __restrict__ bpost2,
    const float* __restrict__ Wlin2, const float* __restrict__ blin2,
    float* __restrict__ y2)
{
    __shared__ int   nbrsS[56];
    __shared__ __align__(16) float a1S[512];         // 8 nodes x 64 post-BN acts
    __shared__ __align__(16) float actS[32*260];     // agg rows (node*4+t), pitch 260 (16B-aligned)
    __shared__ __align__(16) float postS[8*132];
    float4* redS = (float4*)actS;                    // alias; live only after actS reads done

    const int tid  = threadIdx.x;
    // XCD-affine swizzle: graph g -> XCD g%8 (all 64 blocks of a graph share one L2)
    const int ob   = blockIdx.x;
    const int xcd  = ob & 7, slot = ob >> 3;
    const int gph  = ((slot >> 6) << 3) + xcd;       // [0,128)
    const int sub  = slot & 63;
    const int base = gph*NPG + sub*8;

    if (tid < 56) nbrsS[tid] = nbr[base*7 + tid];
    for (int i = tid; i < 512; i += 256) {
        int c = i & 63;
        a1S[i] = fmaxf(y1raw[base*64 + i]*sc1[c] + sh1[c], 0.f);
    }
    __syncthreads();
    // ---- aggregation: 7-neighbor mean/min/max/std over 256 feats per node
    {
        const int t = tid >> 6, f = tid & 63;
        for (int ln = 0; ln < 8; ++ln) {
            float u = u2[(base+ln)*256 + tid];
            float s = 0.f, s2 = 0.f, mn = 3e38f, mx = -3e38f;
#pragma unroll
            for (int e = 0; e < 7; ++e) {
                float vv = v2[nbrsS[ln*7+e]*256 + tid];
                s += vv; s2 += vv*vv; mn = fminf(mn, vv); mx = fmaxf(mx, vv);
            }
            float mean = s * (1.f/7.f);
            float var  = s2 * (1.f/7.f) - mean*mean;
            float sd   = sqrtf(fmaxf(var, 0.f) + 1e-5f);
            const int ro = (ln*4 + t)*260;
            actS[ro +       f] = u + mean;
            actS[ro +  64 + f] = u + mn;
            actS[ro + 128 + f] = u + mx;
            actS[ro + 192 + f] = sd;
        }
    }
    __syncthreads();
    const int q = tid & 31, h = tid >> 5;
    const int t = q >> 3, c4 = q * 4;        // output col = 4q
    // ---- post-MLP
    float4 acc[8];
#pragma unroll
    for (int j = 0; j < 8; ++j) acc[j] = make_float4(0.f,0.f,0.f,0.f);
    {   // sub-loop A: G in [8h, 8h+8), acts from a1S (float4 groups of 4 G)
        const float* wp = Weff2 + (t*320 + 8*h)*32 + (q&7)*4;
#pragma unroll
        for (int g4 = 0; g4 < 2; ++g4) {
            const float4 w0 = *(const float4*)(wp);
            const float4 w1 = *(const float4*)(wp + 32);
            const float4 w2 = *(const float4*)(wp + 64);
            const float4 w3 = *(const float4*)(wp + 96);
            wp += 128;
#pragma unroll
            for (int nn = 0; nn < 8; ++nn) {
                const float4 p = *(const float4*)&a1S[nn*64 + 8*h + g4*4];
                FMA4(acc[nn], p.x, w0) FMA4(acc[nn], p.y, w1)
                FMA4(acc[nn], p.z, w2) FMA4(acc[nn], p.w, w3)
            }
        }
    }
    {   // sub-loop B: G in [64+32h, 64+32h+32), acts from actS rows (nn*4+t)
        const float* wp = Weff2 + (t*320 + 64 + 32*h)*32 + (q&7)*4;
        const float* ap = actS + t*260 + 32*h;
#pragma unroll
        for (int g4 = 0; g4 < 8; ++g4) {
            const float4 w0 = *(const float4*)(wp);
            const float4 w1 = *(const float4*)(wp + 32);
            const float4 w2 = *(const float4*)(wp + 64);
            const float4 w3 = *(const float4*)(wp + 96);
            wp += 128;
#pragma unroll
            for (int nn = 0; nn < 8; ++nn) {
                const float4 p = *(const float4*)&ap[nn*1040 + g4*4];
                FMA4(acc[nn], p.x, w0) FMA4(acc[nn], p.y, w1)
                FMA4(acc[nn], p.z, w2) FMA4(acc[nn], p.w, w3)
            }
        }
    }
    __syncthreads();                 // actS reads done; redS alias safe
    hreduce(acc, redS, h, q);
    if (h == 0) {
        const float4 bb = *(const float4*)&bpost2[c4];
#pragma unroll
        for (int nn = 0; nn < 8; ++nn) {
            float4 a = acc[nn];
            a.x += bb.x; a.y += bb.y; a.z += bb.z; a.w += bb.w;
            *(float4*)&postS[nn*132 + c4] = a;
        }
    }
    __syncthreads();
    // ---- mixing linear: o in [16h, 16h+16), float4 groups of 4 o's
    float4 acc2[8];
#pragma unroll
    for (int j = 0; j < 8; ++j) acc2[j] = make_float4(0.f,0.f,0.f,0.f);
    {
        const float* wp = Wlin2 + (16*h)*128 + c4;
        const float* pp = postS + 16*h;
#pragma unroll
        for (int o4 = 0; o4 < 4; ++o4) {
            const float4 w0 = *(const float4*)(wp);
            const float4 w1 = *(const float4*)(wp + 128);
            const float4 w2 = *(const float4*)(wp + 256);
            const float4 w3 = *(const float4*)(wp + 384);
            wp += 512;
#pragma unroll
            for (int nn = 0; nn < 8; ++nn) {
                const float4 p = *(const float4*)&pp[nn*132 + o4*4];
                FMA4(acc2[nn], p.x, w0) FMA4(acc2[nn], p.y, w1)
                FMA4(acc2[nn], p.z, w2) FMA4(acc2[nn], p.w, w3)
            }
        }
    }
    hreduce(acc2, redS, h, q);
    if (h == 0) {
        const float4 bb = *(const float4*)&blin2[c4];
#pragma unroll
        for (int nn = 0; nn < 8; ++nn) {
            float4 a = acc2[nn];
            a.x += bb.x; a.y += bb.y; a.z += bb.z; a.w += bb.w;
            *(float4*)&y2[(base+nn)*128 + c4] = a;
        }
    }
}

// ---------------------------------------------------------------- BN2(precomputed) + relu + per-graph mean pool
__global__ __launch_bounds__(128) void pool_kernel(
    const float* __restrict__ y2, const float* __restrict__ sc2, const float* __restrict__ sh2,
    float* __restrict__ out)
{
    const int c = threadIdx.x;
    const int g = blockIdx.x;
    const float sc = sc2[c];
    const float sh = sh2[c];
    float acc = 0.f;
    const int baseIdx = g*NPG*128 + c;
#pragma unroll 4
    for (int i = 0; i < NPG; ++i) {
        float v = y2[baseIdx + i*128];
        acc += fmaxf(v*sc + sh, 0.f);
    }
    out[g*128 + c] = acc * (1.f/(float)NPG);
}

// ---------------------------------------------------------------- launcher
extern "C" void kernel_launch(void* const* d_in, const int* in_sizes, int n_in,
                              void* d_out, int out_size, void* d_ws, size_t ws_size,
                              hipStream_t stream)
{
    const float* x      = (const float*)d_in[0];
    const float* pos    = (const float*)d_in[1];
    const float* Wpre1  = (const float*)d_in[2];
    const float* bpre1  = (const float*)d_in[3];
    const float* Wpost1 = (const float*)d_in[4];
    const float* bpost1 = (const float*)d_in[5];
    const float* Wlin1  = (const float*)d_in[6];
    const float* blin1  = (const float*)d_in[7];
    const float* bn1g   = (const float*)d_in[8];
    const float* bn1b   = (const float*)d_in[9];
    const float* Wpre2  = (const float*)d_in[10];
    const float* bpre2  = (const float*)d_in[11];
    const float* Wpost2 = (const float*)d_in[12];
    const float* bpost2 = (const float*)d_in[13];
    const float* Wlin2  = (const float*)d_in[14];
    const float* blin2  = (const float*)d_in[15];
    const float* bn2g   = (const float*)d_in[16];
    const float* bn2b   = (const float*)d_in[17];
    float* out = (float*)d_out;

    char* ws = (char*)d_ws;
    size_t off = 0;
    auto alloc = [&](size_t bytes) { void* p = ws + off; off += (bytes + 255) & ~(size_t)255; return p; };
    int*   nbr   = (int*)  alloc((size_t)NN*7*4);
    float* u1    = (float*)alloc((size_t)NN*32*4);
    float* v1    = (float*)alloc((size_t)NN*32*4);
    float* y1    = (float*)alloc((size_t)NN*64*4);     // raw (pre-BN)
    float* u2    = (float*)alloc((size_t)NN*256*4);
    float* v2    = (float*)alloc((size_t)NN*256*4);
    float* y2    = (float*)alloc((size_t)NN*128*4);    // raw (pre-BN)
    float* Weff1 = (float*)alloc(2560*4);
    float* Weff2 = (float*)alloc(40960*4);
    float* W2u   = (float*)alloc(16384*4);
    float* W2v   = (float*)alloc(16384*4);
    float* P1s   = (float*)alloc(128*64*4);
    float* P1q   = (float*)alloc(128*64*4);
    float* sc1   = (float*)alloc(64*4);
    float* sh1   = (float*)alloc(64*4);
    float* P2s   = (float*)alloc(128*128*4);
    float* P2q   = (float*)alloc(128*128*4);
    float* sc2   = (float*)alloc(128*4);
    float* sh2   = (float*)alloc(128*4);

    prep_kernel<<<128, 256, 0, stream>>>(Wpost1, Wpost2, Wpre2, Weff1, Weff2, W2u, W2v);
    knn_kernel<<<NGRAPH*2, 256, 0, stream>>>(pos, nbr);
    a1_kernel<<<NN/8, 256, 0, stream>>>(x, Wpre1, bpre1, u1, v1);
    b1_kernel<<<NN/16, 256, 0, stream>>>(x, nbr, u1, v1, Weff1, bpost1, Wlin1, blin1, y1);
    bn_stats_kernel<64,6><<<128, 256, 0, stream>>>(y1, P1s, P1q);
    fin_kernel<64><<<1, 64, 0, stream>>>(P1s, P1q, bn1g, bn1b, sc1, sh1);
    a2_kernel<<<NN/32, 256, 0, stream>>>(y1, sc1, sh1, W2u, W2v, bpre2, u2, v2);
    b2_kernel<<<NN/8, 256, 0, stream>>>(nbr, y1, sc1, sh1, u2, v2, Weff2, bpost2, Wlin2, blin2, y2);
    bn_stats_kernel<128,7><<<128, 256, 0, stream>>>(y2, P2s, P2q);
    fin_kernel<128><<<1, 128, 0, stream>>>(P2s, P2q, bn2g, bn2b, sc2, sh2);
    pool_kernel<<<NGRAPH, 128, 0, stream>>>(y2, sc2, sh2, out);
}

// Round 8
// 420.898 us; speedup vs baseline: 1.3136x; 1.2368x over previous
//
#include <hip/hip_runtime.h>
#include <math.h>

// PNANet on MI355X, round 8: b2 GEMM phases -> bf16 MFMA (16x16x32).
//  * Wfrag_post / Wfrag_lin pre-packed in MFMA fragment order (prep).
//  * b_post folded through W_lin into blin_eff (exact algebra).
//  * b2: 16 nodes/block, wave=tower for post, wave=32-col slab for lin.
//  * everything else identical to round 7.

#define NGRAPH 128
#define NPG    512
#define NN     (NGRAPH*NPG)   // 65536
#define KNB    7

constexpr double AVG_DEG_LOG_D = 2.0239670479173344;  // (100*ln6+200*ln7+700*ln8)/1000
constexpr double LOG8_D        = 2.0794415416798357;

#define FMA4(A_, P_, W_) { (A_).x += (P_)*(W_).x; (A_).y += (P_)*(W_).y; (A_).z += (P_)*(W_).z; (A_).w += (P_)*(W_).w; }

typedef short bf16x8 __attribute__((ext_vector_type(8)));
typedef float f32x4  __attribute__((ext_vector_type(4)));

__device__ __forceinline__ unsigned short f2bf(float x) {   // RNE, finite inputs
    unsigned u = __float_as_uint(x);
    return (unsigned short)((u + 0x7fffu + ((u >> 16) & 1u)) >> 16);
}

// ---------------------------------------------------------------- weight prep
__global__ __launch_bounds__(256) void prep_kernel(
    const float* __restrict__ Wpost1, const float* __restrict__ Wpost2,
    const float* __restrict__ Wpre2,  const float* __restrict__ Wlin2,
    const float* __restrict__ bpost2, const float* __restrict__ blin2,
    float* __restrict__ Weff1, float* __restrict__ W2u, float* __restrict__ W2v,
    unsigned short* __restrict__ Wfp, unsigned short* __restrict__ Wfl,
    float* __restrict__ blin_eff)
{
    const float AMP = (float)(LOG8_D / AVG_DEG_LOG_D);
    const float ATT = (float)(AVG_DEG_LOG_D / LOG8_D);
    for (int i = blockIdx.x*256 + threadIdx.x; i < 92800; i += gridDim.x*256) {
        if (i < 2560) {
            // Weff1 [4][40][16]
            int t = i / 640, r = i % 640, g = r >> 4, fo = r & 15;
            float val;
            if (g < 8) val = Wpost1[(t*104 + g)*16 + fo];
            else {
                int g2 = g - 8;
                val = Wpost1[(t*104 +  8 + g2)*16 + fo]
                    + AMP*Wpost1[(t*104 + 40 + g2)*16 + fo]
                    + ATT*Wpost1[(t*104 + 72 + g2)*16 + fo];
            }
            Weff1[i] = val;
        } else if (i < 35328) {
            // W2u/W2v: [k=64][tf=256]
            int j = i - 2560;
            int half = j >> 14, j2 = j & 16383;
            int k = j2 >> 8, tf = j2 & 255, t = tf >> 6, f = tf & 63;
            if (half == 0) W2u[j2] = Wpre2[(t*128 +      k)*64 + f];
            else           W2v[j2] = Wpre2[(t*128 + 64 + k)*64 + f];
        } else if (i < 76288) {
            // Wfrag_post: [t][kk<10][c<2][lane<64][j<8], bf16
            int jj = i - 35328;
            int t = jj / 10240, r = jj % 10240;
            int kk = r / 1024, r2 = r % 1024;
            int c = r2 >> 9, lane = (r2 >> 3) & 63, jf = r2 & 7;
            int G   = kk*32 + (lane >> 4)*8 + jf;
            int col = c*16 + (lane & 15);
            float val;
            if (G < 64) val = Wpost2[(t*832 + G)*32 + col];
            else {
                int g2 = G - 64;
                val = Wpost2[(t*832 +  64 + g2)*32 + col]
                    + AMP*Wpost2[(t*832 + 320 + g2)*32 + col]
                    + ATT*Wpost2[(t*832 + 576 + g2)*32 + col];
            }
            Wfp[jj] = f2bf(val);
        } else if (i < 92672) {
            // Wfrag_lin: [kk<4][tile<8][lane<64][j<8], bf16
            int jj = i - 76288;
            int kk = jj / 4096, r = jj % 4096;
            int tile = r >> 9, lane = (r >> 3) & 63, jf = r & 7;
            int k   = kk*32 + (lane >> 4)*8 + jf;
            int col = tile*16 + (lane & 15);
            Wfl[jj] = f2bf(Wlin2[k*128 + col]);
        } else {
            // blin_eff[c] = blin2[c] + sum_o bpost2[o]*Wlin2[o][c]
            int c = i - 92672;
            float s = blin2[c];
            for (int o = 0; o < 128; ++o) s += bpost2[o]*Wlin2[o*128 + c];
            blin_eff[c] = s;
        }
    }
}

// ---------------------------------------------------------------- kNN (k=7); 2 blocks per graph
__global__ __launch_bounds__(256) void knn_kernel(const float* __restrict__ pos, int* __restrict__ nbr)
{
    __shared__ float4 posS[NPG];
    const int g    = blockIdx.x >> 1;
    const int half = blockIdx.x & 1;
    const int gb   = g * NPG;
    for (int j = threadIdx.x; j < NPG; j += 256)
        posS[j] = make_float4(pos[(gb+j)*3+0], pos[(gb+j)*3+1], pos[(gb+j)*3+2], 0.f);
    __syncthreads();
    const int i = half*256 + threadIdx.x;
    const float4 pi = posS[i];
    float bd[KNB]; int bi[KNB];
#pragma unroll
    for (int e = 0; e < KNB; ++e) { bd[e] = 3.0e38f; bi[e] = -1; }
#pragma unroll 4
    for (int j = 0; j < NPG; ++j) {
        float4 pj = posS[j];
        float dx = pi.x - pj.x, dy = pi.y - pj.y, dz = pi.z - pj.z;
        float d2 = __fadd_rn(__fadd_rn(__fmul_rn(dx,dx), __fmul_rn(dy,dy)), __fmul_rn(dz,dz));
        if (j == i) d2 = __builtin_inff();
        bool cmp[KNB];
#pragma unroll
        for (int e = 0; e < KNB; ++e) cmp[e] = d2 < bd[e];
#pragma unroll
        for (int e = KNB-1; e >= 1; --e) {
            bd[e] = cmp[e-1] ? bd[e-1] : (cmp[e] ? d2 : bd[e]);
            bi[e] = cmp[e-1] ? bi[e-1] : (cmp[e] ? j  : bi[e]);
        }
        bd[0] = cmp[0] ? d2 : bd[0];
        bi[0] = cmp[0] ? j  : bi[0];
    }
#pragma unroll
    for (int e = 0; e < KNB; ++e) nbr[(gb+i)*KNB + e] = gb + bi[e];
}

// ---------------------------------------------------------------- layer1: u1,v1 [N,32]
__global__ __launch_bounds__(256) void a1_kernel(
    const float* __restrict__ x, const float* __restrict__ Wpre1, const float* __restrict__ bpre1,
    float* __restrict__ u1, float* __restrict__ v1)
{
    __shared__ float wS[512];
    __shared__ float bS[32];
    const int tid = threadIdx.x;
    wS[tid] = Wpre1[tid]; wS[tid+256] = Wpre1[tid+256];
    if (tid < 32) bS[tid] = bpre1[tid];
    __syncthreads();
    const int n  = blockIdx.x*8 + (tid>>5);
    const int tf = tid & 31;
    const int t = tf >> 3, f = tf & 7;
    float u = bS[tf], v = 0.f;
#pragma unroll
    for (int e = 0; e < 8; ++e) {
        float xv = x[n*8+e];
        u += xv * wS[(t*16 + e)*8 + f];
        v += xv * wS[(t*16 + 8 + e)*8 + f];
    }
    u1[n*32+tf] = u;
    v1[n*32+tf] = v;
}

// ---------------------------------------------------------------- layer1 fused: agg + post + lin -> y1 [N,64]
__global__ __launch_bounds__(256) void b1_kernel(
    const float* __restrict__ x, const int* __restrict__ nbr,
    const float* __restrict__ u1, const float* __restrict__ v1,
    const float* __restrict__ Weff1, const float* __restrict__ bpost1,
    const float* __restrict__ Wlin1, const float* __restrict__ blin1,
    float* __restrict__ y1)
{
    __shared__ int   nbrsS[16*7];
    __shared__ float xsS[16*8];
    __shared__ float aggS[64*41];
    __shared__ float postS[16*68];
    const int tid  = threadIdx.x;
    const int base = blockIdx.x * 16;
    if (tid < 112) nbrsS[tid] = nbr[base*7 + tid];
    if (tid < 128) xsS[tid]   = x[base*8 + tid];
    __syncthreads();
#pragma unroll
    for (int it = 0; it < 2; ++it) {
        int task = tid + 256*it;
        int ln = task >> 5, tf = task & 31;
        float u = u1[(base+ln)*32 + tf];
        float s = 0.f, s2 = 0.f, mn = 3e38f, mx = -3e38f;
#pragma unroll
        for (int e = 0; e < 7; ++e) {
            float vv = v1[nbrsS[ln*7+e]*32 + tf];
            s += vv; s2 += vv*vv; mn = fminf(mn, vv); mx = fmaxf(mx, vv);
        }
        float mean = s * (1.f/7.f);
        float var  = s2 * (1.f/7.f) - mean*mean;
        float sd   = sqrtf(fmaxf(var, 0.f) + 1e-5f);
        int t = tf >> 3, f = tf & 7;
        int bo = (ln*4 + t)*41 + f;
        aggS[bo]    = u + mean;
        aggS[bo+8]  = u + mn;
        aggS[bo+16] = u + mx;
        aggS[bo+24] = sd;
    }
    __syncthreads();
    {   // post-MLP
        int ln = tid >> 4, q = tid & 15;
        int t = q >> 2, fo4 = (q & 3) * 4;
        float4 acc = *(const float4*)&bpost1[t*16 + fo4];
#pragma unroll
        for (int g = 0; g < 8; ++g) {
            float p = xsS[ln*8+g];
            float4 wv4 = *(const float4*)&Weff1[(t*40 + g)*16 + fo4];
            FMA4(acc, p, wv4)
        }
#pragma unroll 8
        for (int g = 0; g < 32; ++g) {
            float p = aggS[(ln*4 + t)*41 + g];
            float4 wv4 = *(const float4*)&Weff1[(t*40 + 8 + g)*16 + fo4];
            FMA4(acc, p, wv4)
        }
        *(float4*)&postS[ln*68 + t*16 + fo4] = acc;
    }
    __syncthreads();
    {   // mixing linear
        int ln = tid >> 4, q = tid & 15;
        int c4 = q*4;
        float4 acc = *(const float4*)&blin1[c4];
#pragma unroll 8
        for (int o = 0; o < 64; ++o) {
            float p = postS[ln*68 + o];
            float4 wv4 = *(const float4*)&Wlin1[o*64 + c4];
            FMA4(acc, p, wv4)
        }
        *(float4*)&y1[(base+ln)*64 + c4] = acc;
    }
}

// ---------------------------------------------------------------- BN stats partials (no atomics)
template<int C, int LOGC>
__global__ __launch_bounds__(256) void bn_stats_kernel(
    const float* __restrict__ y, float* __restrict__ Ps, float* __restrict__ Pq)
{
    __shared__ float sS[256], qS[256];
    const int tid = threadIdx.x;
    const int c  = tid & (C-1);
    const int rg = tid >> LOGC;
    const int G  = 256 >> LOGC;
    const int ROWS = NN/128;
    const int rowBase = blockIdx.x * ROWS;
    float s = 0.f, q = 0.f;
    for (int r = rg; r < ROWS; r += G) {
        float v = y[(rowBase + r)*C + c];
        s += v; q += v*v;
    }
    sS[tid] = s; qS[tid] = q;
    __syncthreads();
    if (rg == 0) {
        for (int g2 = 1; g2 < G; ++g2) { s += sS[g2*C + c]; q += qS[g2*C + c]; }
        Ps[blockIdx.x*C + c] = s;
        Pq[blockIdx.x*C + c] = q;
    }
}

// ---------------------------------------------------------------- finalize BN -> scale/shift
template<int C>
__global__ __launch_bounds__(C) void fin_kernel(
    const float* __restrict__ Ps, const float* __restrict__ Pq,
    const float* __restrict__ g, const float* __restrict__ b,
    float* __restrict__ scO, float* __restrict__ shO)
{
    const int c = threadIdx.x;
    float s = 0.f, q = 0.f;
#pragma unroll 8
    for (int i = 0; i < 128; ++i) { s += Ps[i*C + c]; q += Pq[i*C + c]; }
    const float inv = 1.f/(float)NN;
    float mu  = s*inv;
    float var = q*inv - mu*mu;
    float sc  = g[c]*rsqrtf(var + 1e-5f);
    scO[c] = sc;
    shO[c] = b[c] - mu*sc;
}

// ---------------------------------------------------------------- layer2 pre: u2,v2 [N,256]; BN1+relu fused
__global__ __launch_bounds__(256) void a2_kernel(
    const float* __restrict__ y1raw, const float* __restrict__ sc1, const float* __restrict__ sh1,
    const float* __restrict__ W2u, const float* __restrict__ W2v,
    const float* __restrict__ bpre2,
    float* __restrict__ u2, float* __restrict__ v2)
{
    __shared__ float4 As4[512];     // 32 nodes x 16 float4
    const int tid = threadIdx.x;
    for (int i = tid; i < 512; i += 256) {
        float4 vv = ((const float4*)y1raw)[blockIdx.x*512 + i];
        int c0 = (i & 15) * 4;
        float comp[4] = {vv.x, vv.y, vv.z, vv.w};
#pragma unroll
        for (int j = 0; j < 4; ++j) {
            int c = c0 + j;
            comp[j] = fmaxf(comp[j]*sc1[c] + sh1[c], 0.f);
        }
        As4[i] = make_float4(comp[0], comp[1], comp[2], comp[3]);
    }
    __syncthreads();
    const int q = tid & 63, r = tid >> 6;
    const int nodeBase = blockIdx.x*32 + r*8;
    float4 accu[8], accv[8];
    const float4 bias = ((const float4*)bpre2)[q];
#pragma unroll
    for (int i = 0; i < 8; ++i) { accu[i] = bias; accv[i] = make_float4(0.f,0.f,0.f,0.f); }
    const float4* W2u4 = (const float4*)W2u;
    const float4* W2v4 = (const float4*)W2v;
#pragma unroll 2
    for (int kk = 0; kk < 16; ++kk) {
        float4 a4[8];
#pragma unroll
        for (int i = 0; i < 8; ++i) a4[i] = As4[(r*8+i)*16 + kk];
#pragma unroll
        for (int ks = 0; ks < 4; ++ks) {
            const int k = kk*4 + ks;
            const float4 wu4 = W2u4[k*64 + q];
            const float4 wv4 = W2v4[k*64 + q];
#pragma unroll
            for (int i = 0; i < 8; ++i) {
                const float av = (ks==0) ? a4[i].x : (ks==1) ? a4[i].y : (ks==2) ? a4[i].z : a4[i].w;
                FMA4(accu[i], av, wu4)
                FMA4(accv[i], av, wv4)
            }
        }
    }
#pragma unroll
    for (int i = 0; i < 8; ++i) {
        ((float4*)u2)[(nodeBase+i)*64 + q] = accu[i];
        ((float4*)v2)[(nodeBase+i)*64 + q] = accv[i];
    }
}

// ---------------------------------------------------------------- layer2 fused (MFMA): agg + post + lin -> y2 [N,128]
// 16 nodes/block, 4 waves. Post: wave w = tower w, C[16][32] = act[16][320] x W_t.
// Lin: wave w = cols [32w,32w+32), C[16][32] = post[16][128] x Wlin slab.
// mfma_f32_16x16x32_bf16 frags: A row=lane&15,k=(lane>>4)*8+j; B col=lane&15; D row=(lane>>4)*4+j,col=lane&15.
__global__ __launch_bounds__(256) void b2_kernel(
    const int* __restrict__ nbr, const float* __restrict__ y1raw,
    const float* __restrict__ sc1, const float* __restrict__ sh1,
    const float* __restrict__ u2, const float* __restrict__ v2,
    const unsigned short* __restrict__ Wfp, const unsigned short* __restrict__ Wfl,
    const float* __restrict__ blin_eff,
    float* __restrict__ y2)
{
    __shared__ int nbrsS[112];
    __shared__ __align__(16) unsigned short a1S[16*72];     // 16 nodes x 64 a1 (bf16), pitch 72
    __shared__ __align__(16) unsigned short aggS[64*264];   // rows (t*16+n), 256 agg vals, pitch 264
    __shared__ __align__(16) unsigned short postS[16*136];  // 16 nodes x 128 post (bf16), pitch 136

    const int tid = threadIdx.x;
    // XCD-affine swizzle: 32 blocks/graph, graph -> XCD (graph & 7)
    const int ob   = blockIdx.x;
    const int xcd  = ob & 7, slot = ob >> 3;
    const int gph  = ((slot >> 5) << 3) + xcd;
    const int sub  = slot & 31;
    const int base = gph*NPG + sub*16;

    if (tid < 112) nbrsS[tid] = nbr[base*7 + tid];
    for (int i = tid; i < 1024; i += 256) {
        int c = i & 63, n = i >> 6;
        float a = fmaxf(y1raw[base*64 + i]*sc1[c] + sh1[c], 0.f);
        a1S[n*72 + c] = f2bf(a);
    }
    __syncthreads();
    // ---- aggregation: 7-neighbor mean/min/max/std, fp32 -> bf16 rows
    {
        const int t = tid >> 6, f = tid & 63;
        for (int ln = 0; ln < 16; ++ln) {
            float u = u2[(base+ln)*256 + tid];
            float s = 0.f, s2 = 0.f, mn = 3e38f, mx = -3e38f;
#pragma unroll
            for (int e = 0; e < 7; ++e) {
                float vv = v2[nbrsS[ln*7+e]*256 + tid];
                s += vv; s2 += vv*vv; mn = fminf(mn, vv); mx = fmaxf(mx, vv);
            }
            float mean = s * (1.f/7.f);
            float var  = s2 * (1.f/7.f) - mean*mean;
            float sd   = sqrtf(fmaxf(var, 0.f) + 1e-5f);
            const int ro = (t*16 + ln)*264;
            aggS[ro +       f] = f2bf(u + mean);
            aggS[ro +  64 + f] = f2bf(u + mn);
            aggS[ro + 128 + f] = f2bf(u + mx);
            aggS[ro + 192 + f] = f2bf(sd);
        }
    }
    __syncthreads();
    const int l = tid & 63, w = tid >> 6;
    const int lr = l & 15, lk = l >> 4;
    // ---- post GEMM (tower w): K=320 = 2 a1-chunks + 8 agg-chunks
    f32x4 acc0 = {0.f,0.f,0.f,0.f}, acc1 = {0.f,0.f,0.f,0.f};
    {
        const bf16x8* WB = (const bf16x8*)Wfp;
#pragma unroll
        for (int kk = 0; kk < 10; ++kk) {
            bf16x8 a;
            if (kk < 2) a = *(const bf16x8*)&a1S[lr*72 + kk*32 + lk*8];
            else        a = *(const bf16x8*)&aggS[(w*16 + lr)*264 + (kk-2)*32 + lk*8];
            bf16x8 b0 = WB[((w*10 + kk)*2 + 0)*64 + l];
            bf16x8 b1 = WB[((w*10 + kk)*2 + 1)*64 + l];
            acc0 = __builtin_amdgcn_mfma_f32_16x16x32_bf16(a, b0, acc0, 0, 0, 0);
            acc1 = __builtin_amdgcn_mfma_f32_16x16x32_bf16(a, b1, acc1, 0, 0, 0);
        }
    }
#pragma unroll
    for (int j = 0; j < 4; ++j) {
        const int row = lk*4 + j;
        postS[row*136 + w*32 +      lr] = f2bf(acc0[j]);
        postS[row*136 + w*32 + 16 + lr] = f2bf(acc1[j]);
    }
    __syncthreads();
    // ---- lin GEMM (cols 32w..32w+31): K=128
    f32x4 d0 = {0.f,0.f,0.f,0.f}, d1 = {0.f,0.f,0.f,0.f};
    {
        const bf16x8* WB = (const bf16x8*)Wfl;
#pragma unroll
        for (int kk = 0; kk < 4; ++kk) {
            bf16x8 a = *(const bf16x8*)&postS[lr*136 + kk*32 + lk*8];
            bf16x8 b0 = WB[(kk*8 + 2*w + 0)*64 + l];
            bf16x8 b1 = WB[(kk*8 + 2*w + 1)*64 + l];
            d0 = __builtin_amdgcn_mfma_f32_16x16x32_bf16(a, b0, d0, 0, 0, 0);
            d1 = __builtin_amdgcn_mfma_f32_16x16x32_bf16(a, b1, d1, 0, 0, 0);
        }
    }
    const float be0 = blin_eff[w*32 +      lr];
    const float be1 = blin_eff[w*32 + 16 + lr];
#pragma unroll
    for (int j = 0; j < 4; ++j) {
        const int row = lk*4 + j;
        y2[(base + row)*128 + w*32 +      lr] = d0[j] + be0;
        y2[(base + row)*128 + w*32 + 16 + lr] = d1[j] + be1;
    }
}

// ---------------------------------------------------------------- BN2(precomputed) + relu + per-graph mean pool
__global__ __launch_bounds__(128) void pool_kernel(
    const float* __restrict__ y2, const float* __restrict__ sc2, const float* __restrict__ sh2,
    float* __restrict__ out)
{
    const int c = threadIdx.x;
    const int g = blockIdx.x;
    const float sc = sc2[c];
    const float sh = sh2[c];
    float acc = 0.f;
    const int baseIdx = g*NPG*128 + c;
#pragma unroll 4
    for (int i = 0; i < NPG; ++i) {
        float v = y2[baseIdx + i*128];
        acc += fmaxf(v*sc + sh, 0.f);
    }
    out[g*128 + c] = acc * (1.f/(float)NPG);
}

// ---------------------------------------------------------------- launcher
extern "C" void kernel_launch(void* const* d_in, const int* in_sizes, int n_in,
                              void* d_out, int out_size, void* d_ws, size_t ws_size,
                              hipStream_t stream)
{
    const float* x      = (const float*)d_in[0];
    const float* pos    = (const float*)d_in[1];
    const float* Wpre1  = (const float*)d_in[2];
    const float* bpre1  = (const float*)d_in[3];
    const float* Wpost1 = (const float*)d_in[4];
    const float* bpost1 = (const float*)d_in[5];
    const float* Wlin1  = (const float*)d_in[6];
    const float* blin1  = (const float*)d_in[7];
    const float* bn1g   = (const float*)d_in[8];
    const float* bn1b   = (const float*)d_in[9];
    const float* Wpre2  = (const float*)d_in[10];
    const float* bpre2  = (const float*)d_in[11];
    const float* Wpost2 = (const float*)d_in[12];
    const float* bpost2 = (const float*)d_in[13];
    const float* Wlin2  = (const float*)d_in[14];
    const float* blin2  = (const float*)d_in[15];
    const float* bn2g   = (const float*)d_in[16];
    const float* bn2b   = (const float*)d_in[17];
    float* out = (float*)d_out;

    char* ws = (char*)d_ws;
    size_t off = 0;
    auto alloc = [&](size_t bytes) { void* p = ws + off; off += (bytes + 255) & ~(size_t)255; return p; };
    int*   nbr   = (int*)  alloc((size_t)NN*7*4);
    float* u1    = (float*)alloc((size_t)NN*32*4);
    float* v1    = (float*)alloc((size_t)NN*32*4);
    float* y1    = (float*)alloc((size_t)NN*64*4);     // raw (pre-BN)
    float* u2    = (float*)alloc((size_t)NN*256*4);
    float* v2    = (float*)alloc((size_t)NN*256*4);
    float* y2    = (float*)alloc((size_t)NN*128*4);    // raw (pre-BN)
    float* Weff1 = (float*)alloc(2560*4);
    float* W2u   = (float*)alloc(16384*4);
    float* W2v   = (float*)alloc(16384*4);
    unsigned short* Wfp = (unsigned short*)alloc(40960*2);
    unsigned short* Wfl = (unsigned short*)alloc(16384*2);
    float* blin_eff = (float*)alloc(128*4);
    float* P1s   = (float*)alloc(128*64*4);
    float* P1q   = (float*)alloc(128*64*4);
    float* sc1   = (float*)alloc(64*4);
    float* sh1   = (float*)alloc(64*4);
    float* P2s   = (float*)alloc(128*128*4);
    float* P2q   = (float*)alloc(128*128*4);
    float* sc2   = (float*)alloc(128*4);
    float* sh2   = (float*)alloc(128*4);

    prep_kernel<<<128, 256, 0, stream>>>(Wpost1, Wpost2, Wpre2, Wlin2, bpost2, blin2,
                                         Weff1, W2u, W2v, Wfp, Wfl, blin_eff);
    knn_kernel<<<NGRAPH*2, 256, 0, stream>>>(pos, nbr);
    a1_kernel<<<NN/8, 256, 0, stream>>>(x, Wpre1, bpre1, u1, v1);
    b1_kernel<<<NN/16, 256, 0, stream>>>(x, nbr, u1, v1, Weff1, bpost1, Wlin1, blin1, y1);
    bn_stats_kernel<64,6><<<128, 256, 0, stream>>>(y1, P1s, P1q);
    fin_kernel<64><<<1, 64, 0, stream>>>(P1s, P1q, bn1g, bn1b, sc1, sh1);
    a2_kernel<<<NN/32, 256, 0, stream>>>(y1, sc1, sh1, W2u, W2v, bpre2, u2, v2);
    b2_kernel<<<NN/16, 256, 0, stream>>>(nbr, y1, sc1, sh1, u2, v2, Wfp, Wfl, blin_eff, y2);
    bn_stats_kernel<128,7><<<128, 256, 0, stream>>>(y2, P2s, P2q);
    fin_kernel<128><<<1, 128, 0, stream>>>(P2s, P2q, bn2g, bn2b, sc2, sh2);
    pool_kernel<<<NGRAPH, 128, 0, stream>>>(y2, sc2, sh2, out);
}

// Round 9
// 343.798 us; speedup vs baseline: 1.6082x; 1.2243x over previous
//
#include <hip/hip_runtime.h>
#include <math.h>

// PNANet on MI355X, round 9: a2 -> bf16 MFMA GEMM, uv2 stored bf16 [N][512] (u||v).
//  * Wfuv pre-packed in B-fragment order (prep); bias added pre-store.
//  * A-frags loaded once per wave, reused across 32 col-tiles.
//  * b2 reads uv2 as bf16 (half the gather bytes). Everything else = round 8.

#define NGRAPH 128
#define NPG    512
#define NN     (NGRAPH*NPG)   // 65536
#define KNB    7

constexpr double AVG_DEG_LOG_D = 2.0239670479173344;  // (100*ln6+200*ln7+700*ln8)/1000
constexpr double LOG8_D        = 2.0794415416798357;

#define FMA4(A_, P_, W_) { (A_).x += (P_)*(W_).x; (A_).y += (P_)*(W_).y; (A_).z += (P_)*(W_).z; (A_).w += (P_)*(W_).w; }

typedef short bf16x8 __attribute__((ext_vector_type(8)));
typedef float f32x4  __attribute__((ext_vector_type(4)));

__device__ __forceinline__ unsigned short f2bf(float x) {   // RNE, finite inputs
    unsigned u = __float_as_uint(x);
    return (unsigned short)((u + 0x7fffu + ((u >> 16) & 1u)) >> 16);
}
__device__ __forceinline__ float bf2f(unsigned short u) {
    return __uint_as_float(((unsigned)u) << 16);
}

// ---------------------------------------------------------------- weight prep
__global__ __launch_bounds__(256) void prep_kernel(
    const float* __restrict__ Wpost1, const float* __restrict__ Wpost2,
    const float* __restrict__ Wpre2,  const float* __restrict__ Wlin2,
    const float* __restrict__ bpost2, const float* __restrict__ blin2,
    float* __restrict__ Weff1, unsigned short* __restrict__ Wfuv,
    unsigned short* __restrict__ Wfp, unsigned short* __restrict__ Wfl,
    float* __restrict__ blin_eff)
{
    const float AMP = (float)(LOG8_D / AVG_DEG_LOG_D);
    const float ATT = (float)(AVG_DEG_LOG_D / LOG8_D);
    for (int i = blockIdx.x*256 + threadIdx.x; i < 92800; i += gridDim.x*256) {
        if (i < 2560) {
            // Weff1 [4][40][16]
            int t = i / 640, r = i % 640, g = r >> 4, fo = r & 15;
            float val;
            if (g < 8) val = Wpost1[(t*104 + g)*16 + fo];
            else {
                int g2 = g - 8;
                val = Wpost1[(t*104 +  8 + g2)*16 + fo]
                    + AMP*Wpost1[(t*104 + 40 + g2)*16 + fo]
                    + ATT*Wpost1[(t*104 + 72 + g2)*16 + fo];
            }
            Weff1[i] = val;
        } else if (i < 35328) {
            // Wfuv: [kk<2][ct<32][lane<64][j<8] bf16; col = ct*16+(lane&15) in [0,512) = u||v
            int jj = i - 2560;
            int kk = jj >> 14, ct = (jj >> 9) & 31, lane = (jj >> 3) & 63, jf = jj & 7;
            int k   = kk*32 + (lane >> 4)*8 + jf;
            int col = ct*16 + (lane & 15);
            float val;
            if (col < 256) { int t = col >> 6, f = col & 63; val = Wpre2[(t*128 +      k)*64 + f]; }
            else { int c2 = col - 256; int t = c2 >> 6, f = c2 & 63; val = Wpre2[(t*128 + 64 + k)*64 + f]; }
            Wfuv[jj] = f2bf(val);
        } else if (i < 76288) {
            // Wfrag_post: [t][kk<10][c<2][lane<64][j<8], bf16
            int jj = i - 35328;
            int t = jj / 10240, r = jj % 10240;
            int kk = r / 1024, r2 = r % 1024;
            int c = r2 >> 9, lane = (r2 >> 3) & 63, jf = r2 & 7;
            int G   = kk*32 + (lane >> 4)*8 + jf;
            int col = c*16 + (lane & 15);
            float val;
            if (G < 64) val = Wpost2[(t*832 + G)*32 + col];
            else {
                int g2 = G - 64;
                val = Wpost2[(t*832 +  64 + g2)*32 + col]
                    + AMP*Wpost2[(t*832 + 320 + g2)*32 + col]
                    + ATT*Wpost2[(t*832 + 576 + g2)*32 + col];
            }
            Wfp[jj] = f2bf(val);
        } else if (i < 92672) {
            // Wfrag_lin: [kk<4][tile<8][lane<64][j<8], bf16
            int jj = i - 76288;
            int kk = jj / 4096, r = jj % 4096;
            int tile = r >> 9, lane = (r >> 3) & 63, jf = r & 7;
            int k   = kk*32 + (lane >> 4)*8 + jf;
            int col = tile*16 + (lane & 15);
            Wfl[jj] = f2bf(Wlin2[k*128 + col]);
        } else {
            // blin_eff[c] = blin2[c] + sum_o bpost2[o]*Wlin2[o][c]
            int c = i - 92672;
            float s = blin2[c];
            for (int o = 0; o < 128; ++o) s += bpost2[o]*Wlin2[o*128 + c];
            blin_eff[c] = s;
        }
    }
}

// ---------------------------------------------------------------- kNN (k=7); 2 blocks per graph
__global__ __launch_bounds__(256) void knn_kernel(const float* __restrict__ pos, int* __restrict__ nbr)
{
    __shared__ float4 posS[NPG];
    const int g    = blockIdx.x >> 1;
    const int half = blockIdx.x & 1;
    const int gb   = g * NPG;
    for (int j = threadIdx.x; j < NPG; j += 256)
        posS[j] = make_float4(pos[(gb+j)*3+0], pos[(gb+j)*3+1], pos[(gb+j)*3+2], 0.f);
    __syncthreads();
    const int i = half*256 + threadIdx.x;
    const float4 pi = posS[i];
    float bd[KNB]; int bi[KNB];
#pragma unroll
    for (int e = 0; e < KNB; ++e) { bd[e] = 3.0e38f; bi[e] = -1; }
#pragma unroll 4
    for (int j = 0; j < NPG; ++j) {
        float4 pj = posS[j];
        float dx = pi.x - pj.x, dy = pi.y - pj.y, dz = pi.z - pj.z;
        float d2 = __fadd_rn(__fadd_rn(__fmul_rn(dx,dx), __fmul_rn(dy,dy)), __fmul_rn(dz,dz));
        if (j == i) d2 = __builtin_inff();
        bool cmp[KNB];
#pragma unroll
        for (int e = 0; e < KNB; ++e) cmp[e] = d2 < bd[e];
#pragma unroll
        for (int e = KNB-1; e >= 1; --e) {
            bd[e] = cmp[e-1] ? bd[e-1] : (cmp[e] ? d2 : bd[e]);
            bi[e] = cmp[e-1] ? bi[e-1] : (cmp[e] ? j  : bi[e]);
        }
        bd[0] = cmp[0] ? d2 : bd[0];
        bi[0] = cmp[0] ? j  : bi[0];
    }
#pragma unroll
    for (int e = 0; e < KNB; ++e) nbr[(gb+i)*KNB + e] = gb + bi[e];
}

// ---------------------------------------------------------------- layer1: u1,v1 [N,32]
__global__ __launch_bounds__(256) void a1_kernel(
    const float* __restrict__ x, const float* __restrict__ Wpre1, const float* __restrict__ bpre1,
    float* __restrict__ u1, float* __restrict__ v1)
{
    __shared__ float wS[512];
    __shared__ float bS[32];
    const int tid = threadIdx.x;
    wS[tid] = Wpre1[tid]; wS[tid+256] = Wpre1[tid+256];
    if (tid < 32) bS[tid] = bpre1[tid];
    __syncthreads();
    const int n  = blockIdx.x*8 + (tid>>5);
    const int tf = tid & 31;
    const int t = tf >> 3, f = tf & 7;
    float u = bS[tf], v = 0.f;
#pragma unroll
    for (int e = 0; e < 8; ++e) {
        float xv = x[n*8+e];
        u += xv * wS[(t*16 + e)*8 + f];
        v += xv * wS[(t*16 + 8 + e)*8 + f];
    }
    u1[n*32+tf] = u;
    v1[n*32+tf] = v;
}

// ---------------------------------------------------------------- layer1 fused: agg + post + lin -> y1 [N,64]
__global__ __launch_bounds__(256) void b1_kernel(
    const float* __restrict__ x, const int* __restrict__ nbr,
    const float* __restrict__ u1, const float* __restrict__ v1,
    const float* __restrict__ Weff1, const float* __restrict__ bpost1,
    const float* __restrict__ Wlin1, const float* __restrict__ blin1,
    float* __restrict__ y1)
{
    __shared__ int   nbrsS[16*7];
    __shared__ float xsS[16*8];
    __shared__ float aggS[64*41];
    __shared__ float postS[16*68];
    const int tid  = threadIdx.x;
    const int base = blockIdx.x * 16;
    if (tid < 112) nbrsS[tid] = nbr[base*7 + tid];
    if (tid < 128) xsS[tid]   = x[base*8 + tid];
    __syncthreads();
#pragma unroll
    for (int it = 0; it < 2; ++it) {
        int task = tid + 256*it;
        int ln = task >> 5, tf = task & 31;
        float u = u1[(base+ln)*32 + tf];
        float s = 0.f, s2 = 0.f, mn = 3e38f, mx = -3e38f;
#pragma unroll
        for (int e = 0; e < 7; ++e) {
            float vv = v1[nbrsS[ln*7+e]*32 + tf];
            s += vv; s2 += vv*vv; mn = fminf(mn, vv); mx = fmaxf(mx, vv);
        }
        float mean = s * (1.f/7.f);
        float var  = s2 * (1.f/7.f) - mean*mean;
        float sd   = sqrtf(fmaxf(var, 0.f) + 1e-5f);
        int t = tf >> 3, f = tf & 7;
        int bo = (ln*4 + t)*41 + f;
        aggS[bo]    = u + mean;
        aggS[bo+8]  = u + mn;
        aggS[bo+16] = u + mx;
        aggS[bo+24] = sd;
    }
    __syncthreads();
    {   // post-MLP
        int ln = tid >> 4, q = tid & 15;
        int t = q >> 2, fo4 = (q & 3) * 4;
        float4 acc = *(const float4*)&bpost1[t*16 + fo4];
#pragma unroll
        for (int g = 0; g < 8; ++g) {
            float p = xsS[ln*8+g];
            float4 wv4 = *(const float4*)&Weff1[(t*40 + g)*16 + fo4];
            FMA4(acc, p, wv4)
        }
#pragma unroll 8
        for (int g = 0; g < 32; ++g) {
            float p = aggS[(ln*4 + t)*41 + g];
            float4 wv4 = *(const float4*)&Weff1[(t*40 + 8 + g)*16 + fo4];
            FMA4(acc, p, wv4)
        }
        *(float4*)&postS[ln*68 + t*16 + fo4] = acc;
    }
    __syncthreads();
    {   // mixing linear
        int ln = tid >> 4, q = tid & 15;
        int c4 = q*4;
        float4 acc = *(const float4*)&blin1[c4];
#pragma unroll 8
        for (int o = 0; o < 64; ++o) {
            float p = postS[ln*68 + o];
            float4 wv4 = *(const float4*)&Wlin1[o*64 + c4];
            FMA4(acc, p, wv4)
        }
        *(float4*)&y1[(base+ln)*64 + c4] = acc;
    }
}

// ---------------------------------------------------------------- BN stats partials (no atomics)
template<int C, int LOGC>
__global__ __launch_bounds__(256) void bn_stats_kernel(
    const float* __restrict__ y, float* __restrict__ Ps, float* __restrict__ Pq)
{
    __shared__ float sS[256], qS[256];
    const int tid = threadIdx.x;
    const int c  = tid & (C-1);
    const int rg = tid >> LOGC;
    const int G  = 256 >> LOGC;
    const int ROWS = NN/128;
    const int rowBase = blockIdx.x * ROWS;
    float s = 0.f, q = 0.f;
    for (int r = rg; r < ROWS; r += G) {
        float v = y[(rowBase + r)*C + c];
        s += v; q += v*v;
    }
    sS[tid] = s; qS[tid] = q;
    __syncthreads();
    if (rg == 0) {
        for (int g2 = 1; g2 < G; ++g2) { s += sS[g2*C + c]; q += qS[g2*C + c]; }
        Ps[blockIdx.x*C + c] = s;
        Pq[blockIdx.x*C + c] = q;
    }
}

// ---------------------------------------------------------------- finalize BN -> scale/shift
template<int C>
__global__ __launch_bounds__(C) void fin_kernel(
    const float* __restrict__ Ps, const float* __restrict__ Pq,
    const float* __restrict__ g, const float* __restrict__ b,
    float* __restrict__ scO, float* __restrict__ shO)
{
    const int c = threadIdx.x;
    float s = 0.f, q = 0.f;
#pragma unroll 8
    for (int i = 0; i < 128; ++i) { s += Ps[i*C + c]; q += Pq[i*C + c]; }
    const float inv = 1.f/(float)NN;
    float mu  = s*inv;
    float var = q*inv - mu*mu;
    float sc  = g[c]*rsqrtf(var + 1e-5f);
    scO[c] = sc;
    shO[c] = b[c] - mu*sc;
}

// ---------------------------------------------------------------- layer2 pre (MFMA): uv2 [N][512] bf16 = [u||v]
// 64 nodes/block, wave w = row-tile of 16 nodes. A-frags loaded once, 32 col-tiles.
__global__ __launch_bounds__(256) void a2_kernel(
    const float* __restrict__ y1raw, const float* __restrict__ sc1, const float* __restrict__ sh1,
    const unsigned short* __restrict__ Wfuv, const float* __restrict__ bpre2,
    unsigned short* __restrict__ uv2)
{
    __shared__ __align__(16) unsigned short a1S[64*72];   // 64 nodes x 64 bf16, pitch 72
    __shared__ float biasS[256];
    const int tid  = threadIdx.x;
    const int base = blockIdx.x * 64;
    biasS[tid] = bpre2[tid];
#pragma unroll
    for (int it = 0; it < 4; ++it) {
        int i = tid + it*256;                       // over 1024 float4 = 64 rows x 16 f4
        float4 vv = ((const float4*)y1raw)[blockIdx.x*1024 + i];
        int n = i >> 4, c0 = (i & 15)*4;
        float c_[4] = {vv.x, vv.y, vv.z, vv.w};
#pragma unroll
        for (int j = 0; j < 4; ++j) {
            int c = c0 + j;
            a1S[n*72 + c] = f2bf(fmaxf(c_[j]*sc1[c] + sh1[c], 0.f));
        }
    }
    __syncthreads();
    const int l = tid & 63, w = tid >> 6;
    const int lr = l & 15, lk = l >> 4;
    const bf16x8 a0  = *(const bf16x8*)&a1S[(w*16 + lr)*72 +      lk*8];
    const bf16x8 a1f = *(const bf16x8*)&a1S[(w*16 + lr)*72 + 32 + lk*8];
    const bf16x8* WB = (const bf16x8*)Wfuv;
#pragma unroll 4
    for (int ct = 0; ct < 32; ++ct) {
        f32x4 acc = {0.f,0.f,0.f,0.f};
        bf16x8 b0 = WB[ct*64 + l];
        bf16x8 b1 = WB[(32 + ct)*64 + l];
        acc = __builtin_amdgcn_mfma_f32_16x16x32_bf16(a0,  b0, acc, 0, 0, 0);
        acc = __builtin_amdgcn_mfma_f32_16x16x32_bf16(a1f, b1, acc, 0, 0, 0);
        const int col = ct*16 + lr;
        const float bias = (ct < 16) ? biasS[col] : 0.f;
#pragma unroll
        for (int j = 0; j < 4; ++j)
            uv2[(base + w*16 + lk*4 + j)*512 + col] = f2bf(acc[j] + bias);
    }
}

// ---------------------------------------------------------------- layer2 fused (MFMA): agg + post + lin -> y2 [N,128]
__global__ __launch_bounds__(256) void b2_kernel(
    const int* __restrict__ nbr, const float* __restrict__ y1raw,
    const float* __restrict__ sc1, const float* __restrict__ sh1,
    const unsigned short* __restrict__ uv2,
    const unsigned short* __restrict__ Wfp, const unsigned short* __restrict__ Wfl,
    const float* __restrict__ blin_eff,
    float* __restrict__ y2)
{
    __shared__ int nbrsS[112];
    __shared__ __align__(16) unsigned short a1S[16*72];     // 16 nodes x 64 a1 (bf16), pitch 72
    __shared__ __align__(16) unsigned short aggS[64*264];   // rows (t*16+n), 256 agg vals, pitch 264
    __shared__ __align__(16) unsigned short postS[16*136];  // 16 nodes x 128 post (bf16), pitch 136

    const int tid = threadIdx.x;
    // XCD-affine swizzle: 32 blocks/graph, graph -> XCD (graph & 7)
    const int ob   = blockIdx.x;
    const int xcd  = ob & 7, slot = ob >> 3;
    const int gph  = ((slot >> 5) << 3) + xcd;
    const int sub  = slot & 31;
    const int base = gph*NPG + sub*16;

    if (tid < 112) nbrsS[tid] = nbr[base*7 + tid];
    for (int i = tid; i < 1024; i += 256) {
        int c = i & 63, n = i >> 6;
        float a = fmaxf(y1raw[base*64 + i]*sc1[c] + sh1[c], 0.f);
        a1S[n*72 + c] = f2bf(a);
    }
    __syncthreads();
    // ---- aggregation: 7-neighbor mean/min/max/std from bf16 uv2, fp32 math
    {
        const int t = tid >> 6, f = tid & 63;
        for (int ln = 0; ln < 16; ++ln) {
            float u = bf2f(uv2[(base+ln)*512 + tid]);
            float s = 0.f, s2 = 0.f, mn = 3e38f, mx = -3e38f;
#pragma unroll
            for (int e = 0; e < 7; ++e) {
                float vv = bf2f(uv2[nbrsS[ln*7+e]*512 + 256 + tid]);
                s += vv; s2 += vv*vv; mn = fminf(mn, vv); mx = fmaxf(mx, vv);
            }
            float mean = s * (1.f/7.f);
            float var  = s2 * (1.f/7.f) - mean*mean;
            float sd   = sqrtf(fmaxf(var, 0.f) + 1e-5f);
            const int ro = (t*16 + ln)*264;
            aggS[ro +       f] = f2bf(u + mean);
            aggS[ro +  64 + f] = f2bf(u + mn);
            aggS[ro + 128 + f] = f2bf(u + mx);
            aggS[ro + 192 + f] = f2bf(sd);
        }
    }
    __syncthreads();
    const int l = tid & 63, w = tid >> 6;
    const int lr = l & 15, lk = l >> 4;
    // ---- post GEMM (tower w): K=320 = 2 a1-chunks + 8 agg-chunks
    f32x4 acc0 = {0.f,0.f,0.f,0.f}, acc1 = {0.f,0.f,0.f,0.f};
    {
        const bf16x8* WB = (const bf16x8*)Wfp;
#pragma unroll
        for (int kk = 0; kk < 10; ++kk) {
            bf16x8 a;
            if (kk < 2) a = *(const bf16x8*)&a1S[lr*72 + kk*32 + lk*8];
            else        a = *(const bf16x8*)&aggS[(w*16 + lr)*264 + (kk-2)*32 + lk*8];
            bf16x8 b0 = WB[((w*10 + kk)*2 + 0)*64 + l];
            bf16x8 b1 = WB[((w*10 + kk)*2 + 1)*64 + l];
            acc0 = __builtin_amdgcn_mfma_f32_16x16x32_bf16(a, b0, acc0, 0, 0, 0);
            acc1 = __builtin_amdgcn_mfma_f32_16x16x32_bf16(a, b1, acc1, 0, 0, 0);
        }
    }
#pragma unroll
    for (int j = 0; j < 4; ++j) {
        const int row = lk*4 + j;
        postS[row*136 + w*32 +      lr] = f2bf(acc0[j]);
        postS[row*136 + w*32 + 16 + lr] = f2bf(acc1[j]);
    }
    __syncthreads();
    // ---- lin GEMM (cols 32w..32w+31): K=128
    f32x4 d0 = {0.f,0.f,0.f,0.f}, d1 = {0.f,0.f,0.f,0.f};
    {
        const bf16x8* WB = (const bf16x8*)Wfl;
#pragma unroll
        for (int kk = 0; kk < 4; ++kk) {
            bf16x8 a = *(const bf16x8*)&postS[lr*136 + kk*32 + lk*8];
            bf16x8 b0 = WB[(kk*8 + 2*w + 0)*64 + l];
            bf16x8 b1 = WB[(kk*8 + 2*w + 1)*64 + l];
            d0 = __builtin_amdgcn_mfma_f32_16x16x32_bf16(a, b0, d0, 0, 0, 0);
            d1 = __builtin_amdgcn_mfma_f32_16x16x32_bf16(a, b1, d1, 0, 0, 0);
        }
    }
    const float be0 = blin_eff[w*32 +      lr];
    const float be1 = blin_eff[w*32 + 16 + lr];
#pragma unroll
    for (int j = 0; j < 4; ++j) {
        const int row = lk*4 + j;
        y2[(base + row)*128 + w*32 +      lr] = d0[j] + be0;
        y2[(base + row)*128 + w*32 + 16 + lr] = d1[j] + be1;
    }
}

// ---------------------------------------------------------------- BN2(precomputed) + relu + per-graph mean pool
__global__ __launch_bounds__(128) void pool_kernel(
    const float* __restrict__ y2, const float* __restrict__ sc2, const float* __restrict__ sh2,
    float* __restrict__ out)
{
    const int c = threadIdx.x;
    const int g = blockIdx.x;
    const float sc = sc2[c];
    const float sh = sh2[c];
    float acc = 0.f;
    const int baseIdx = g*NPG*128 + c;
#pragma unroll 4
    for (int i = 0; i < NPG; ++i) {
        float v = y2[baseIdx + i*128];
        acc += fmaxf(v*sc + sh, 0.f);
    }
    out[g*128 + c] = acc * (1.f/(float)NPG);
}

// ---------------------------------------------------------------- launcher
extern "C" void kernel_launch(void* const* d_in, const int* in_sizes, int n_in,
                              void* d_out, int out_size, void* d_ws, size_t ws_size,
                              hipStream_t stream)
{
    const float* x      = (const float*)d_in[0];
    const float* pos    = (const float*)d_in[1];
    const float* Wpre1  = (const float*)d_in[2];
    const float* bpre1  = (const float*)d_in[3];
    const float* Wpost1 = (const float*)d_in[4];
    const float* bpost1 = (const float*)d_in[5];
    const float* Wlin1  = (const float*)d_in[6];
    const float* blin1  = (const float*)d_in[7];
    const float* bn1g   = (const float*)d_in[8];
    const float* bn1b   = (const float*)d_in[9];
    const float* Wpre2  = (const float*)d_in[10];
    const float* bpre2  = (const float*)d_in[11];
    const float* Wpost2 = (const float*)d_in[12];
    const float* bpost2 = (const float*)d_in[13];
    const float* Wlin2  = (const float*)d_in[14];
    const float* blin2  = (const float*)d_in[15];
    const float* bn2g   = (const float*)d_in[16];
    const float* bn2b   = (const float*)d_in[17];
    float* out = (float*)d_out;

    char* ws = (char*)d_ws;
    size_t off = 0;
    auto alloc = [&](size_t bytes) { void* p = ws + off; off += (bytes + 255) & ~(size_t)255; return p; };
    int*   nbr   = (int*)  alloc((size_t)NN*7*4);
    float* u1    = (float*)alloc((size_t)NN*32*4);
    float* v1    = (float*)alloc((size_t)NN*32*4);
    float* y1    = (float*)alloc((size_t)NN*64*4);            // raw (pre-BN)
    unsigned short* uv2 = (unsigned short*)alloc((size_t)NN*512*2);   // bf16 [u||v]
    float* y2    = (float*)alloc((size_t)NN*128*4);           // raw (pre-BN)
    float* Weff1 = (float*)alloc(2560*4);
    unsigned short* Wfuv = (unsigned short*)alloc(32768*2);
    unsigned short* Wfp  = (unsigned short*)alloc(40960*2);
    unsigned short* Wfl  = (unsigned short*)alloc(16384*2);
    float* blin_eff = (float*)alloc(128*4);
    float* P1s   = (float*)alloc(128*64*4);
    float* P1q   = (float*)alloc(128*64*4);
    float* sc1   = (float*)alloc(64*4);
    float* sh1   = (float*)alloc(64*4);
    float* P2s   = (float*)alloc(128*128*4);
    float* P2q   = (float*)alloc(128*128*4);
    float* sc2   = (float*)alloc(128*4);
    float* sh2   = (float*)alloc(128*4);

    prep_kernel<<<128, 256, 0, stream>>>(Wpost1, Wpost2, Wpre2, Wlin2, bpost2, blin2,
                                         Weff1, Wfuv, Wfp, Wfl, blin_eff);
    knn_kernel<<<NGRAPH*2, 256, 0, stream>>>(pos, nbr);
    a1_kernel<<<NN/8, 256, 0, stream>>>(x, Wpre1, bpre1, u1, v1);
    b1_kernel<<<NN/16, 256, 0, stream>>>(x, nbr, u1, v1, Weff1, bpost1, Wlin1, blin1, y1);
    bn_stats_kernel<64,6><<<128, 256, 0, stream>>>(y1, P1s, P1q);
    fin_kernel<64><<<1, 64, 0, stream>>>(P1s, P1q, bn1g, bn1b, sc1, sh1);
    a2_kernel<<<NN/64, 256, 0, stream>>>(y1, sc1, sh1, Wfuv, bpre2, uv2);
    b2_kernel<<<NN/16, 256, 0, stream>>>(nbr, y1, sc1, sh1, uv2, Wfp, Wfl, blin_eff, y2);
    bn_stats_kernel<128,7><<<128, 256, 0, stream>>>(y2, P2s, P2q);
    fin_kernel<128><<<1, 128, 0, stream>>>(P2s, P2q, bn2g, bn2b, sc2, sh2);
    pool_kernel<<<NGRAPH, 128, 0, stream>>>(y2, sc2, sh2, out);
}

// Round 10
// 233.153 us; speedup vs baseline: 2.3714x; 1.4746x over previous
//
#include <hip/hip_runtime.h>
#include <math.h>

// PNANet on MI355X, round 10: fix latency-starved reductions.
//  * bn_stats: 128 -> 1024 blocks, float4 loads, LDS tree, partials (was 68us @ 4.8% occ).
//  * 2-level finalize (finA 64 blocks -> fin).
//  * pool: split into pool_part (1024 blocks) + pool_fin.
//  * b1/b2/a2/knn/a1 untouched from round 9.

#define NGRAPH 128
#define NPG    512
#define NN     (NGRAPH*NPG)   // 65536
#define KNB    7

constexpr double AVG_DEG_LOG_D = 2.0239670479173344;  // (100*ln6+200*ln7+700*ln8)/1000
constexpr double LOG8_D        = 2.0794415416798357;

#define FMA4(A_, P_, W_) { (A_).x += (P_)*(W_).x; (A_).y += (P_)*(W_).y; (A_).z += (P_)*(W_).z; (A_).w += (P_)*(W_).w; }

typedef short bf16x8 __attribute__((ext_vector_type(8)));
typedef float f32x4  __attribute__((ext_vector_type(4)));

__device__ __forceinline__ unsigned short f2bf(float x) {   // RNE, finite inputs
    unsigned u = __float_as_uint(x);
    return (unsigned short)((u + 0x7fffu + ((u >> 16) & 1u)) >> 16);
}
__device__ __forceinline__ float bf2f(unsigned short u) {
    return __uint_as_float(((unsigned)u) << 16);
}

// ---------------------------------------------------------------- weight prep
__global__ __launch_bounds__(256) void prep_kernel(
    const float* __restrict__ Wpost1, const float* __restrict__ Wpost2,
    const float* __restrict__ Wpre2,  const float* __restrict__ Wlin2,
    const float* __restrict__ bpost2, const float* __restrict__ blin2,
    float* __restrict__ Weff1, unsigned short* __restrict__ Wfuv,
    unsigned short* __restrict__ Wfp, unsigned short* __restrict__ Wfl,
    float* __restrict__ blin_eff)
{
    const float AMP = (float)(LOG8_D / AVG_DEG_LOG_D);
    const float ATT = (float)(AVG_DEG_LOG_D / LOG8_D);
    for (int i = blockIdx.x*256 + threadIdx.x; i < 92800; i += gridDim.x*256) {
        if (i < 2560) {
            // Weff1 [4][40][16]
            int t = i / 640, r = i % 640, g = r >> 4, fo = r & 15;
            float val;
            if (g < 8) val = Wpost1[(t*104 + g)*16 + fo];
            else {
                int g2 = g - 8;
                val = Wpost1[(t*104 +  8 + g2)*16 + fo]
                    + AMP*Wpost1[(t*104 + 40 + g2)*16 + fo]
                    + ATT*Wpost1[(t*104 + 72 + g2)*16 + fo];
            }
            Weff1[i] = val;
        } else if (i < 35328) {
            // Wfuv: [kk<2][ct<32][lane<64][j<8] bf16; col = ct*16+(lane&15) in [0,512) = u||v
            int jj = i - 2560;
            int kk = jj >> 14, ct = (jj >> 9) & 31, lane = (jj >> 3) & 63, jf = jj & 7;
            int k   = kk*32 + (lane >> 4)*8 + jf;
            int col = ct*16 + (lane & 15);
            float val;
            if (col < 256) { int t = col >> 6, f = col & 63; val = Wpre2[(t*128 +      k)*64 + f]; }
            else { int c2 = col - 256; int t = c2 >> 6, f = c2 & 63; val = Wpre2[(t*128 + 64 + k)*64 + f]; }
            Wfuv[jj] = f2bf(val);
        } else if (i < 76288) {
            // Wfrag_post: [t][kk<10][c<2][lane<64][j<8], bf16
            int jj = i - 35328;
            int t = jj / 10240, r = jj % 10240;
            int kk = r / 1024, r2 = r % 1024;
            int c = r2 >> 9, lane = (r2 >> 3) & 63, jf = r2 & 7;
            int G   = kk*32 + (lane >> 4)*8 + jf;
            int col = c*16 + (lane & 15);
            float val;
            if (G < 64) val = Wpost2[(t*832 + G)*32 + col];
            else {
                int g2 = G - 64;
                val = Wpost2[(t*832 +  64 + g2)*32 + col]
                    + AMP*Wpost2[(t*832 + 320 + g2)*32 + col]
                    + ATT*Wpost2[(t*832 + 576 + g2)*32 + col];
            }
            Wfp[jj] = f2bf(val);
        } else if (i < 92672) {
            // Wfrag_lin: [kk<4][tile<8][lane<64][j<8], bf16
            int jj = i - 76288;
            int kk = jj / 4096, r = jj % 4096;
            int tile = r >> 9, lane = (r >> 3) & 63, jf = r & 7;
            int k   = kk*32 + (lane >> 4)*8 + jf;
            int col = tile*16 + (lane & 15);
            Wfl[jj] = f2bf(Wlin2[k*128 + col]);
        } else {
            // blin_eff[c] = blin2[c] + sum_o bpost2[o]*Wlin2[o][c]
            int c = i - 92672;
            float s = blin2[c];
            for (int o = 0; o < 128; ++o) s += bpost2[o]*Wlin2[o*128 + c];
            blin_eff[c] = s;
        }
    }
}

// ---------------------------------------------------------------- kNN (k=7); 2 blocks per graph
__global__ __launch_bounds__(256) void knn_kernel(const float* __restrict__ pos, int* __restrict__ nbr)
{
    __shared__ float4 posS[NPG];
    const int g    = blockIdx.x >> 1;
    const int half = blockIdx.x & 1;
    const int gb   = g * NPG;
    for (int j = threadIdx.x; j < NPG; j += 256)
        posS[j] = make_float4(pos[(gb+j)*3+0], pos[(gb+j)*3+1], pos[(gb+j)*3+2], 0.f);
    __syncthreads();
    const int i = half*256 + threadIdx.x;
    const float4 pi = posS[i];
    float bd[KNB]; int bi[KNB];
#pragma unroll
    for (int e = 0; e < KNB; ++e) { bd[e] = 3.0e38f; bi[e] = -1; }
#pragma unroll 4
    for (int j = 0; j < NPG; ++j) {
        float4 pj = posS[j];
        float dx = pi.x - pj.x, dy = pi.y - pj.y, dz = pi.z - pj.z;
        float d2 = __fadd_rn(__fadd_rn(__fmul_rn(dx,dx), __fmul_rn(dy,dy)), __fmul_rn(dz,dz));
        if (j == i) d2 = __builtin_inff();
        bool cmp[KNB];
#pragma unroll
        for (int e = 0; e < KNB; ++e) cmp[e] = d2 < bd[e];
#pragma unroll
        for (int e = KNB-1; e >= 1; --e) {
            bd[e] = cmp[e-1] ? bd[e-1] : (cmp[e] ? d2 : bd[e]);
            bi[e] = cmp[e-1] ? bi[e-1] : (cmp[e] ? j  : bi[e]);
        }
        bd[0] = cmp[0] ? d2 : bd[0];
        bi[0] = cmp[0] ? j  : bi[0];
    }
#pragma unroll
    for (int e = 0; e < KNB; ++e) nbr[(gb+i)*KNB + e] = gb + bi[e];
}

// ---------------------------------------------------------------- layer1: u1,v1 [N,32]
__global__ __launch_bounds__(256) void a1_kernel(
    const float* __restrict__ x, const float* __restrict__ Wpre1, const float* __restrict__ bpre1,
    float* __restrict__ u1, float* __restrict__ v1)
{
    __shared__ float wS[512];
    __shared__ float bS[32];
    const int tid = threadIdx.x;
    wS[tid] = Wpre1[tid]; wS[tid+256] = Wpre1[tid+256];
    if (tid < 32) bS[tid] = bpre1[tid];
    __syncthreads();
    const int n  = blockIdx.x*8 + (tid>>5);
    const int tf = tid & 31;
    const int t = tf >> 3, f = tf & 7;
    float u = bS[tf], v = 0.f;
#pragma unroll
    for (int e = 0; e < 8; ++e) {
        float xv = x[n*8+e];
        u += xv * wS[(t*16 + e)*8 + f];
        v += xv * wS[(t*16 + 8 + e)*8 + f];
    }
    u1[n*32+tf] = u;
    v1[n*32+tf] = v;
}

// ---------------------------------------------------------------- layer1 fused: agg + post + lin -> y1 [N,64]
__global__ __launch_bounds__(256) void b1_kernel(
    const float* __restrict__ x, const int* __restrict__ nbr,
    const float* __restrict__ u1, const float* __restrict__ v1,
    const float* __restrict__ Weff1, const float* __restrict__ bpost1,
    const float* __restrict__ Wlin1, const float* __restrict__ blin1,
    float* __restrict__ y1)
{
    __shared__ int   nbrsS[16*7];
    __shared__ float xsS[16*8];
    __shared__ float aggS[64*41];
    __shared__ float postS[16*68];
    const int tid  = threadIdx.x;
    const int base = blockIdx.x * 16;
    if (tid < 112) nbrsS[tid] = nbr[base*7 + tid];
    if (tid < 128) xsS[tid]   = x[base*8 + tid];
    __syncthreads();
#pragma unroll
    for (int it = 0; it < 2; ++it) {
        int task = tid + 256*it;
        int ln = task >> 5, tf = task & 31;
        float u = u1[(base+ln)*32 + tf];
        float s = 0.f, s2 = 0.f, mn = 3e38f, mx = -3e38f;
#pragma unroll
        for (int e = 0; e < 7; ++e) {
            float vv = v1[nbrsS[ln*7+e]*32 + tf];
            s += vv; s2 += vv*vv; mn = fminf(mn, vv); mx = fmaxf(mx, vv);
        }
        float mean = s * (1.f/7.f);
        float var  = s2 * (1.f/7.f) - mean*mean;
        float sd   = sqrtf(fmaxf(var, 0.f) + 1e-5f);
        int t = tf >> 3, f = tf & 7;
        int bo = (ln*4 + t)*41 + f;
        aggS[bo]    = u + mean;
        aggS[bo+8]  = u + mn;
        aggS[bo+16] = u + mx;
        aggS[bo+24] = sd;
    }
    __syncthreads();
    {   // post-MLP
        int ln = tid >> 4, q = tid & 15;
        int t = q >> 2, fo4 = (q & 3) * 4;
        float4 acc = *(const float4*)&bpost1[t*16 + fo4];
#pragma unroll
        for (int g = 0; g < 8; ++g) {
            float p = xsS[ln*8+g];
            float4 wv4 = *(const float4*)&Weff1[(t*40 + g)*16 + fo4];
            FMA4(acc, p, wv4)
        }
#pragma unroll 8
        for (int g = 0; g < 32; ++g) {
            float p = aggS[(ln*4 + t)*41 + g];
            float4 wv4 = *(const float4*)&Weff1[(t*40 + 8 + g)*16 + fo4];
            FMA4(acc, p, wv4)
        }
        *(float4*)&postS[ln*68 + t*16 + fo4] = acc;
    }
    __syncthreads();
    {   // mixing linear
        int ln = tid >> 4, q = tid & 15;
        int c4 = q*4;
        float4 acc = *(const float4*)&blin1[c4];
#pragma unroll 8
        for (int o = 0; o < 64; ++o) {
            float p = postS[ln*68 + o];
            float4 wv4 = *(const float4*)&Wlin1[o*64 + c4];
            FMA4(acc, p, wv4)
        }
        *(float4*)&y1[(base+ln)*64 + c4] = acc;
    }
}

// ---------------------------------------------------------------- BN stats: 1024 blocks, float4, LDS tree -> partials
template<int C>
__global__ __launch_bounds__(256) void bn_stats_kernel(
    const float* __restrict__ y, float* __restrict__ Ps, float* __restrict__ Pq)
{
    constexpr int IT     = (NN/1024)*(C/4)/256;   // C=64 -> 4, C=128 -> 8
    constexpr int GROUPS = C/4;                    // threads sharing a c0
    constexpr int REPS   = 256/GROUPS;
    const int tid = threadIdx.x;
    const float4* y4 = (const float4*)y + (size_t)blockIdx.x*256*IT;
    float4 s = make_float4(0.f,0.f,0.f,0.f), q = make_float4(0.f,0.f,0.f,0.f);
#pragma unroll
    for (int it = 0; it < IT; ++it) {
        float4 v = y4[it*256 + tid];
        s.x += v.x; s.y += v.y; s.z += v.z; s.w += v.w;
        q.x += v.x*v.x; q.y += v.y*v.y; q.z += v.z*v.z; q.w += v.w*v.w;
    }
    __shared__ float4 sS[256], qS[256];
    sS[tid] = s; qS[tid] = q;
    __syncthreads();
#pragma unroll
    for (int step = REPS/2; step >= 1; step >>= 1) {
        if (tid < step*GROUPS) {
            float4 s2 = sS[tid + step*GROUPS], q2 = qS[tid + step*GROUPS];
            float4 ss = sS[tid], qq = qS[tid];
            ss.x += s2.x; ss.y += s2.y; ss.z += s2.z; ss.w += s2.w;
            qq.x += q2.x; qq.y += q2.y; qq.z += q2.z; qq.w += q2.w;
            sS[tid] = ss; qS[tid] = qq;
        }
        __syncthreads();
    }
    if (tid < GROUPS) {
        ((float4*)&Ps[(size_t)blockIdx.x*C])[tid] = sS[tid];
        ((float4*)&Pq[(size_t)blockIdx.x*C])[tid] = qS[tid];
    }
}

// ---------------------------------------------------------------- finA: 64 blocks, sum 16 partial-rows
template<int C>
__global__ __launch_bounds__(C) void finA_kernel(
    const float* __restrict__ Ps, const float* __restrict__ Pq,
    float* __restrict__ As, float* __restrict__ Aq)
{
    const int c = threadIdx.x, b = blockIdx.x;
    float s = 0.f, q = 0.f;
#pragma unroll
    for (int i = 0; i < 16; ++i) {
        s += Ps[(b*16 + i)*C + c];
        q += Pq[(b*16 + i)*C + c];
    }
    As[b*C + c] = s;
    Aq[b*C + c] = q;
}

// ---------------------------------------------------------------- finalize BN -> scale/shift (sums 64)
template<int C>
__global__ __launch_bounds__(C) void fin_kernel(
    const float* __restrict__ As, const float* __restrict__ Aq,
    const float* __restrict__ g, const float* __restrict__ b,
    float* __restrict__ scO, float* __restrict__ shO)
{
    const int c = threadIdx.x;
    float s = 0.f, q = 0.f;
#pragma unroll 8
    for (int i = 0; i < 64; ++i) { s += As[i*C + c]; q += Aq[i*C + c]; }
    const float inv = 1.f/(float)NN;
    float mu  = s*inv;
    float var = q*inv - mu*mu;
    float sc  = g[c]*rsqrtf(var + 1e-5f);
    scO[c] = sc;
    shO[c] = b[c] - mu*sc;
}

// ---------------------------------------------------------------- layer2 pre (MFMA): uv2 [N][512] bf16 = [u||v]
__global__ __launch_bounds__(256) void a2_kernel(
    const float* __restrict__ y1raw, const float* __restrict__ sc1, const float* __restrict__ sh1,
    const unsigned short* __restrict__ Wfuv, const float* __restrict__ bpre2,
    unsigned short* __restrict__ uv2)
{
    __shared__ __align__(16) unsigned short a1S[64*72];   // 64 nodes x 64 bf16, pitch 72
    __shared__ float biasS[256];
    const int tid  = threadIdx.x;
    const int base = blockIdx.x * 64;
    biasS[tid] = bpre2[tid];
#pragma unroll
    for (int it = 0; it < 4; ++it) {
        int i = tid + it*256;                       // over 1024 float4 = 64 rows x 16 f4
        float4 vv = ((const float4*)y1raw)[blockIdx.x*1024 + i];
        int n = i >> 4, c0 = (i & 15)*4;
        float c_[4] = {vv.x, vv.y, vv.z, vv.w};
#pragma unroll
        for (int j = 0; j < 4; ++j) {
            int c = c0 + j;
            a1S[n*72 + c] = f2bf(fmaxf(c_[j]*sc1[c] + sh1[c], 0.f));
        }
    }
    __syncthreads();
    const int l = tid & 63, w = tid >> 6;
    const int lr = l & 15, lk = l >> 4;
    const bf16x8 a0  = *(const bf16x8*)&a1S[(w*16 + lr)*72 +      lk*8];
    const bf16x8 a1f = *(const bf16x8*)&a1S[(w*16 + lr)*72 + 32 + lk*8];
    const bf16x8* WB = (const bf16x8*)Wfuv;
#pragma unroll 4
    for (int ct = 0; ct < 32; ++ct) {
        f32x4 acc = {0.f,0.f,0.f,0.f};
        bf16x8 b0 = WB[ct*64 + l];
        bf16x8 b1 = WB[(32 + ct)*64 + l];
        acc = __builtin_amdgcn_mfma_f32_16x16x32_bf16(a0,  b0, acc, 0, 0, 0);
        acc = __builtin_amdgcn_mfma_f32_16x16x32_bf16(a1f, b1, acc, 0, 0, 0);
        const int col = ct*16 + lr;
        const float bias = (ct < 16) ? biasS[col] : 0.f;
#pragma unroll
        for (int j = 0; j < 4; ++j)
            uv2[(base + w*16 + lk*4 + j)*512 + col] = f2bf(acc[j] + bias);
    }
}

// ---------------------------------------------------------------- layer2 fused (MFMA): agg + post + lin -> y2 [N,128]
__global__ __launch_bounds__(256) void b2_kernel(
    const int* __restrict__ nbr, const float* __restrict__ y1raw,
    const float* __restrict__ sc1, const float* __restrict__ sh1,
    const unsigned short* __restrict__ uv2,
    const unsigned short* __restrict__ Wfp, const unsigned short* __restrict__ Wfl,
    const float* __restrict__ blin_eff,
    float* __restrict__ y2)
{
    __shared__ int nbrsS[112];
    __shared__ __align__(16) unsigned short a1S[16*72];     // 16 nodes x 64 a1 (bf16), pitch 72
    __shared__ __align__(16) unsigned short aggS[64*264];   // rows (t*16+n), 256 agg vals, pitch 264
    __shared__ __align__(16) unsigned short postS[16*136];  // 16 nodes x 128 post (bf16), pitch 136

    const int tid = threadIdx.x;
    // XCD-affine swizzle: 32 blocks/graph, graph -> XCD (graph & 7)
    const int ob   = blockIdx.x;
    const int xcd  = ob & 7, slot = ob >> 3;
    const int gph  = ((slot >> 5) << 3) + xcd;
    const int sub  = slot & 31;
    const int base = gph*NPG + sub*16;

    if (tid < 112) nbrsS[tid] = nbr[base*7 + tid];
    for (int i = tid; i < 1024; i += 256) {
        int c = i & 63, n = i >> 6;
        float a = fmaxf(y1raw[base*64 + i]*sc1[c] + sh1[c], 0.f);
        a1S[n*72 + c] = f2bf(a);
    }
    __syncthreads();
    // ---- aggregation: 7-neighbor mean/min/max/std from bf16 uv2, fp32 math
    {
        const int t = tid >> 6, f = tid & 63;
        for (int ln = 0; ln < 16; ++ln) {
            float u = bf2f(uv2[(base+ln)*512 + tid]);
            float s = 0.f, s2 = 0.f, mn = 3e38f, mx = -3e38f;
#pragma unroll
            for (int e = 0; e < 7; ++e) {
                float vv = bf2f(uv2[nbrsS[ln*7+e]*512 + 256 + tid]);
                s += vv; s2 += vv*vv; mn = fminf(mn, vv); mx = fmaxf(mx, vv);
            }
            float mean = s * (1.f/7.f);
            float var  = s2 * (1.f/7.f) - mean*mean;
            float sd   = sqrtf(fmaxf(var, 0.f) + 1e-5f);
            const int ro = (t*16 + ln)*264;
            aggS[ro +       f] = f2bf(u + mean);
            aggS[ro +  64 + f] = f2bf(u + mn);
            aggS[ro + 128 + f] = f2bf(u + mx);
            aggS[ro + 192 + f] = f2bf(sd);
        }
    }
    __syncthreads();
    const int l = tid & 63, w = tid >> 6;
    const int lr = l & 15, lk = l >> 4;
    // ---- post GEMM (tower w): K=320 = 2 a1-chunks + 8 agg-chunks
    f32x4 acc0 = {0.f,0.f,0.f,0.f}, acc1 = {0.f,0.f,0.f,0.f};
    {
        const bf16x8* WB = (const bf16x8*)Wfp;
#pragma unroll
        for (int kk = 0; kk < 10; ++kk) {
            bf16x8 a;
            if (kk < 2) a = *(const bf16x8*)&a1S[lr*72 + kk*32 + lk*8];
            else        a = *(const bf16x8*)&aggS[(w*16 + lr)*264 + (kk-2)*32 + lk*8];
            bf16x8 b0 = WB[((w*10 + kk)*2 + 0)*64 + l];
            bf16x8 b1 = WB[((w*10 + kk)*2 + 1)*64 + l];
            acc0 = __builtin_amdgcn_mfma_f32_16x16x32_bf16(a, b0, acc0, 0, 0, 0);
            acc1 = __builtin_amdgcn_mfma_f32_16x16x32_bf16(a, b1, acc1, 0, 0, 0);
        }
    }
#pragma unroll
    for (int j = 0; j < 4; ++j) {
        const int row = lk*4 + j;
        postS[row*136 + w*32 +      lr] = f2bf(acc0[j]);
        postS[row*136 + w*32 + 16 + lr] = f2bf(acc1[j]);
    }
    __syncthreads();
    // ---- lin GEMM (cols 32w..32w+31): K=128
    f32x4 d0 = {0.f,0.f,0.f,0.f}, d1 = {0.f,0.f,0.f,0.f};
    {
        const bf16x8* WB = (const bf16x8*)Wfl;
#pragma unroll
        for (int kk = 0; kk < 4; ++kk) {
            bf16x8 a = *(const bf16x8*)&postS[lr*136 + kk*32 + lk*8];
            bf16x8 b0 = WB[(kk*8 + 2*w + 0)*64 + l];
            bf16x8 b1 = WB[(kk*8 + 2*w + 1)*64 + l];
            d0 = __builtin_amdgcn_mfma_f32_16x16x32_bf16(a, b0, d0, 0, 0, 0);
            d1 = __builtin_amdgcn_mfma_f32_16x16x32_bf16(a, b1, d1, 0, 0, 0);
        }
    }
    const float be0 = blin_eff[w*32 +      lr];
    const float be1 = blin_eff[w*32 + 16 + lr];
#pragma unroll
    for (int j = 0; j < 4; ++j) {
        const int row = lk*4 + j;
        y2[(base + row)*128 + w*32 +      lr] = d0[j] + be0;
        y2[(base + row)*128 + w*32 + 16 + lr] = d1[j] + be1;
    }
}

// ---------------------------------------------------------------- pool part: BN2+relu+64-row partial sums (1024 blocks)
__global__ __launch_bounds__(128) void pool_part_kernel(
    const float* __restrict__ y2, const float* __restrict__ sc2, const float* __restrict__ sh2,
    float* __restrict__ Pp)
{
    const int c = threadIdx.x;
    const int b = blockIdx.x;                 // b = g*8 + chunk
    const float sc = sc2[c];
    const float sh = sh2[c];
    float acc = 0.f;
    const size_t base = (size_t)b*64*128 + c;
#pragma unroll 4
    for (int i = 0; i < 64; ++i)
        acc += fmaxf(y2[base + (size_t)i*128]*sc + sh, 0.f);
    Pp[b*128 + c] = acc;
}

// ---------------------------------------------------------------- pool finalize: sum 8 chunks -> out [128,128]
__global__ __launch_bounds__(128) void pool_fin_kernel(
    const float* __restrict__ Pp, float* __restrict__ out)
{
    const int c = threadIdx.x, g = blockIdx.x;
    float acc = 0.f;
#pragma unroll
    for (int i = 0; i < 8; ++i) acc += Pp[(g*8 + i)*128 + c];
    out[g*128 + c] = acc * (1.f/(float)NPG);
}

// ---------------------------------------------------------------- launcher
extern "C" void kernel_launch(void* const* d_in, const int* in_sizes, int n_in,
                              void* d_out, int out_size, void* d_ws, size_t ws_size,
                              hipStream_t stream)
{
    const float* x      = (const float*)d_in[0];
    const float* pos    = (const float*)d_in[1];
    const float* Wpre1  = (const float*)d_in[2];
    const float* bpre1  = (const float*)d_in[3];
    const float* Wpost1 = (const float*)d_in[4];
    const float* bpost1 = (const float*)d_in[5];
    const float* Wlin1  = (const float*)d_in[6];
    const float* blin1  = (const float*)d_in[7];
    const float* bn1g   = (const float*)d_in[8];
    const float* bn1b   = (const float*)d_in[9];
    const float* Wpre2  = (const float*)d_in[10];
    const float* bpre2  = (const float*)d_in[11];
    const float* Wpost2 = (const float*)d_in[12];
    const float* bpost2 = (const float*)d_in[13];
    const float* Wlin2  = (const float*)d_in[14];
    const float* blin2  = (const float*)d_in[15];
    const float* bn2g   = (const float*)d_in[16];
    const float* bn2b   = (const float*)d_in[17];
    float* out = (float*)d_out;

    char* ws = (char*)d_ws;
    size_t off = 0;
    auto alloc = [&](size_t bytes) { void* p = ws + off; off += (bytes + 255) & ~(size_t)255; return p; };
    int*   nbr   = (int*)  alloc((size_t)NN*7*4);
    float* u1    = (float*)alloc((size_t)NN*32*4);
    float* v1    = (float*)alloc((size_t)NN*32*4);
    float* y1    = (float*)alloc((size_t)NN*64*4);            // raw (pre-BN)
    unsigned short* uv2 = (unsigned short*)alloc((size_t)NN*512*2);   // bf16 [u||v]
    float* y2    = (float*)alloc((size_t)NN*128*4);           // raw (pre-BN)
    float* Weff1 = (float*)alloc(2560*4);
    unsigned short* Wfuv = (unsigned short*)alloc(32768*2);
    unsigned short* Wfp  = (unsigned short*)alloc(40960*2);
    unsigned short* Wfl  = (unsigned short*)alloc(16384*2);
    float* blin_eff = (float*)alloc(128*4);
    float* P1s   = (float*)alloc(1024*64*4);
    float* P1q   = (float*)alloc(1024*64*4);
    float* A1s   = (float*)alloc(64*64*4);
    float* A1q   = (float*)alloc(64*64*4);
    float* sc1   = (float*)alloc(64*4);
    float* sh1   = (float*)alloc(64*4);
    float* P2s   = (float*)alloc(1024*128*4);
    float* P2q   = (float*)alloc(1024*128*4);
    float* A2s   = (float*)alloc(64*128*4);
    float* A2q   = (float*)alloc(64*128*4);
    float* sc2   = (float*)alloc(128*4);
    float* sh2   = (float*)alloc(128*4);
    float* Pp    = (float*)alloc(1024*128*4);

    prep_kernel<<<128, 256, 0, stream>>>(Wpost1, Wpost2, Wpre2, Wlin2, bpost2, blin2,
                                         Weff1, Wfuv, Wfp, Wfl, blin_eff);
    knn_kernel<<<NGRAPH*2, 256, 0, stream>>>(pos, nbr);
    a1_kernel<<<NN/8, 256, 0, stream>>>(x, Wpre1, bpre1, u1, v1);
    b1_kernel<<<NN/16, 256, 0, stream>>>(x, nbr, u1, v1, Weff1, bpost1, Wlin1, blin1, y1);
    bn_stats_kernel<64><<<1024, 256, 0, stream>>>(y1, P1s, P1q);
    finA_kernel<64><<<64, 64, 0, stream>>>(P1s, P1q, A1s, A1q);
    fin_kernel<64><<<1, 64, 0, stream>>>(A1s, A1q, bn1g, bn1b, sc1, sh1);
    a2_kernel<<<NN/64, 256, 0, stream>>>(y1, sc1, sh1, Wfuv, bpre2, uv2);
    b2_kernel<<<NN/16, 256, 0, stream>>>(nbr, y1, sc1, sh1, uv2, Wfp, Wfl, blin_eff, y2);
    bn_stats_kernel<128><<<1024, 256, 0, stream>>>(y2, P2s, P2q);
    finA_kernel<128><<<64, 128, 0, stream>>>(P2s, P2q, A2s, A2q);
    fin_kernel<128><<<1, 128, 0, stream>>>(A2s, A2q, bn2g, bn2b, sc2, sh2);
    pool_part_kernel<<<1024, 128, 0, stream>>>(y2, sc2, sh2, Pp);
    pool_fin_kernel<<<NGRAPH, 128, 0, stream>>>(Pp, out);
}

// Round 12
// 186.891 us; speedup vs baseline: 2.9584x; 1.2475x over previous
//
#include <hip/hip_runtime.h>
#include <math.h>

// PNANet on MI355X, round 12: fix round-11's two bugs.
//  * b1: restore __syncthreads() between nbrsS fill and agg gather (race -> OOB crash).
//  * b2 agg: row index (t*16+ln) to match MFMA read (was (ln*4+t)).
//  Content otherwise identical to round 11.

#define NGRAPH 128
#define NPG    512
#define NN     (NGRAPH*NPG)   // 65536
#define KNB    7

constexpr double AVG_DEG_LOG_D = 2.0239670479173344;  // (100*ln6+200*ln7+700*ln8)/1000
constexpr double LOG8_D        = 2.0794415416798357;

typedef short bf16x8 __attribute__((ext_vector_type(8)));
typedef float f32x4  __attribute__((ext_vector_type(4)));

__device__ __forceinline__ unsigned short f2bf(float x) {   // RNE, finite inputs
    unsigned u = __float_as_uint(x);
    return (unsigned short)((u + 0x7fffu + ((u >> 16) & 1u)) >> 16);
}
__device__ __forceinline__ float bf2f(unsigned short u) {
    return __uint_as_float(((unsigned)u) << 16);
}

// ---------------------------------------------------------------- weight prep
__global__ __launch_bounds__(256) void prep_kernel(
    const float* __restrict__ Wpost1, const float* __restrict__ Wpost2,
    const float* __restrict__ Wpre2,  const float* __restrict__ Wlin2,
    const float* __restrict__ Wlin1,  const float* __restrict__ bpost1,
    const float* __restrict__ blin1,
    const float* __restrict__ bpost2, const float* __restrict__ blin2,
    unsigned short* __restrict__ Wf1p, unsigned short* __restrict__ Wf1l,
    float* __restrict__ blin1_eff,
    unsigned short* __restrict__ Wfuv,
    unsigned short* __restrict__ Wfp, unsigned short* __restrict__ Wfl,
    float* __restrict__ blin_eff)
{
    const float AMP = (float)(LOG8_D / AVG_DEG_LOG_D);
    const float ATT = (float)(AVG_DEG_LOG_D / LOG8_D);
    for (int i = blockIdx.x*256 + threadIdx.x; i < 98496; i += gridDim.x*256) {
        if (i < 4096) {
            // Wf1p: [t][kk<2][lane<64][j<8]; k = kk*32+(lane>>4)*8+j; col = lane&15
            int t = i >> 10, kk = (i >> 9) & 1, lane = (i >> 3) & 63, j = i & 7;
            int k = kk*32 + ((lane >> 4) << 3) + j;
            int col = lane & 15;
            float val;
            if (k < 8)       val = Wpost1[(t*104 + k)*16 + col];
            else if (k < 40) {
                int g2 = k - 8;
                val = Wpost1[(t*104 +  8 + g2)*16 + col]
                    + AMP*Wpost1[(t*104 + 40 + g2)*16 + col]
                    + ATT*Wpost1[(t*104 + 72 + g2)*16 + col];
            } else val = 0.f;
            Wf1p[i] = f2bf(val);
        } else if (i < 8192) {
            // Wf1l: [kk<2][tile<4][lane<64][j<8]
            int jj = i - 4096;
            int kk = jj >> 11, tile = (jj >> 9) & 3, lane = (jj >> 3) & 63, j = jj & 7;
            int k = kk*32 + ((lane >> 4) << 3) + j;
            int col = tile*16 + (lane & 15);
            Wf1l[jj] = f2bf(Wlin1[k*64 + col]);
        } else if (i < 8256) {
            // blin1_eff[c] = blin1[c] + sum_o bpost1[o]*Wlin1[o][c]
            int c = i - 8192;
            float s = blin1[c];
            for (int o = 0; o < 64; ++o) s += bpost1[o]*Wlin1[o*64 + c];
            blin1_eff[c] = s;
        } else if (i < 41024) {
            // Wfuv: [kk<2][ct<32][lane<64][j<8] bf16; col = ct*16+(lane&15) in [0,512) = u||v
            int jj = i - 8256;
            int kk = jj >> 14, ct = (jj >> 9) & 31, lane = (jj >> 3) & 63, jf = jj & 7;
            int k   = kk*32 + ((lane >> 4) << 3) + jf;
            int col = ct*16 + (lane & 15);
            float val;
            if (col < 256) { int t = col >> 6, f = col & 63; val = Wpre2[(t*128 +      k)*64 + f]; }
            else { int c2 = col - 256; int t = c2 >> 6, f = c2 & 63; val = Wpre2[(t*128 + 64 + k)*64 + f]; }
            Wfuv[jj] = f2bf(val);
        } else if (i < 81984) {
            // Wfrag_post: [t][kk<10][c<2][lane<64][j<8], bf16
            int jj = i - 41024;
            int t = jj / 10240, r = jj % 10240;
            int kk = r / 1024, r2 = r % 1024;
            int c = r2 >> 9, lane = (r2 >> 3) & 63, jf = r2 & 7;
            int G   = kk*32 + ((lane >> 4) << 3) + jf;
            int col = c*16 + (lane & 15);
            float val;
            if (G < 64) val = Wpost2[(t*832 + G)*32 + col];
            else {
                int g2 = G - 64;
                val = Wpost2[(t*832 +  64 + g2)*32 + col]
                    + AMP*Wpost2[(t*832 + 320 + g2)*32 + col]
                    + ATT*Wpost2[(t*832 + 576 + g2)*32 + col];
            }
            Wfp[jj] = f2bf(val);
        } else if (i < 98368) {
            // Wfrag_lin: [kk<4][tile<8][lane<64][j<8], bf16
            int jj = i - 81984;
            int kk = jj / 4096, r = jj % 4096;
            int tile = r >> 9, lane = (r >> 3) & 63, jf = r & 7;
            int k   = kk*32 + ((lane >> 4) << 3) + jf;
            int col = tile*16 + (lane & 15);
            Wfl[jj] = f2bf(Wlin2[k*128 + col]);
        } else {
            // blin_eff[c] = blin2[c] + sum_o bpost2[o]*Wlin2[o][c]
            int c = i - 98368;
            float s = blin2[c];
            for (int o = 0; o < 128; ++o) s += bpost2[o]*Wlin2[o*128 + c];
            blin_eff[c] = s;
        }
    }
}

// ---------------------------------------------------------------- kNN (k=7); 2 blocks per graph
__global__ __launch_bounds__(256) void knn_kernel(const float* __restrict__ pos, int* __restrict__ nbr)
{
    __shared__ float4 posS[NPG];
    const int g    = blockIdx.x >> 1;
    const int half = blockIdx.x & 1;
    const int gb   = g * NPG;
    for (int j = threadIdx.x; j < NPG; j += 256)
        posS[j] = make_float4(pos[(gb+j)*3+0], pos[(gb+j)*3+1], pos[(gb+j)*3+2], 0.f);
    __syncthreads();
    const int i = half*256 + threadIdx.x;
    const float4 pi = posS[i];
    float bd[KNB]; int bi[KNB];
#pragma unroll
    for (int e = 0; e < KNB; ++e) { bd[e] = 3.0e38f; bi[e] = -1; }
#pragma unroll 4
    for (int j = 0; j < NPG; ++j) {
        float4 pj = posS[j];
        float dx = pi.x - pj.x, dy = pi.y - pj.y, dz = pi.z - pj.z;
        float d2 = __fadd_rn(__fadd_rn(__fmul_rn(dx,dx), __fmul_rn(dy,dy)), __fmul_rn(dz,dz));
        if (j == i) d2 = __builtin_inff();
        bool cmp[KNB];
#pragma unroll
        for (int e = 0; e < KNB; ++e) cmp[e] = d2 < bd[e];
#pragma unroll
        for (int e = KNB-1; e >= 1; --e) {
            bd[e] = cmp[e-1] ? bd[e-1] : (cmp[e] ? d2 : bd[e]);
            bi[e] = cmp[e-1] ? bi[e-1] : (cmp[e] ? j  : bi[e]);
        }
        bd[0] = cmp[0] ? d2 : bd[0];
        bi[0] = cmp[0] ? j  : bi[0];
    }
#pragma unroll
    for (int e = 0; e < KNB; ++e) nbr[(gb+i)*KNB + e] = gb + bi[e];
}

// ---------------------------------------------------------------- layer1: u1,v1 [N,32]
__global__ __launch_bounds__(256) void a1_kernel(
    const float* __restrict__ x, const float* __restrict__ Wpre1, const float* __restrict__ bpre1,
    float* __restrict__ u1, float* __restrict__ v1)
{
    __shared__ float wS[512];
    __shared__ float bS[32];
    const int tid = threadIdx.x;
    wS[tid] = Wpre1[tid]; wS[tid+256] = Wpre1[tid+256];
    if (tid < 32) bS[tid] = bpre1[tid];
    __syncthreads();
    const int n  = blockIdx.x*8 + (tid>>5);
    const int tf = tid & 31;
    const int t = tf >> 3, f = tf & 7;
    float u = bS[tf], v = 0.f;
#pragma unroll
    for (int e = 0; e < 8; ++e) {
        float xv = x[n*8+e];
        u += xv * wS[(t*16 + e)*8 + f];
        v += xv * wS[(t*16 + 8 + e)*8 + f];
    }
    u1[n*32+tf] = u;
    v1[n*32+tf] = v;
}

// ---------------------------------------------------------------- layer1 fused (MFMA): agg + post + lin -> y1 [N,64]
// act rows (node*4+t): [x(8) | mean8 min8 max8 std8 | zeros(24)] K=64, pitch 72 (bf16)
__global__ __launch_bounds__(256) void b1_kernel(
    const float* __restrict__ x, const int* __restrict__ nbr,
    const float* __restrict__ u1, const float* __restrict__ v1,
    const unsigned short* __restrict__ Wf1p, const unsigned short* __restrict__ Wf1l,
    const float* __restrict__ blin1_eff,
    float* __restrict__ y1)
{
    __shared__ int nbrsS[112];
    __shared__ __align__(16) unsigned short actS[64*72];
    __shared__ __align__(16) unsigned short postS[16*72];
    const int tid  = threadIdx.x;
    const int base = blockIdx.x * 16;
    if (tid < 112) nbrsS[tid] = nbr[base*7 + tid];
    // zero pad cols 40..63 (disjoint from agg/x fill regions)
    for (int i = tid; i < 384; i += 256) {
        int r = i / 6, gq = i - 6*r;
        *(ushort4*)&actS[r*72 + 40 + gq*4] = make_ushort4(0,0,0,0);
    }
    // x part: cols 0..7 for all 4 tower rows
#pragma unroll
    for (int it = 0; it < 2; ++it) {
        int i = tid + it*256;
        int n = i >> 5, r2 = i & 31, t = r2 >> 3, f = r2 & 7;
        actS[(n*4 + t)*72 + f] = f2bf(x[(base+n)*8 + f]);
    }
    __syncthreads();   // nbrsS visible to all threads (round-11 crash: this was missing)
    // agg part: thread = (node, col-pair); float2 gathers from fp32 u1/v1
    {
        const int n = tid >> 4, cp = tid & 15;
        const int tf0 = cp*2, t = tf0 >> 3, f0 = tf0 & 7;
        float2 uu = *(const float2*)&u1[(base+n)*32 + tf0];
        float s0=0.f,s1=0.f,q0=0.f,q1=0.f;
        float mn0=3e38f,mn1=3e38f,mx0=-3e38f,mx1=-3e38f;
#pragma unroll
        for (int e = 0; e < 7; ++e) {
            float2 vv = *(const float2*)&v1[nbrsS[n*7+e]*32 + tf0];
            s0 += vv.x; q0 += vv.x*vv.x; mn0 = fminf(mn0, vv.x); mx0 = fmaxf(mx0, vv.x);
            s1 += vv.y; q1 += vv.y*vv.y; mn1 = fminf(mn1, vv.y); mx1 = fmaxf(mx1, vv.y);
        }
        float me0 = s0*(1.f/7.f), me1 = s1*(1.f/7.f);
        float sd0 = sqrtf(fmaxf(q0*(1.f/7.f) - me0*me0, 0.f) + 1e-5f);
        float sd1 = sqrtf(fmaxf(q1*(1.f/7.f) - me1*me1, 0.f) + 1e-5f);
        const int row = (n*4 + t)*72;
        ushort2 w_;
        w_.x = f2bf(uu.x + me0); w_.y = f2bf(uu.y + me1); *(ushort2*)&actS[row +  8 + f0] = w_;
        w_.x = f2bf(uu.x + mn0); w_.y = f2bf(uu.y + mn1); *(ushort2*)&actS[row + 16 + f0] = w_;
        w_.x = f2bf(uu.x + mx0); w_.y = f2bf(uu.y + mx1); *(ushort2*)&actS[row + 24 + f0] = w_;
        w_.x = f2bf(sd0);        w_.y = f2bf(sd1);        *(ushort2*)&actS[row + 32 + f0] = w_;
    }
    __syncthreads();
    const int l = tid & 63, w = tid >> 6;
    const int lr = l & 15, lk = l >> 4;
    // post GEMM: wave w = tower w; K=64 (2 chunks), out 16 cols
    f32x4 acc = {0.f,0.f,0.f,0.f};
    {
        const bf16x8* WB = (const bf16x8*)Wf1p;
#pragma unroll
        for (int kk = 0; kk < 2; ++kk) {
            bf16x8 a = *(const bf16x8*)&actS[(lr*4 + w)*72 + kk*32 + lk*8];
            bf16x8 b = WB[(w*2 + kk)*64 + l];
            acc = __builtin_amdgcn_mfma_f32_16x16x32_bf16(a, b, acc, 0, 0, 0);
        }
    }
#pragma unroll
    for (int j = 0; j < 4; ++j)
        postS[(lk*4 + j)*72 + w*16 + lr] = f2bf(acc[j]);
    __syncthreads();
    // lin GEMM: wave w = out col-tile w; K=64 (2 chunks)
    f32x4 d = {0.f,0.f,0.f,0.f};
    {
        const bf16x8* WB = (const bf16x8*)Wf1l;
#pragma unroll
        for (int kk = 0; kk < 2; ++kk) {
            bf16x8 a = *(const bf16x8*)&postS[lr*72 + kk*32 + lk*8];
            bf16x8 b = WB[(kk*4 + w)*64 + l];
            d = __builtin_amdgcn_mfma_f32_16x16x32_bf16(a, b, d, 0, 0, 0);
        }
    }
    const float be = blin1_eff[w*16 + lr];
#pragma unroll
    for (int j = 0; j < 4; ++j)
        y1[(base + lk*4 + j)*64 + w*16 + lr] = d[j] + be;
}

// ---------------------------------------------------------------- BN stats: 1024 blocks, float4, LDS tree -> partials
template<int C>
__global__ __launch_bounds__(256) void bn_stats_kernel(
    const float* __restrict__ y, float* __restrict__ Ps, float* __restrict__ Pq)
{
    constexpr int IT     = (NN/1024)*(C/4)/256;   // C=64 -> 4, C=128 -> 8
    constexpr int GROUPS = C/4;
    constexpr int REPS   = 256/GROUPS;
    const int tid = threadIdx.x;
    const float4* y4 = (const float4*)y + (size_t)blockIdx.x*256*IT;
    float4 s = make_float4(0.f,0.f,0.f,0.f), q = make_float4(0.f,0.f,0.f,0.f);
#pragma unroll
    for (int it = 0; it < IT; ++it) {
        float4 v = y4[it*256 + tid];
        s.x += v.x; s.y += v.y; s.z += v.z; s.w += v.w;
        q.x += v.x*v.x; q.y += v.y*v.y; q.z += v.z*v.z; q.w += v.w*v.w;
    }
    __shared__ float4 sS[256], qS[256];
    sS[tid] = s; qS[tid] = q;
    __syncthreads();
#pragma unroll
    for (int step = REPS/2; step >= 1; step >>= 1) {
        if (tid < step*GROUPS) {
            float4 s2 = sS[tid + step*GROUPS], q2 = qS[tid + step*GROUPS];
            float4 ss = sS[tid], qq = qS[tid];
            ss.x += s2.x; ss.y += s2.y; ss.z += s2.z; ss.w += s2.w;
            qq.x += q2.x; qq.y += q2.y; qq.z += q2.z; qq.w += q2.w;
            sS[tid] = ss; qS[tid] = qq;
        }
        __syncthreads();
    }
    if (tid < GROUPS) {
        ((float4*)&Ps[(size_t)blockIdx.x*C])[tid] = sS[tid];
        ((float4*)&Pq[(size_t)blockIdx.x*C])[tid] = qS[tid];
    }
}

// ---------------------------------------------------------------- finA: 64 blocks, sum 16 partial-rows
template<int C>
__global__ __launch_bounds__(C) void finA_kernel(
    const float* __restrict__ Ps, const float* __restrict__ Pq,
    float* __restrict__ As, float* __restrict__ Aq)
{
    const int c = threadIdx.x, b = blockIdx.x;
    float s = 0.f, q = 0.f;
#pragma unroll
    for (int i = 0; i < 16; ++i) {
        s += Ps[(b*16 + i)*C + c];
        q += Pq[(b*16 + i)*C + c];
    }
    As[b*C + c] = s;
    Aq[b*C + c] = q;
}

// ---------------------------------------------------------------- finalize BN -> scale/shift (sums 64)
template<int C>
__global__ __launch_bounds__(C) void fin_kernel(
    const float* __restrict__ As, const float* __restrict__ Aq,
    const float* __restrict__ g, const float* __restrict__ b,
    float* __restrict__ scO, float* __restrict__ shO)
{
    const int c = threadIdx.x;
    float s = 0.f, q = 0.f;
#pragma unroll 8
    for (int i = 0; i < 64; ++i) { s += As[i*C + c]; q += Aq[i*C + c]; }
    const float inv = 1.f/(float)NN;
    float mu  = s*inv;
    float var = q*inv - mu*mu;
    float sc  = g[c]*rsqrtf(var + 1e-5f);
    scO[c] = sc;
    shO[c] = b[c] - mu*sc;
}

// ---------------------------------------------------------------- layer2 pre (MFMA): uv2 [N][512] bf16 = [u||v]
__global__ __launch_bounds__(256) void a2_kernel(
    const float* __restrict__ y1raw, const float* __restrict__ sc1, const float* __restrict__ sh1,
    const unsigned short* __restrict__ Wfuv, const float* __restrict__ bpre2,
    unsigned short* __restrict__ uv2)
{
    __shared__ __align__(16) unsigned short a1S[64*72];   // 64 nodes x 64 bf16, pitch 72
    __shared__ float biasS[256];
    const int tid  = threadIdx.x;
    const int base = blockIdx.x * 64;
    biasS[tid] = bpre2[tid];
#pragma unroll
    for (int it = 0; it < 4; ++it) {
        int i = tid + it*256;                       // over 1024 float4 = 64 rows x 16 f4
        float4 vv = ((const float4*)y1raw)[blockIdx.x*1024 + i];
        int n = i >> 4, c0 = (i & 15)*4;
        float c_[4] = {vv.x, vv.y, vv.z, vv.w};
#pragma unroll
        for (int j = 0; j < 4; ++j) {
            int c = c0 + j;
            a1S[n*72 + c] = f2bf(fmaxf(c_[j]*sc1[c] + sh1[c], 0.f));
        }
    }
    __syncthreads();
    const int l = tid & 63, w = tid >> 6;
    const int lr = l & 15, lk = l >> 4;
    const bf16x8 a0  = *(const bf16x8*)&a1S[(w*16 + lr)*72 +      lk*8];
    const bf16x8 a1f = *(const bf16x8*)&a1S[(w*16 + lr)*72 + 32 + lk*8];
    const bf16x8* WB = (const bf16x8*)Wfuv;
#pragma unroll 4
    for (int ct = 0; ct < 32; ++ct) {
        f32x4 acc = {0.f,0.f,0.f,0.f};
        bf16x8 b0 = WB[ct*64 + l];
        bf16x8 b1 = WB[(32 + ct)*64 + l];
        acc = __builtin_amdgcn_mfma_f32_16x16x32_bf16(a0,  b0, acc, 0, 0, 0);
        acc = __builtin_amdgcn_mfma_f32_16x16x32_bf16(a1f, b1, acc, 0, 0, 0);
        const int col = ct*16 + lr;
        const float bias = (ct < 16) ? biasS[col] : 0.f;
#pragma unroll
        for (int j = 0; j < 4; ++j)
            uv2[(base + w*16 + lk*4 + j)*512 + col] = f2bf(acc[j] + bias);
    }
}

// ---------------------------------------------------------------- layer2 fused (MFMA): agg + post + lin -> y2 [N,128]
__global__ __launch_bounds__(256) void b2_kernel(
    const int* __restrict__ nbr, const float* __restrict__ y1raw,
    const float* __restrict__ sc1, const float* __restrict__ sh1,
    const unsigned short* __restrict__ uv2,
    const unsigned short* __restrict__ Wfp, const unsigned short* __restrict__ Wfl,
    const float* __restrict__ blin_eff,
    float* __restrict__ y2)
{
    __shared__ int nbrsS[112];
    __shared__ __align__(16) unsigned short a1S[16*72];     // 16 nodes x 64 a1 (bf16), pitch 72
    __shared__ __align__(16) unsigned short aggS[64*264];   // rows (t*16+node), 256 agg vals, pitch 264
    __shared__ __align__(16) unsigned short postS[16*136];  // 16 nodes x 128 post (bf16), pitch 136

    const int tid = threadIdx.x;
    // XCD-affine swizzle: 32 blocks/graph, graph -> XCD (graph & 7)
    const int ob   = blockIdx.x;
    const int xcd  = ob & 7, slot = ob >> 3;
    const int gph  = ((slot >> 5) << 3) + xcd;
    const int sub  = slot & 31;
    const int base = gph*NPG + sub*16;

    if (tid < 112) nbrsS[tid] = nbr[base*7 + tid];
    for (int i = tid; i < 1024; i += 256) {
        int c = i & 63, n = i >> 6;
        float a = fmaxf(y1raw[base*64 + i]*sc1[c] + sh1[c], 0.f);
        a1S[n*72 + c] = f2bf(a);
    }
    __syncthreads();
    // ---- aggregation: ushort4 gathers, 4 cols/thread, 4 nodes/iter
    {
        const int ns = tid >> 6, cg = tid & 63;
        const int t = cg >> 4, f0 = (cg & 15) * 4;
#pragma unroll
        for (int it = 0; it < 4; ++it) {
            const int ln = it*4 + ns;
            ushort4 uu4 = *(const ushort4*)&uv2[(size_t)(base+ln)*512 + cg*4];
            float u0 = bf2f(uu4.x), u1v = bf2f(uu4.y), u2v = bf2f(uu4.z), u3v = bf2f(uu4.w);
            float s0=0.f,s1=0.f,s2=0.f,s3=0.f, q0=0.f,q1=0.f,q2=0.f,q3=0.f;
            float mn0=3e38f,mn1=3e38f,mn2=3e38f,mn3=3e38f;
            float mx0=-3e38f,mx1=-3e38f,mx2=-3e38f,mx3=-3e38f;
#pragma unroll
            for (int e = 0; e < 7; ++e) {
                ushort4 vv4 = *(const ushort4*)&uv2[(size_t)nbrsS[ln*7+e]*512 + 256 + cg*4];
                float v0 = bf2f(vv4.x), v1 = bf2f(vv4.y), v2 = bf2f(vv4.z), v3 = bf2f(vv4.w);
                s0 += v0; q0 += v0*v0; mn0 = fminf(mn0,v0); mx0 = fmaxf(mx0,v0);
                s1 += v1; q1 += v1*v1; mn1 = fminf(mn1,v1); mx1 = fmaxf(mx1,v1);
                s2 += v2; q2 += v2*v2; mn2 = fminf(mn2,v2); mx2 = fmaxf(mx2,v2);
                s3 += v3; q3 += v3*v3; mn3 = fminf(mn3,v3); mx3 = fmaxf(mx3,v3);
            }
            float me0 = s0*(1.f/7.f), me1 = s1*(1.f/7.f), me2 = s2*(1.f/7.f), me3 = s3*(1.f/7.f);
            float sd0 = sqrtf(fmaxf(q0*(1.f/7.f) - me0*me0, 0.f) + 1e-5f);
            float sd1 = sqrtf(fmaxf(q1*(1.f/7.f) - me1*me1, 0.f) + 1e-5f);
            float sd2 = sqrtf(fmaxf(q2*(1.f/7.f) - me2*me2, 0.f) + 1e-5f);
            float sd3 = sqrtf(fmaxf(q3*(1.f/7.f) - me3*me3, 0.f) + 1e-5f);
            const int ro = (t*16 + ln)*264 + f0;    // row = tower*16 + node (matches MFMA read)
            *(ushort4*)&aggS[ro      ] = make_ushort4(f2bf(u0+me0), f2bf(u1v+me1), f2bf(u2v+me2), f2bf(u3v+me3));
            *(ushort4*)&aggS[ro +  64] = make_ushort4(f2bf(u0+mn0), f2bf(u1v+mn1), f2bf(u2v+mn2), f2bf(u3v+mn3));
            *(ushort4*)&aggS[ro + 128] = make_ushort4(f2bf(u0+mx0), f2bf(u1v+mx1), f2bf(u2v+mx2), f2bf(u3v+mx3));
            *(ushort4*)&aggS[ro + 192] = make_ushort4(f2bf(sd0),    f2bf(sd1),     f2bf(sd2),     f2bf(sd3));
        }
    }
    __syncthreads();
    const int l = tid & 63, w = tid >> 6;
    const int lr = l & 15, lk = l >> 4;
    // ---- post GEMM (tower w): K=320 = 2 a1-chunks + 8 agg-chunks
    f32x4 acc0 = {0.f,0.f,0.f,0.f}, acc1 = {0.f,0.f,0.f,0.f};
    {
        const bf16x8* WB = (const bf16x8*)Wfp;
#pragma unroll
        for (int kk = 0; kk < 10; ++kk) {
            bf16x8 a;
            if (kk < 2) a = *(const bf16x8*)&a1S[lr*72 + kk*32 + lk*8];
            else        a = *(const bf16x8*)&aggS[(w*16 + lr)*264 + (kk-2)*32 + lk*8];
            bf16x8 b0 = WB[((w*10 + kk)*2 + 0)*64 + l];
            bf16x8 b1 = WB[((w*10 + kk)*2 + 1)*64 + l];
            acc0 = __builtin_amdgcn_mfma_f32_16x16x32_bf16(a, b0, acc0, 0, 0, 0);
            acc1 = __builtin_amdgcn_mfma_f32_16x16x32_bf16(a, b1, acc1, 0, 0, 0);
        }
    }
#pragma unroll
    for (int j = 0; j < 4; ++j) {
        const int row = lk*4 + j;
        postS[row*136 + w*32 +      lr] = f2bf(acc0[j]);
        postS[row*136 + w*32 + 16 + lr] = f2bf(acc1[j]);
    }
    __syncthreads();
    // ---- lin GEMM (cols 32w..32w+31): K=128
    f32x4 d0 = {0.f,0.f,0.f,0.f}, d1 = {0.f,0.f,0.f,0.f};
    {
        const bf16x8* WB = (const bf16x8*)Wfl;
#pragma unroll
        for (int kk = 0; kk < 4; ++kk) {
            bf16x8 a = *(const bf16x8*)&postS[lr*136 + kk*32 + lk*8];
            bf16x8 b0 = WB[(kk*8 + 2*w + 0)*64 + l];
            bf16x8 b1 = WB[(kk*8 + 2*w + 1)*64 + l];
            d0 = __builtin_amdgcn_mfma_f32_16x16x32_bf16(a, b0, d0, 0, 0, 0);
            d1 = __builtin_amdgcn_mfma_f32_16x16x32_bf16(a, b1, d1, 0, 0, 0);
        }
    }
    const float be0 = blin_eff[w*32 +      lr];
    const float be1 = blin_eff[w*32 + 16 + lr];
#pragma unroll
    for (int j = 0; j < 4; ++j) {
        const int row = lk*4 + j;
        y2[(base + row)*128 + w*32 +      lr] = d0[j] + be0;
        y2[(base + row)*128 + w*32 + 16 + lr] = d1[j] + be1;
    }
}

// ---------------------------------------------------------------- pool part: BN2+relu+64-row partial sums (1024 blocks)
__global__ __launch_bounds__(128) void pool_part_kernel(
    const float* __restrict__ y2, const float* __restrict__ sc2, const float* __restrict__ sh2,
    float* __restrict__ Pp)
{
    const int c = threadIdx.x;
    const int b = blockIdx.x;                 // b = g*8 + chunk
    const float sc = sc2[c];
    const float sh = sh2[c];
    float acc = 0.f;
    const size_t base = (size_t)b*64*128 + c;
#pragma unroll 4
    for (int i = 0; i < 64; ++i)
        acc += fmaxf(y2[base + (size_t)i*128]*sc + sh, 0.f);
    Pp[b*128 + c] = acc;
}

// ---------------------------------------------------------------- pool finalize: sum 8 chunks -> out [128,128]
__global__ __launch_bounds__(128) void pool_fin_kernel(
    const float* __restrict__ Pp, float* __restrict__ out)
{
    const int c = threadIdx.x, g = blockIdx.x;
    float acc = 0.f;
#pragma unroll
    for (int i = 0; i < 8; ++i) acc += Pp[(g*8 + i)*128 + c];
    out[g*128 + c] = acc * (1.f/(float)NPG);
}

// ---------------------------------------------------------------- launcher
extern "C" void kernel_launch(void* const* d_in, const int* in_sizes, int n_in,
                              void* d_out, int out_size, void* d_ws, size_t ws_size,
                              hipStream_t stream)
{
    const float* x      = (const float*)d_in[0];
    const float* pos    = (const float*)d_in[1];
    const float* Wpre1  = (const float*)d_in[2];
    const float* bpre1  = (const float*)d_in[3];
    const float* Wpost1 = (const float*)d_in[4];
    const float* bpost1 = (const float*)d_in[5];
    const float* Wlin1  = (const float*)d_in[6];
    const float* blin1  = (const float*)d_in[7];
    const float* bn1g   = (const float*)d_in[8];
    const float* bn1b   = (const float*)d_in[9];
    const float* Wpre2  = (const float*)d_in[10];
    const float* bpre2  = (const float*)d_in[11];
    const float* Wpost2 = (const float*)d_in[12];
    const float* bpost2 = (const float*)d_in[13];
    const float* Wlin2  = (const float*)d_in[14];
    const float* blin2  = (const float*)d_in[15];
    const float* bn2g   = (const float*)d_in[16];
    const float* bn2b   = (const float*)d_in[17];
    float* out = (float*)d_out;

    char* ws = (char*)d_ws;
    size_t off = 0;
    auto alloc = [&](size_t bytes) { void* p = ws + off; off += (bytes + 255) & ~(size_t)255; return p; };
    int*   nbr   = (int*)  alloc((size_t)NN*7*4);
    float* u1    = (float*)alloc((size_t)NN*32*4);
    float* v1    = (float*)alloc((size_t)NN*32*4);
    float* y1    = (float*)alloc((size_t)NN*64*4);            // raw (pre-BN)
    unsigned short* uv2 = (unsigned short*)alloc((size_t)NN*512*2);   // bf16 [u||v]
    float* y2    = (float*)alloc((size_t)NN*128*4);           // raw (pre-BN)
    unsigned short* Wf1p = (unsigned short*)alloc(4096*2);
    unsigned short* Wf1l = (unsigned short*)alloc(4096*2);
    float* blin1_eff = (float*)alloc(64*4);
    unsigned short* Wfuv = (unsigned short*)alloc(32768*2);
    unsigned short* Wfp  = (unsigned short*)alloc(40960*2);
    unsigned short* Wfl  = (unsigned short*)alloc(16384*2);
    float* blin_eff = (float*)alloc(128*4);
    float* P1s   = (float*)alloc(1024*64*4);
    float* P1q   = (float*)alloc(1024*64*4);
    float* A1s   = (float*)alloc(64*64*4);
    float* A1q   = (float*)alloc(64*64*4);
    float* sc1   = (float*)alloc(64*4);
    float* sh1   = (float*)alloc(64*4);
    float* P2s   = (float*)alloc(1024*128*4);
    float* P2q   = (float*)alloc(1024*128*4);
    float* A2s   = (float*)alloc(64*128*4);
    float* A2q   = (float*)alloc(64*128*4);
    float* sc2   = (float*)alloc(128*4);
    float* sh2   = (float*)alloc(128*4);
    float* Pp    = (float*)alloc(1024*128*4);

    prep_kernel<<<128, 256, 0, stream>>>(Wpost1, Wpost2, Wpre2, Wlin2, Wlin1, bpost1, blin1,
                                         bpost2, blin2,
                                         Wf1p, Wf1l, blin1_eff, Wfuv, Wfp, Wfl, blin_eff);
    knn_kernel<<<NGRAPH*2, 256, 0, stream>>>(pos, nbr);
    a1_kernel<<<NN/8, 256, 0, stream>>>(x, Wpre1, bpre1, u1, v1);
    b1_kernel<<<NN/16, 256, 0, stream>>>(x, nbr, u1, v1, Wf1p, Wf1l, blin1_eff, y1);
    bn_stats_kernel<64><<<1024, 256, 0, stream>>>(y1, P1s, P1q);
    finA_kernel<64><<<64, 64, 0, stream>>>(P1s, P1q, A1s, A1q);
    fin_kernel<64><<<1, 64, 0, stream>>>(A1s, A1q, bn1g, bn1b, sc1, sh1);
    a2_kernel<<<NN/64, 256, 0, stream>>>(y1, sc1, sh1, Wfuv, bpre2, uv2);
    b2_kernel<<<NN/16, 256, 0, stream>>>(nbr, y1, sc1, sh1, uv2, Wfp, Wfl, blin_eff, y2);
    bn_stats_kernel<128><<<1024, 256, 0, stream>>>(y2, P2s, P2q);
    finA_kernel<128><<<64, 128, 0, stream>>>(P2s, P2q, A2s, A2q);
    fin_kernel<128><<<1, 128, 0, stream>>>(A2s, A2q, bn2g, bn2b, sc2, sh2);
    pool_part_kernel<<<1024, 128, 0, stream>>>(y2, sc2, sh2, Pp);
    pool_fin_kernel<<<NGRAPH, 128, 0, stream>>>(Pp, out);
}

// Round 13
// 181.090 us; speedup vs baseline: 3.0532x; 1.0320x over previous
//
#include <hip/hip_runtime.h>
#include <math.h>

// PNANet on MI355X, round 13: bf16 -> fp16 datapath (same-rate MFMA, packed VALU).
//  * b2 agg: packed h2 stats (v_pk_*_f16) -> ~half the agg VALU; sd finalized fp32.
//  * all frag weights / uv2 / LDS tiles fp16; mfma_f32_16x16x32_f16.
//  * f32->f16 = 1-op v_cvt (vs 4-op bf16 RNE). Structure identical to round 12.

#define NGRAPH 128
#define NPG    512
#define NN     (NGRAPH*NPG)   // 65536
#define KNB    7

constexpr double AVG_DEG_LOG_D = 2.0239670479173344;  // (100*ln6+200*ln7+700*ln8)/1000
constexpr double LOG8_D        = 2.0794415416798357;

typedef _Float16 f16x8 __attribute__((ext_vector_type(8)));
typedef _Float16 h2    __attribute__((ext_vector_type(2)));
typedef float    f32x4 __attribute__((ext_vector_type(4)));

__device__ __forceinline__ unsigned short f2h(float x) {
    _Float16 h = (_Float16)x;
    return __builtin_bit_cast(unsigned short, h);
}

// ---------------------------------------------------------------- weight prep
__global__ __launch_bounds__(256) void prep_kernel(
    const float* __restrict__ Wpost1, const float* __restrict__ Wpost2,
    const float* __restrict__ Wpre2,  const float* __restrict__ Wlin2,
    const float* __restrict__ Wlin1,  const float* __restrict__ bpost1,
    const float* __restrict__ blin1,
    const float* __restrict__ bpost2, const float* __restrict__ blin2,
    unsigned short* __restrict__ Wf1p, unsigned short* __restrict__ Wf1l,
    float* __restrict__ blin1_eff,
    unsigned short* __restrict__ Wfuv,
    unsigned short* __restrict__ Wfp, unsigned short* __restrict__ Wfl,
    float* __restrict__ blin_eff)
{
    const float AMP = (float)(LOG8_D / AVG_DEG_LOG_D);
    const float ATT = (float)(AVG_DEG_LOG_D / LOG8_D);
    for (int i = blockIdx.x*256 + threadIdx.x; i < 98496; i += gridDim.x*256) {
        if (i < 4096) {
            // Wf1p: [t][kk<2][lane<64][j<8]; k = kk*32+(lane>>4)*8+j; col = lane&15
            int t = i >> 10, kk = (i >> 9) & 1, lane = (i >> 3) & 63, j = i & 7;
            int k = kk*32 + ((lane >> 4) << 3) + j;
            int col = lane & 15;
            float val;
            if (k < 8)       val = Wpost1[(t*104 + k)*16 + col];
            else if (k < 40) {
                int g2 = k - 8;
                val = Wpost1[(t*104 +  8 + g2)*16 + col]
                    + AMP*Wpost1[(t*104 + 40 + g2)*16 + col]
                    + ATT*Wpost1[(t*104 + 72 + g2)*16 + col];
            } else val = 0.f;
            Wf1p[i] = f2h(val);
        } else if (i < 8192) {
            // Wf1l: [kk<2][tile<4][lane<64][j<8]
            int jj = i - 4096;
            int kk = jj >> 11, tile = (jj >> 9) & 3, lane = (jj >> 3) & 63, j = jj & 7;
            int k = kk*32 + ((lane >> 4) << 3) + j;
            int col = tile*16 + (lane & 15);
            Wf1l[jj] = f2h(Wlin1[k*64 + col]);
        } else if (i < 8256) {
            // blin1_eff[c] = blin1[c] + sum_o bpost1[o]*Wlin1[o][c]
            int c = i - 8192;
            float s = blin1[c];
            for (int o = 0; o < 64; ++o) s += bpost1[o]*Wlin1[o*64 + c];
            blin1_eff[c] = s;
        } else if (i < 41024) {
            // Wfuv: [kk<2][ct<32][lane<64][j<8] f16; col = ct*16+(lane&15) in [0,512) = u||v
            int jj = i - 8256;
            int kk = jj >> 14, ct = (jj >> 9) & 31, lane = (jj >> 3) & 63, jf = jj & 7;
            int k   = kk*32 + ((lane >> 4) << 3) + jf;
            int col = ct*16 + (lane & 15);
            float val;
            if (col < 256) { int t = col >> 6, f = col & 63; val = Wpre2[(t*128 +      k)*64 + f]; }
            else { int c2 = col - 256; int t = c2 >> 6, f = c2 & 63; val = Wpre2[(t*128 + 64 + k)*64 + f]; }
            Wfuv[jj] = f2h(val);
        } else if (i < 81984) {
            // Wfrag_post: [t][kk<10][c<2][lane<64][j<8], f16
            int jj = i - 41024;
            int t = jj / 10240, r = jj % 10240;
            int kk = r / 1024, r2 = r % 1024;
            int c = r2 >> 9, lane = (r2 >> 3) & 63, jf = r2 & 7;
            int G   = kk*32 + ((lane >> 4) << 3) + jf;
            int col = c*16 + (lane & 15);
            float val;
            if (G < 64) val = Wpost2[(t*832 + G)*32 + col];
            else {
                int g2 = G - 64;
                val = Wpost2[(t*832 +  64 + g2)*32 + col]
                    + AMP*Wpost2[(t*832 + 320 + g2)*32 + col]
                    + ATT*Wpost2[(t*832 + 576 + g2)*32 + col];
            }
            Wfp[jj] = f2h(val);
        } else if (i < 98368) {
            // Wfrag_lin: [kk<4][tile<8][lane<64][j<8], f16
            int jj = i - 81984;
            int kk = jj / 4096, r = jj % 4096;
            int tile = r >> 9, lane = (r >> 3) & 63, jf = r & 7;
            int k   = kk*32 + ((lane >> 4) << 3) + jf;
            int col = tile*16 + (lane & 15);
            Wfl[jj] = f2h(Wlin2[k*128 + col]);
        } else {
            // blin_eff[c] = blin2[c] + sum_o bpost2[o]*Wlin2[o][c]
            int c = i - 98368;
            float s = blin2[c];
            for (int o = 0; o < 128; ++o) s += bpost2[o]*Wlin2[o*128 + c];
            blin_eff[c] = s;
        }
    }
}

// ---------------------------------------------------------------- kNN (k=7); 2 blocks per graph
__global__ __launch_bounds__(256) void knn_kernel(const float* __restrict__ pos, int* __restrict__ nbr)
{
    __shared__ float4 posS[NPG];
    const int g    = blockIdx.x >> 1;
    const int half = blockIdx.x & 1;
    const int gb   = g * NPG;
    for (int j = threadIdx.x; j < NPG; j += 256)
        posS[j] = make_float4(pos[(gb+j)*3+0], pos[(gb+j)*3+1], pos[(gb+j)*3+2], 0.f);
    __syncthreads();
    const int i = half*256 + threadIdx.x;
    const float4 pi = posS[i];
    float bd[KNB]; int bi[KNB];
#pragma unroll
    for (int e = 0; e < KNB; ++e) { bd[e] = 3.0e38f; bi[e] = -1; }
#pragma unroll 4
    for (int j = 0; j < NPG; ++j) {
        float4 pj = posS[j];
        float dx = pi.x - pj.x, dy = pi.y - pj.y, dz = pi.z - pj.z;
        float d2 = __fadd_rn(__fadd_rn(__fmul_rn(dx,dx), __fmul_rn(dy,dy)), __fmul_rn(dz,dz));
        if (j == i) d2 = __builtin_inff();
        bool cmp[KNB];
#pragma unroll
        for (int e = 0; e < KNB; ++e) cmp[e] = d2 < bd[e];
#pragma unroll
        for (int e = KNB-1; e >= 1; --e) {
            bd[e] = cmp[e-1] ? bd[e-1] : (cmp[e] ? d2 : bd[e]);
            bi[e] = cmp[e-1] ? bi[e-1] : (cmp[e] ? j  : bi[e]);
        }
        bd[0] = cmp[0] ? d2 : bd[0];
        bi[0] = cmp[0] ? j  : bi[0];
    }
#pragma unroll
    for (int e = 0; e < KNB; ++e) nbr[(gb+i)*KNB + e] = gb + bi[e];
}

// ---------------------------------------------------------------- layer1: u1,v1 [N,32]
__global__ __launch_bounds__(256) void a1_kernel(
    const float* __restrict__ x, const float* __restrict__ Wpre1, const float* __restrict__ bpre1,
    float* __restrict__ u1, float* __restrict__ v1)
{
    __shared__ float wS[512];
    __shared__ float bS[32];
    const int tid = threadIdx.x;
    wS[tid] = Wpre1[tid]; wS[tid+256] = Wpre1[tid+256];
    if (tid < 32) bS[tid] = bpre1[tid];
    __syncthreads();
    const int n  = blockIdx.x*8 + (tid>>5);
    const int tf = tid & 31;
    const int t = tf >> 3, f = tf & 7;
    float u = bS[tf], v = 0.f;
#pragma unroll
    for (int e = 0; e < 8; ++e) {
        float xv = x[n*8+e];
        u += xv * wS[(t*16 + e)*8 + f];
        v += xv * wS[(t*16 + 8 + e)*8 + f];
    }
    u1[n*32+tf] = u;
    v1[n*32+tf] = v;
}

// ---------------------------------------------------------------- layer1 fused (MFMA f16): agg + post + lin -> y1 [N,64]
// act rows (node*4+t): [x(8) | mean8 min8 max8 std8 | zeros(24)] K=64, pitch 72 (f16)
__global__ __launch_bounds__(256) void b1_kernel(
    const float* __restrict__ x, const int* __restrict__ nbr,
    const float* __restrict__ u1, const float* __restrict__ v1,
    const unsigned short* __restrict__ Wf1p, const unsigned short* __restrict__ Wf1l,
    const float* __restrict__ blin1_eff,
    float* __restrict__ y1)
{
    __shared__ int nbrsS[112];
    __shared__ __align__(16) unsigned short actS[64*72];
    __shared__ __align__(16) unsigned short postS[16*72];
    const int tid  = threadIdx.x;
    const int base = blockIdx.x * 16;
    if (tid < 112) nbrsS[tid] = nbr[base*7 + tid];
    // zero pad cols 40..63 (disjoint from agg/x fill regions)
    for (int i = tid; i < 384; i += 256) {
        int r = i / 6, gq = i - 6*r;
        *(ushort4*)&actS[r*72 + 40 + gq*4] = make_ushort4(0,0,0,0);
    }
    // x part: cols 0..7 for all 4 tower rows
#pragma unroll
    for (int it = 0; it < 2; ++it) {
        int i = tid + it*256;
        int n = i >> 5, r2 = i & 31, t = r2 >> 3, f = r2 & 7;
        actS[(n*4 + t)*72 + f] = f2h(x[(base+n)*8 + f]);
    }
    __syncthreads();   // nbrsS visible to all threads
    // agg part: thread = (node, col-pair); float2 gathers from fp32 u1/v1
    {
        const int n = tid >> 4, cp = tid & 15;
        const int tf0 = cp*2, t = tf0 >> 3, f0 = tf0 & 7;
        float2 uu = *(const float2*)&u1[(base+n)*32 + tf0];
        float s0=0.f,s1=0.f,q0=0.f,q1=0.f;
        float mn0=3e38f,mn1=3e38f,mx0=-3e38f,mx1=-3e38f;
#pragma unroll
        for (int e = 0; e < 7; ++e) {
            float2 vv = *(const float2*)&v1[nbrsS[n*7+e]*32 + tf0];
            s0 += vv.x; q0 += vv.x*vv.x; mn0 = fminf(mn0, vv.x); mx0 = fmaxf(mx0, vv.x);
            s1 += vv.y; q1 += vv.y*vv.y; mn1 = fminf(mn1, vv.y); mx1 = fmaxf(mx1, vv.y);
        }
        float me0 = s0*(1.f/7.f), me1 = s1*(1.f/7.f);
        float sd0 = sqrtf(fmaxf(q0*(1.f/7.f) - me0*me0, 0.f) + 1e-5f);
        float sd1 = sqrtf(fmaxf(q1*(1.f/7.f) - me1*me1, 0.f) + 1e-5f);
        const int row = (n*4 + t)*72;
        ushort2 w_;
        w_.x = f2h(uu.x + me0); w_.y = f2h(uu.y + me1); *(ushort2*)&actS[row +  8 + f0] = w_;
        w_.x = f2h(uu.x + mn0); w_.y = f2h(uu.y + mn1); *(ushort2*)&actS[row + 16 + f0] = w_;
        w_.x = f2h(uu.x + mx0); w_.y = f2h(uu.y + mx1); *(ushort2*)&actS[row + 24 + f0] = w_;
        w_.x = f2h(sd0);        w_.y = f2h(sd1);        *(ushort2*)&actS[row + 32 + f0] = w_;
    }
    __syncthreads();
    const int l = tid & 63, w = tid >> 6;
    const int lr = l & 15, lk = l >> 4;
    // post GEMM: wave w = tower w; K=64 (2 chunks), out 16 cols
    f32x4 acc = {0.f,0.f,0.f,0.f};
    {
        const f16x8* WB = (const f16x8*)Wf1p;
#pragma unroll
        for (int kk = 0; kk < 2; ++kk) {
            f16x8 a = *(const f16x8*)&actS[(lr*4 + w)*72 + kk*32 + lk*8];
            f16x8 b = WB[(w*2 + kk)*64 + l];
            acc = __builtin_amdgcn_mfma_f32_16x16x32_f16(a, b, acc, 0, 0, 0);
        }
    }
#pragma unroll
    for (int j = 0; j < 4; ++j)
        postS[(lk*4 + j)*72 + w*16 + lr] = f2h(acc[j]);
    __syncthreads();
    // lin GEMM: wave w = out col-tile w; K=64 (2 chunks)
    f32x4 d = {0.f,0.f,0.f,0.f};
    {
        const f16x8* WB = (const f16x8*)Wf1l;
#pragma unroll
        for (int kk = 0; kk < 2; ++kk) {
            f16x8 a = *(const f16x8*)&postS[lr*72 + kk*32 + lk*8];
            f16x8 b = WB[(kk*4 + w)*64 + l];
            d = __builtin_amdgcn_mfma_f32_16x16x32_f16(a, b, d, 0, 0, 0);
        }
    }
    const float be = blin1_eff[w*16 + lr];
#pragma unroll
    for (int j = 0; j < 4; ++j)
        y1[(base + lk*4 + j)*64 + w*16 + lr] = d[j] + be;
}

// ---------------------------------------------------------------- BN stats: 1024 blocks, float4, LDS tree -> partials
template<int C>
__global__ __launch_bounds__(256) void bn_stats_kernel(
    const float* __restrict__ y, float* __restrict__ Ps, float* __restrict__ Pq)
{
    constexpr int IT     = (NN/1024)*(C/4)/256;   // C=64 -> 4, C=128 -> 8
    constexpr int GROUPS = C/4;
    constexpr int REPS   = 256/GROUPS;
    const int tid = threadIdx.x;
    const float4* y4 = (const float4*)y + (size_t)blockIdx.x*256*IT;
    float4 s = make_float4(0.f,0.f,0.f,0.f), q = make_float4(0.f,0.f,0.f,0.f);
#pragma unroll
    for (int it = 0; it < IT; ++it) {
        float4 v = y4[it*256 + tid];
        s.x += v.x; s.y += v.y; s.z += v.z; s.w += v.w;
        q.x += v.x*v.x; q.y += v.y*v.y; q.z += v.z*v.z; q.w += v.w*v.w;
    }
    __shared__ float4 sS[256], qS[256];
    sS[tid] = s; qS[tid] = q;
    __syncthreads();
#pragma unroll
    for (int step = REPS/2; step >= 1; step >>= 1) {
        if (tid < step*GROUPS) {
            float4 s2 = sS[tid + step*GROUPS], q2 = qS[tid + step*GROUPS];
            float4 ss = sS[tid], qq = qS[tid];
            ss.x += s2.x; ss.y += s2.y; ss.z += s2.z; ss.w += s2.w;
            qq.x += q2.x; qq.y += q2.y; qq.z += q2.z; qq.w += q2.w;
            sS[tid] = ss; qS[tid] = qq;
        }
        __syncthreads();
    }
    if (tid < GROUPS) {
        ((float4*)&Ps[(size_t)blockIdx.x*C])[tid] = sS[tid];
        ((float4*)&Pq[(size_t)blockIdx.x*C])[tid] = qS[tid];
    }
}

// ---------------------------------------------------------------- finA: 64 blocks, sum 16 partial-rows
template<int C>
__global__ __launch_bounds__(C) void finA_kernel(
    const float* __restrict__ Ps, const float* __restrict__ Pq,
    float* __restrict__ As, float* __restrict__ Aq)
{
    const int c = threadIdx.x, b = blockIdx.x;
    float s = 0.f, q = 0.f;
#pragma unroll
    for (int i = 0; i < 16; ++i) {
        s += Ps[(b*16 + i)*C + c];
        q += Pq[(b*16 + i)*C + c];
    }
    As[b*C + c] = s;
    Aq[b*C + c] = q;
}

// ---------------------------------------------------------------- finalize BN -> scale/shift (sums 64)
template<int C>
__global__ __launch_bounds__(C) void fin_kernel(
    const float* __restrict__ As, const float* __restrict__ Aq,
    const float* __restrict__ g, const float* __restrict__ b,
    float* __restrict__ scO, float* __restrict__ shO)
{
    const int c = threadIdx.x;
    float s = 0.f, q = 0.f;
#pragma unroll 8
    for (int i = 0; i < 64; ++i) { s += As[i*C + c]; q += Aq[i*C + c]; }
    const float inv = 1.f/(float)NN;
    float mu  = s*inv;
    float var = q*inv - mu*mu;
    float sc  = g[c]*rsqrtf(var + 1e-5f);
    scO[c] = sc;
    shO[c] = b[c] - mu*sc;
}

// ---------------------------------------------------------------- layer2 pre (MFMA f16): uv2 [N][512] f16 = [u||v]
__global__ __launch_bounds__(256) void a2_kernel(
    const float* __restrict__ y1raw, const float* __restrict__ sc1, const float* __restrict__ sh1,
    const unsigned short* __restrict__ Wfuv, const float* __restrict__ bpre2,
    unsigned short* __restrict__ uv2)
{
    __shared__ __align__(16) unsigned short a1S[64*72];   // 64 nodes x 64 f16, pitch 72
    __shared__ float biasS[256];
    const int tid  = threadIdx.x;
    const int base = blockIdx.x * 64;
    biasS[tid] = bpre2[tid];
#pragma unroll
    for (int it = 0; it < 4; ++it) {
        int i = tid + it*256;                       // over 1024 float4 = 64 rows x 16 f4
        float4 vv = ((const float4*)y1raw)[blockIdx.x*1024 + i];
        int n = i >> 4, c0 = (i & 15)*4;
        float c_[4] = {vv.x, vv.y, vv.z, vv.w};
#pragma unroll
        for (int j = 0; j < 4; ++j) {
            int c = c0 + j;
            a1S[n*72 + c] = f2h(fmaxf(c_[j]*sc1[c] + sh1[c], 0.f));
        }
    }
    __syncthreads();
    const int l = tid & 63, w = tid >> 6;
    const int lr = l & 15, lk = l >> 4;
    const f16x8 a0  = *(const f16x8*)&a1S[(w*16 + lr)*72 +      lk*8];
    const f16x8 a1f = *(const f16x8*)&a1S[(w*16 + lr)*72 + 32 + lk*8];
    const f16x8* WB = (const f16x8*)Wfuv;
#pragma unroll 4
    for (int ct = 0; ct < 32; ++ct) {
        f32x4 acc = {0.f,0.f,0.f,0.f};
        f16x8 b0 = WB[ct*64 + l];
        f16x8 b1 = WB[(32 + ct)*64 + l];
        acc = __builtin_amdgcn_mfma_f32_16x16x32_f16(a0,  b0, acc, 0, 0, 0);
        acc = __builtin_amdgcn_mfma_f32_16x16x32_f16(a1f, b1, acc, 0, 0, 0);
        const int col = ct*16 + lr;
        const float bias = (ct < 16) ? biasS[col] : 0.f;
#pragma unroll
        for (int j = 0; j < 4; ++j)
            uv2[(base + w*16 + lk*4 + j)*512 + col] = f2h(acc[j] + bias);
    }
}

// ---------------------------------------------------------------- layer2 fused (MFMA f16): agg + post + lin -> y2 [N,128]
__global__ __launch_bounds__(256) void b2_kernel(
    const int* __restrict__ nbr, const float* __restrict__ y1raw,
    const float* __restrict__ sc1, const float* __restrict__ sh1,
    const unsigned short* __restrict__ uv2,
    const unsigned short* __restrict__ Wfp, const unsigned short* __restrict__ Wfl,
    const float* __restrict__ blin_eff,
    float* __restrict__ y2)
{
    __shared__ int nbrsS[112];
    __shared__ __align__(16) unsigned short a1S[16*72];     // 16 nodes x 64 a1 (f16), pitch 72
    __shared__ __align__(16) unsigned short aggS[64*264];   // rows (t*16+node), 256 agg vals, pitch 264
    __shared__ __align__(16) unsigned short postS[16*136];  // 16 nodes x 128 post (f16), pitch 136

    const int tid = threadIdx.x;
    // XCD-affine swizzle: 32 blocks/graph, graph -> XCD (graph & 7)
    const int ob   = blockIdx.x;
    const int xcd  = ob & 7, slot = ob >> 3;
    const int gph  = ((slot >> 5) << 3) + xcd;
    const int sub  = slot & 31;
    const int base = gph*NPG + sub*16;

    if (tid < 112) nbrsS[tid] = nbr[base*7 + tid];
    for (int i = tid; i < 1024; i += 256) {
        int c = i & 63, n = i >> 6;
        float a = fmaxf(y1raw[base*64 + i]*sc1[c] + sh1[c], 0.f);
        a1S[n*72 + c] = f2h(a);
    }
    __syncthreads();
    // ---- aggregation: packed-h2 stats, 4 cols/thread, 4 nodes/iter
    {
        const int ns = tid >> 6, cg = tid & 63;
        const int t = cg >> 4, f0 = (cg & 15) * 4;
        const h2 inv7 = { (_Float16)(1.f/7.f), (_Float16)(1.f/7.f) };
#pragma unroll
        for (int it = 0; it < 4; ++it) {
            const int ln = it*4 + ns;
            uint2 uu = *(const uint2*)&uv2[(size_t)(base+ln)*512 + cg*4];
            h2 u01 = __builtin_bit_cast(h2, uu.x);
            h2 u23 = __builtin_bit_cast(h2, uu.y);
            h2 z = { (_Float16)0.f, (_Float16)0.f };
            h2 s01 = z, s23 = z, q01 = z, q23 = z;
            h2 mn01 = { (_Float16)65504.f, (_Float16)65504.f }, mn23 = mn01;
            h2 mx01 = { (_Float16)-65504.f, (_Float16)-65504.f }, mx23 = mx01;
#pragma unroll
            for (int e = 0; e < 7; ++e) {
                uint2 vv = *(const uint2*)&uv2[(size_t)nbrsS[ln*7+e]*512 + 256 + cg*4];
                h2 v01 = __builtin_bit_cast(h2, vv.x);
                h2 v23 = __builtin_bit_cast(h2, vv.y);
                s01 += v01; s23 += v23;
                q01 += v01*v01; q23 += v23*v23;
                mn01 = __builtin_elementwise_min(mn01, v01);
                mn23 = __builtin_elementwise_min(mn23, v23);
                mx01 = __builtin_elementwise_max(mx01, v01);
                mx23 = __builtin_elementwise_max(mx23, v23);
            }
            h2 me01 = s01*inv7, me23 = s23*inv7;
            h2 om01 = u01 + me01, om23 = u23 + me23;
            h2 on01 = u01 + mn01, on23 = u23 + mn23;
            h2 ox01 = u01 + mx01, ox23 = u23 + mx23;
            // sd in fp32 (cancellation safety)
            float m0 = (float)me01[0], m1 = (float)me01[1];
            float m2 = (float)me23[0], m3 = (float)me23[1];
            float sd0 = sqrtf(fmaxf(fmaf((float)q01[0], 1.f/7.f, -m0*m0), 0.f) + 1e-5f);
            float sd1 = sqrtf(fmaxf(fmaf((float)q01[1], 1.f/7.f, -m1*m1), 0.f) + 1e-5f);
            float sd2 = sqrtf(fmaxf(fmaf((float)q23[0], 1.f/7.f, -m2*m2), 0.f) + 1e-5f);
            float sd3 = sqrtf(fmaxf(fmaf((float)q23[1], 1.f/7.f, -m3*m3), 0.f) + 1e-5f);
            h2 sd01 = { (_Float16)sd0, (_Float16)sd1 };
            h2 sd23 = { (_Float16)sd2, (_Float16)sd3 };
            const int ro = (t*16 + ln)*264 + f0;    // row = tower*16 + node
            *(uint2*)&aggS[ro      ] = make_uint2(__builtin_bit_cast(unsigned, om01), __builtin_bit_cast(unsigned, om23));
            *(uint2*)&aggS[ro +  64] = make_uint2(__builtin_bit_cast(unsigned, on01), __builtin_bit_cast(unsigned, on23));
            *(uint2*)&aggS[ro + 128] = make_uint2(__builtin_bit_cast(unsigned, ox01), __builtin_bit_cast(unsigned, ox23));
            *(uint2*)&aggS[ro + 192] = make_uint2(__builtin_bit_cast(unsigned, sd01), __builtin_bit_cast(unsigned, sd23));
        }
    }
    __syncthreads();
    const int l = tid & 63, w = tid >> 6;
    const int lr = l & 15, lk = l >> 4;
    // ---- post GEMM (tower w): K=320 = 2 a1-chunks + 8 agg-chunks
    f32x4 acc0 = {0.f,0.f,0.f,0.f}, acc1 = {0.f,0.f,0.f,0.f};
    {
        const f16x8* WB = (const f16x8*)Wfp;
#pragma unroll
        for (int kk = 0; kk < 10; ++kk) {
            f16x8 a;
            if (kk < 2) a = *(const f16x8*)&a1S[lr*72 + kk*32 + lk*8];
            else        a = *(const f16x8*)&aggS[(w*16 + lr)*264 + (kk-2)*32 + lk*8];
            f16x8 b0 = WB[((w*10 + kk)*2 + 0)*64 + l];
            f16x8 b1 = WB[((w*10 + kk)*2 + 1)*64 + l];
            acc0 = __builtin_amdgcn_mfma_f32_16x16x32_f16(a, b0, acc0, 0, 0, 0);
            acc1 = __builtin_amdgcn_mfma_f32_16x16x32_f16(a, b1, acc1, 0, 0, 0);
        }
    }
#pragma unroll
    for (int j = 0; j < 4; ++j) {
        const int row = lk*4 + j;
        postS[row*136 + w*32 +      lr] = f2h(acc0[j]);
        postS[row*136 + w*32 + 16 + lr] = f2h(acc1[j]);
    }
    __syncthreads();
    // ---- lin GEMM (cols 32w..32w+31): K=128
    f32x4 d0 = {0.f,0.f,0.f,0.f}, d1 = {0.f,0.f,0.f,0.f};
    {
        const f16x8* WB = (const f16x8*)Wfl;
#pragma unroll
        for (int kk = 0; kk < 4; ++kk) {
            f16x8 a = *(const f16x8*)&postS[lr*136 + kk*32 + lk*8];
            f16x8 b0 = WB[(kk*8 + 2*w + 0)*64 + l];
            f16x8 b1 = WB[(kk*8 + 2*w + 1)*64 + l];
            d0 = __builtin_amdgcn_mfma_f32_16x16x32_f16(a, b0, d0, 0, 0, 0);
            d1 = __builtin_amdgcn_mfma_f32_16x16x32_f16(a, b1, d1, 0, 0, 0);
        }
    }
    const float be0 = blin_eff[w*32 +      lr];
    const float be1 = blin_eff[w*32 + 16 + lr];
#pragma unroll
    for (int j = 0; j < 4; ++j) {
        const int row = lk*4 + j;
        y2[(base + row)*128 + w*32 +      lr] = d0[j] + be0;
        y2[(base + row)*128 + w*32 + 16 + lr] = d1[j] + be1;
    }
}

// ---------------------------------------------------------------- pool part: BN2+relu+64-row partial sums (1024 blocks)
__global__ __launch_bounds__(128) void pool_part_kernel(
    const float* __restrict__ y2, const float* __restrict__ sc2, const float* __restrict__ sh2,
    float* __restrict__ Pp)
{
    const int c = threadIdx.x;
    const int b = blockIdx.x;                 // b = g*8 + chunk
    const float sc = sc2[c];
    const float sh = sh2[c];
    float acc = 0.f;
    const size_t base = (size_t)b*64*128 + c;
#pragma unroll 4
    for (int i = 0; i < 64; ++i)
        acc += fmaxf(y2[base + (size_t)i*128]*sc + sh, 0.f);
    Pp[b*128 + c] = acc;
}

// ---------------------------------------------------------------- pool finalize: sum 8 chunks -> out [128,128]
__global__ __launch_bounds__(128) void pool_fin_kernel(
    const float* __restrict__ Pp, float* __restrict__ out)
{
    const int c = threadIdx.x, g = blockIdx.x;
    float acc = 0.f;
#pragma unroll
    for (int i = 0; i < 8; ++i) acc += Pp[(g*8 + i)*128 + c];
    out[g*128 + c] = acc * (1.f/(float)NPG);
}

// ---------------------------------------------------------------- launcher
extern "C" void kernel_launch(void* const* d_in, const int* in_sizes, int n_in,
                              void* d_out, int out_size, void* d_ws, size_t ws_size,
                              hipStream_t stream)
{
    const float* x      = (const float*)d_in[0];
    const float* pos    = (const float*)d_in[1];
    const float* Wpre1  = (const float*)d_in[2];
    const float* bpre1  = (const float*)d_in[3];
    const float* Wpost1 = (const float*)d_in[4];
    const float* bpost1 = (const float*)d_in[5];
    const float* Wlin1  = (const float*)d_in[6];
    const float* blin1  = (const float*)d_in[7];
    const float* bn1g   = (const float*)d_in[8];
    const float* bn1b   = (const float*)d_in[9];
    const float* Wpre2  = (const float*)d_in[10];
    const float* bpre2  = (const float*)d_in[11];
    const float* Wpost2 = (const float*)d_in[12];
    const float* bpost2 = (const float*)d_in[13];
    const float* Wlin2  = (const float*)d_in[14];
    const float* blin2  = (const float*)d_in[15];
    const float* bn2g   = (const float*)d_in[16];
    const float* bn2b   = (const float*)d_in[17];
    float* out = (float*)d_out;

    char* ws = (char*)d_ws;
    size_t off = 0;
    auto alloc = [&](size_t bytes) { void* p = ws + off; off += (bytes + 255) & ~(size_t)255; return p; };
    int*   nbr   = (int*)  alloc((size_t)NN*7*4);
    float* u1    = (float*)alloc((size_t)NN*32*4);
    float* v1    = (float*)alloc((size_t)NN*32*4);
    float* y1    = (float*)alloc((size_t)NN*64*4);            // raw (pre-BN)
    unsigned short* uv2 = (unsigned short*)alloc((size_t)NN*512*2);   // f16 [u||v]
    float* y2    = (float*)alloc((size_t)NN*128*4);           // raw (pre-BN)
    unsigned short* Wf1p = (unsigned short*)alloc(4096*2);
    unsigned short* Wf1l = (unsigned short*)alloc(4096*2);
    float* blin1_eff = (float*)alloc(64*4);
    unsigned short* Wfuv = (unsigned short*)alloc(32768*2);
    unsigned short* Wfp  = (unsigned short*)alloc(40960*2);
    unsigned short* Wfl  = (unsigned short*)alloc(16384*2);
    float* blin_eff = (float*)alloc(128*4);
    float* P1s   = (float*)alloc(1024*64*4);
    float* P1q   = (float*)alloc(1024*64*4);
    float* A1s   = (float*)alloc(64*64*4);
    float* A1q   = (float*)alloc(64*64*4);
    float* sc1   = (float*)alloc(64*4);
    float* sh1   = (float*)alloc(64*4);
    float* P2s   = (float*)alloc(1024*128*4);
    float* P2q   = (float*)alloc(1024*128*4);
    float* A2s   = (float*)alloc(64*128*4);
    float* A2q   = (float*)alloc(64*128*4);
    float* sc2   = (float*)alloc(128*4);
    float* sh2   = (float*)alloc(128*4);
    float* Pp    = (float*)alloc(1024*128*4);

    prep_kernel<<<128, 256, 0, stream>>>(Wpost1, Wpost2, Wpre2, Wlin2, Wlin1, bpost1, blin1,
                                         bpost2, blin2,
                                         Wf1p, Wf1l, blin1_eff, Wfuv, Wfp, Wfl, blin_eff);
    knn_kernel<<<NGRAPH*2, 256, 0, stream>>>(pos, nbr);
    a1_kernel<<<NN/8, 256, 0, stream>>>(x, Wpre1, bpre1, u1, v1);
    b1_kernel<<<NN/16, 256, 0, stream>>>(x, nbr, u1, v1, Wf1p, Wf1l, blin1_eff, y1);
    bn_stats_kernel<64><<<1024, 256, 0, stream>>>(y1, P1s, P1q);
    finA_kernel<64><<<64, 64, 0, stream>>>(P1s, P1q, A1s, A1q);
    fin_kernel<64><<<1, 64, 0, stream>>>(A1s, A1q, bn1g, bn1b, sc1, sh1);
    a2_kernel<<<NN/64, 256, 0, stream>>>(y1, sc1, sh1, Wfuv, bpre2, uv2);
    b2_kernel<<<NN/16, 256, 0, stream>>>(nbr, y1, sc1, sh1, uv2, Wfp, Wfl, blin_eff, y2);
    bn_stats_kernel<128><<<1024, 256, 0, stream>>>(y2, P2s, P2q);
    finA_kernel<128><<<64, 128, 0, stream>>>(P2s, P2q, A2s, A2q);
    fin_kernel<128><<<1, 128, 0, stream>>>(A2s, A2q, bn2g, bn2b, sc2, sh2);
    pool_part_kernel<<<1024, 128, 0, stream>>>(y2, sc2, sh2, Pp);
    pool_fin_kernel<<<NGRAPH, 128, 0, stream>>>(Pp, out);
}

// Round 14
// 175.703 us; speedup vs baseline: 3.1468x; 1.0307x over previous
//
#include <hip/hip_runtime.h>
#include <math.h>

// PNANet on MI355X, round 14: kNN occupancy fix (was 1 wave/SIMD, 55us).
//  * knn_part: (node-half, cand-quarter) grid -> 1024 blocks; 128 cands/thread.
//  * knn_merge: 1 thread/node, merge 4x top-7 (stable ties via quarter-major order).
//  * everything else identical to round 13 (fp16 MFMA datapath).

#define NGRAPH 128
#define NPG    512
#define NN     (NGRAPH*NPG)   // 65536
#define KNB    7

constexpr double AVG_DEG_LOG_D = 2.0239670479173344;  // (100*ln6+200*ln7+700*ln8)/1000
constexpr double LOG8_D        = 2.0794415416798357;

typedef _Float16 f16x8 __attribute__((ext_vector_type(8)));
typedef _Float16 h2    __attribute__((ext_vector_type(2)));
typedef float    f32x4 __attribute__((ext_vector_type(4)));

__device__ __forceinline__ unsigned short f2h(float x) {
    _Float16 h = (_Float16)x;
    return __builtin_bit_cast(unsigned short, h);
}

// ---------------------------------------------------------------- weight prep
__global__ __launch_bounds__(256) void prep_kernel(
    const float* __restrict__ Wpost1, const float* __restrict__ Wpost2,
    const float* __restrict__ Wpre2,  const float* __restrict__ Wlin2,
    const float* __restrict__ Wlin1,  const float* __restrict__ bpost1,
    const float* __restrict__ blin1,
    const float* __restrict__ bpost2, const float* __restrict__ blin2,
    unsigned short* __restrict__ Wf1p, unsigned short* __restrict__ Wf1l,
    float* __restrict__ blin1_eff,
    unsigned short* __restrict__ Wfuv,
    unsigned short* __restrict__ Wfp, unsigned short* __restrict__ Wfl,
    float* __restrict__ blin_eff)
{
    const float AMP = (float)(LOG8_D / AVG_DEG_LOG_D);
    const float ATT = (float)(AVG_DEG_LOG_D / LOG8_D);
    for (int i = blockIdx.x*256 + threadIdx.x; i < 98496; i += gridDim.x*256) {
        if (i < 4096) {
            // Wf1p: [t][kk<2][lane<64][j<8]; k = kk*32+(lane>>4)*8+j; col = lane&15
            int t = i >> 10, kk = (i >> 9) & 1, lane = (i >> 3) & 63, j = i & 7;
            int k = kk*32 + ((lane >> 4) << 3) + j;
            int col = lane & 15;
            float val;
            if (k < 8)       val = Wpost1[(t*104 + k)*16 + col];
            else if (k < 40) {
                int g2 = k - 8;
                val = Wpost1[(t*104 +  8 + g2)*16 + col]
                    + AMP*Wpost1[(t*104 + 40 + g2)*16 + col]
                    + ATT*Wpost1[(t*104 + 72 + g2)*16 + col];
            } else val = 0.f;
            Wf1p[i] = f2h(val);
        } else if (i < 8192) {
            // Wf1l: [kk<2][tile<4][lane<64][j<8]
            int jj = i - 4096;
            int kk = jj >> 11, tile = (jj >> 9) & 3, lane = (jj >> 3) & 63, j = jj & 7;
            int k = kk*32 + ((lane >> 4) << 3) + j;
            int col = tile*16 + (lane & 15);
            Wf1l[jj] = f2h(Wlin1[k*64 + col]);
        } else if (i < 8256) {
            // blin1_eff[c] = blin1[c] + sum_o bpost1[o]*Wlin1[o][c]
            int c = i - 8192;
            float s = blin1[c];
            for (int o = 0; o < 64; ++o) s += bpost1[o]*Wlin1[o*64 + c];
            blin1_eff[c] = s;
        } else if (i < 41024) {
            // Wfuv: [kk<2][ct<32][lane<64][j<8] f16; col = ct*16+(lane&15) in [0,512) = u||v
            int jj = i - 8256;
            int kk = jj >> 14, ct = (jj >> 9) & 31, lane = (jj >> 3) & 63, jf = jj & 7;
            int k   = kk*32 + ((lane >> 4) << 3) + jf;
            int col = ct*16 + (lane & 15);
            float val;
            if (col < 256) { int t = col >> 6, f = col & 63; val = Wpre2[(t*128 +      k)*64 + f]; }
            else { int c2 = col - 256; int t = c2 >> 6, f = c2 & 63; val = Wpre2[(t*128 + 64 + k)*64 + f]; }
            Wfuv[jj] = f2h(val);
        } else if (i < 81984) {
            // Wfrag_post: [t][kk<10][c<2][lane<64][j<8], f16
            int jj = i - 41024;
            int t = jj / 10240, r = jj % 10240;
            int kk = r / 1024, r2 = r % 1024;
            int c = r2 >> 9, lane = (r2 >> 3) & 63, jf = r2 & 7;
            int G   = kk*32 + ((lane >> 4) << 3) + jf;
            int col = c*16 + (lane & 15);
            float val;
            if (G < 64) val = Wpost2[(t*832 + G)*32 + col];
            else {
                int g2 = G - 64;
                val = Wpost2[(t*832 +  64 + g2)*32 + col]
                    + AMP*Wpost2[(t*832 + 320 + g2)*32 + col]
                    + ATT*Wpost2[(t*832 + 576 + g2)*32 + col];
            }
            Wfp[jj] = f2h(val);
        } else if (i < 98368) {
            // Wfrag_lin: [kk<4][tile<8][lane<64][j<8], f16
            int jj = i - 81984;
            int kk = jj / 4096, r = jj % 4096;
            int tile = r >> 9, lane = (r >> 3) & 63, jf = r & 7;
            int k   = kk*32 + ((lane >> 4) << 3) + jf;
            int col = tile*16 + (lane & 15);
            Wfl[jj] = f2h(Wlin2[k*128 + col]);
        } else {
            // blin_eff[c] = blin2[c] + sum_o bpost2[o]*Wlin2[o][c]
            int c = i - 98368;
            float s = blin2[c];
            for (int o = 0; o < 128; ++o) s += bpost2[o]*Wlin2[o*128 + c];
            blin_eff[c] = s;
        }
    }
}

// ---------------------------------------------------------------- kNN part: (node-half, cand-quarter); 128 cands/thread
__global__ __launch_bounds__(256) void knn_part_kernel(const float* __restrict__ pos, float2* __restrict__ part)
{
    __shared__ float4 cposS[128];
    const int b = blockIdx.x;
    const int g = b >> 3, h = (b >> 2) & 1, q = b & 3;
    const int gb = g * NPG;
    const int cbase = q * 128;
    if (threadIdx.x < 128) {
        int j = cbase + threadIdx.x;
        cposS[threadIdx.x] = make_float4(pos[(gb+j)*3+0], pos[(gb+j)*3+1], pos[(gb+j)*3+2], 0.f);
    }
    __syncthreads();
    const int i = h*256 + threadIdx.x;       // local node id
    const float px = pos[(gb+i)*3+0], py = pos[(gb+i)*3+1], pz = pos[(gb+i)*3+2];
    float bd[KNB]; int bi[KNB];
#pragma unroll
    for (int e = 0; e < KNB; ++e) { bd[e] = 3.0e38f; bi[e] = -1; }
#pragma unroll 4
    for (int j = 0; j < 128; ++j) {
        float4 pj = cposS[j];
        float dx = px - pj.x, dy = py - pj.y, dz = pz - pj.z;
        float d2 = __fadd_rn(__fadd_rn(__fmul_rn(dx,dx), __fmul_rn(dy,dy)), __fmul_rn(dz,dz));
        if (cbase + j == i) d2 = __builtin_inff();
        bool cmp[KNB];
#pragma unroll
        for (int e = 0; e < KNB; ++e) cmp[e] = d2 < bd[e];   // strict <: stable ties
#pragma unroll
        for (int e = KNB-1; e >= 1; --e) {
            bd[e] = cmp[e-1] ? bd[e-1] : (cmp[e] ? d2 : bd[e]);
            bi[e] = cmp[e-1] ? bi[e-1] : (cmp[e] ? cbase + j : bi[e]);
        }
        bd[0] = cmp[0] ? d2 : bd[0];
        bi[0] = cmp[0] ? cbase + j : bi[0];
    }
    float2* dst = &part[((size_t)(g*NPG + i)*4 + q)*KNB];
#pragma unroll
    for (int e = 0; e < KNB; ++e) dst[e] = make_float2(bd[e], __int_as_float(bi[e]));
}

// ---------------------------------------------------------------- kNN merge: 1 thread/node, 28 pairs -> top-7
__global__ __launch_bounds__(256) void knn_merge_kernel(const float2* __restrict__ part, int* __restrict__ nbr)
{
    const int n = blockIdx.x*256 + threadIdx.x;     // global node
    const float4* p4 = (const float4*)&part[(size_t)n*28];
    float bd[KNB]; int bi[KNB];
#pragma unroll
    for (int e = 0; e < KNB; ++e) { bd[e] = 3.0e38f; bi[e] = -1; }
#pragma unroll
    for (int m4 = 0; m4 < 14; ++m4) {
        float4 pr = p4[m4];
#pragma unroll
        for (int half = 0; half < 2; ++half) {
            float d2  = half ? pr.z : pr.x;
            int   idx = __float_as_int(half ? pr.w : pr.y);
            bool cmp[KNB];
#pragma unroll
            for (int e = 0; e < KNB; ++e) cmp[e] = d2 < bd[e];
#pragma unroll
            for (int e = KNB-1; e >= 1; --e) {
                bd[e] = cmp[e-1] ? bd[e-1] : (cmp[e] ? d2 : bd[e]);
                bi[e] = cmp[e-1] ? bi[e-1] : (cmp[e] ? idx : bi[e]);
            }
            bd[0] = cmp[0] ? d2 : bd[0];
            bi[0] = cmp[0] ? idx : bi[0];
        }
    }
    const int gb = n & ~(NPG-1);                    // graph base (NPG=512)
#pragma unroll
    for (int e = 0; e < KNB; ++e) nbr[n*KNB + e] = gb + bi[e];
}

// ---------------------------------------------------------------- layer1: u1,v1 [N,32]
__global__ __launch_bounds__(256) void a1_kernel(
    const float* __restrict__ x, const float* __restrict__ Wpre1, const float* __restrict__ bpre1,
    float* __restrict__ u1, float* __restrict__ v1)
{
    __shared__ float wS[512];
    __shared__ float bS[32];
    const int tid = threadIdx.x;
    wS[tid] = Wpre1[tid]; wS[tid+256] = Wpre1[tid+256];
    if (tid < 32) bS[tid] = bpre1[tid];
    __syncthreads();
    const int n  = blockIdx.x*8 + (tid>>5);
    const int tf = tid & 31;
    const int t = tf >> 3, f = tf & 7;
    float u = bS[tf], v = 0.f;
#pragma unroll
    for (int e = 0; e < 8; ++e) {
        float xv = x[n*8+e];
        u += xv * wS[(t*16 + e)*8 + f];
        v += xv * wS[(t*16 + 8 + e)*8 + f];
    }
    u1[n*32+tf] = u;
    v1[n*32+tf] = v;
}

// ---------------------------------------------------------------- layer1 fused (MFMA f16): agg + post + lin -> y1 [N,64]
__global__ __launch_bounds__(256) void b1_kernel(
    const float* __restrict__ x, const int* __restrict__ nbr,
    const float* __restrict__ u1, const float* __restrict__ v1,
    const unsigned short* __restrict__ Wf1p, const unsigned short* __restrict__ Wf1l,
    const float* __restrict__ blin1_eff,
    float* __restrict__ y1)
{
    __shared__ int nbrsS[112];
    __shared__ __align__(16) unsigned short actS[64*72];
    __shared__ __align__(16) unsigned short postS[16*72];
    const int tid  = threadIdx.x;
    const int base = blockIdx.x * 16;
    if (tid < 112) nbrsS[tid] = nbr[base*7 + tid];
    for (int i = tid; i < 384; i += 256) {
        int r = i / 6, gq = i - 6*r;
        *(ushort4*)&actS[r*72 + 40 + gq*4] = make_ushort4(0,0,0,0);
    }
#pragma unroll
    for (int it = 0; it < 2; ++it) {
        int i = tid + it*256;
        int n = i >> 5, r2 = i & 31, t = r2 >> 3, f = r2 & 7;
        actS[(n*4 + t)*72 + f] = f2h(x[(base+n)*8 + f]);
    }
    __syncthreads();   // nbrsS visible to all threads
    {
        const int n = tid >> 4, cp = tid & 15;
        const int tf0 = cp*2, t = tf0 >> 3, f0 = tf0 & 7;
        float2 uu = *(const float2*)&u1[(base+n)*32 + tf0];
        float s0=0.f,s1=0.f,q0=0.f,q1=0.f;
        float mn0=3e38f,mn1=3e38f,mx0=-3e38f,mx1=-3e38f;
#pragma unroll
        for (int e = 0; e < 7; ++e) {
            float2 vv = *(const float2*)&v1[nbrsS[n*7+e]*32 + tf0];
            s0 += vv.x; q0 += vv.x*vv.x; mn0 = fminf(mn0, vv.x); mx0 = fmaxf(mx0, vv.x);
            s1 += vv.y; q1 += vv.y*vv.y; mn1 = fminf(mn1, vv.y); mx1 = fmaxf(mx1, vv.y);
        }
        float me0 = s0*(1.f/7.f), me1 = s1*(1.f/7.f);
        float sd0 = sqrtf(fmaxf(q0*(1.f/7.f) - me0*me0, 0.f) + 1e-5f);
        float sd1 = sqrtf(fmaxf(q1*(1.f/7.f) - me1*me1, 0.f) + 1e-5f);
        const int row = (n*4 + t)*72;
        ushort2 w_;
        w_.x = f2h(uu.x + me0); w_.y = f2h(uu.y + me1); *(ushort2*)&actS[row +  8 + f0] = w_;
        w_.x = f2h(uu.x + mn0); w_.y = f2h(uu.y + mn1); *(ushort2*)&actS[row + 16 + f0] = w_;
        w_.x = f2h(uu.x + mx0); w_.y = f2h(uu.y + mx1); *(ushort2*)&actS[row + 24 + f0] = w_;
        w_.x = f2h(sd0);        w_.y = f2h(sd1);        *(ushort2*)&actS[row + 32 + f0] = w_;
    }
    __syncthreads();
    const int l = tid & 63, w = tid >> 6;
    const int lr = l & 15, lk = l >> 4;
    f32x4 acc = {0.f,0.f,0.f,0.f};
    {
        const f16x8* WB = (const f16x8*)Wf1p;
#pragma unroll
        for (int kk = 0; kk < 2; ++kk) {
            f16x8 a = *(const f16x8*)&actS[(lr*4 + w)*72 + kk*32 + lk*8];
            f16x8 b = WB[(w*2 + kk)*64 + l];
            acc = __builtin_amdgcn_mfma_f32_16x16x32_f16(a, b, acc, 0, 0, 0);
        }
    }
#pragma unroll
    for (int j = 0; j < 4; ++j)
        postS[(lk*4 + j)*72 + w*16 + lr] = f2h(acc[j]);
    __syncthreads();
    f32x4 d = {0.f,0.f,0.f,0.f};
    {
        const f16x8* WB = (const f16x8*)Wf1l;
#pragma unroll
        for (int kk = 0; kk < 2; ++kk) {
            f16x8 a = *(const f16x8*)&postS[lr*72 + kk*32 + lk*8];
            f16x8 b = WB[(kk*4 + w)*64 + l];
            d = __builtin_amdgcn_mfma_f32_16x16x32_f16(a, b, d, 0, 0, 0);
        }
    }
    const float be = blin1_eff[w*16 + lr];
#pragma unroll
    for (int j = 0; j < 4; ++j)
        y1[(base + lk*4 + j)*64 + w*16 + lr] = d[j] + be;
}

// ---------------------------------------------------------------- BN stats: 1024 blocks, float4, LDS tree -> partials
template<int C>
__global__ __launch_bounds__(256) void bn_stats_kernel(
    const float* __restrict__ y, float* __restrict__ Ps, float* __restrict__ Pq)
{
    constexpr int IT     = (NN/1024)*(C/4)/256;
    constexpr int GROUPS = C/4;
    constexpr int REPS   = 256/GROUPS;
    const int tid = threadIdx.x;
    const float4* y4 = (const float4*)y + (size_t)blockIdx.x*256*IT;
    float4 s = make_float4(0.f,0.f,0.f,0.f), q = make_float4(0.f,0.f,0.f,0.f);
#pragma unroll
    for (int it = 0; it < IT; ++it) {
        float4 v = y4[it*256 + tid];
        s.x += v.x; s.y += v.y; s.z += v.z; s.w += v.w;
        q.x += v.x*v.x; q.y += v.y*v.y; q.z += v.z*v.z; q.w += v.w*v.w;
    }
    __shared__ float4 sS[256], qS[256];
    sS[tid] = s; qS[tid] = q;
    __syncthreads();
#pragma unroll
    for (int step = REPS/2; step >= 1; step >>= 1) {
        if (tid < step*GROUPS) {
            float4 s2 = sS[tid + step*GROUPS], q2 = qS[tid + step*GROUPS];
            float4 ss = sS[tid], qq = qS[tid];
            ss.x += s2.x; ss.y += s2.y; ss.z += s2.z; ss.w += s2.w;
            qq.x += q2.x; qq.y += q2.y; qq.z += q2.z; qq.w += q2.w;
            sS[tid] = ss; qS[tid] = qq;
        }
        __syncthreads();
    }
    if (tid < GROUPS) {
        ((float4*)&Ps[(size_t)blockIdx.x*C])[tid] = sS[tid];
        ((float4*)&Pq[(size_t)blockIdx.x*C])[tid] = qS[tid];
    }
}

// ---------------------------------------------------------------- finA: 64 blocks, sum 16 partial-rows
template<int C>
__global__ __launch_bounds__(C) void finA_kernel(
    const float* __restrict__ Ps, const float* __restrict__ Pq,
    float* __restrict__ As, float* __restrict__ Aq)
{
    const int c = threadIdx.x, b = blockIdx.x;
    float s = 0.f, q = 0.f;
#pragma unroll
    for (int i = 0; i < 16; ++i) {
        s += Ps[(b*16 + i)*C + c];
        q += Pq[(b*16 + i)*C + c];
    }
    As[b*C + c] = s;
    Aq[b*C + c] = q;
}

// ---------------------------------------------------------------- finalize BN -> scale/shift (sums 64)
template<int C>
__global__ __launch_bounds__(C) void fin_kernel(
    const float* __restrict__ As, const float* __restrict__ Aq,
    const float* __restrict__ g, const float* __restrict__ b,
    float* __restrict__ scO, float* __restrict__ shO)
{
    const int c = threadIdx.x;
    float s = 0.f, q = 0.f;
#pragma unroll 8
    for (int i = 0; i < 64; ++i) { s += As[i*C + c]; q += Aq[i*C + c]; }
    const float inv = 1.f/(float)NN;
    float mu  = s*inv;
    float var = q*inv - mu*mu;
    float sc  = g[c]*rsqrtf(var + 1e-5f);
    scO[c] = sc;
    shO[c] = b[c] - mu*sc;
}

// ---------------------------------------------------------------- layer2 pre (MFMA f16): uv2 [N][512] f16 = [u||v]
__global__ __launch_bounds__(256) void a2_kernel(
    const float* __restrict__ y1raw, const float* __restrict__ sc1, const float* __restrict__ sh1,
    const unsigned short* __restrict__ Wfuv, const float* __restrict__ bpre2,
    unsigned short* __restrict__ uv2)
{
    __shared__ __align__(16) unsigned short a1S[64*72];
    __shared__ float biasS[256];
    const int tid  = threadIdx.x;
    const int base = blockIdx.x * 64;
    biasS[tid] = bpre2[tid];
#pragma unroll
    for (int it = 0; it < 4; ++it) {
        int i = tid + it*256;
        float4 vv = ((const float4*)y1raw)[blockIdx.x*1024 + i];
        int n = i >> 4, c0 = (i & 15)*4;
        float c_[4] = {vv.x, vv.y, vv.z, vv.w};
#pragma unroll
        for (int j = 0; j < 4; ++j) {
            int c = c0 + j;
            a1S[n*72 + c] = f2h(fmaxf(c_[j]*sc1[c] + sh1[c], 0.f));
        }
    }
    __syncthreads();
    const int l = tid & 63, w = tid >> 6;
    const int lr = l & 15, lk = l >> 4;
    const f16x8 a0  = *(const f16x8*)&a1S[(w*16 + lr)*72 +      lk*8];
    const f16x8 a1f = *(const f16x8*)&a1S[(w*16 + lr)*72 + 32 + lk*8];
    const f16x8* WB = (const f16x8*)Wfuv;
#pragma unroll 4
    for (int ct = 0; ct < 32; ++ct) {
        f32x4 acc = {0.f,0.f,0.f,0.f};
        f16x8 b0 = WB[ct*64 + l];
        f16x8 b1 = WB[(32 + ct)*64 + l];
        acc = __builtin_amdgcn_mfma_f32_16x16x32_f16(a0,  b0, acc, 0, 0, 0);
        acc = __builtin_amdgcn_mfma_f32_16x16x32_f16(a1f, b1, acc, 0, 0, 0);
        const int col = ct*16 + lr;
        const float bias = (ct < 16) ? biasS[col] : 0.f;
#pragma unroll
        for (int j = 0; j < 4; ++j)
            uv2[(base + w*16 + lk*4 + j)*512 + col] = f2h(acc[j] + bias);
    }
}

// ---------------------------------------------------------------- layer2 fused (MFMA f16): agg + post + lin -> y2 [N,128]
__global__ __launch_bounds__(256) void b2_kernel(
    const int* __restrict__ nbr, const float* __restrict__ y1raw,
    const float* __restrict__ sc1, const float* __restrict__ sh1,
    const unsigned short* __restrict__ uv2,
    const unsigned short* __restrict__ Wfp, const unsigned short* __restrict__ Wfl,
    const float* __restrict__ blin_eff,
    float* __restrict__ y2)
{
    __shared__ int nbrsS[112];
    __shared__ __align__(16) unsigned short a1S[16*72];
    __shared__ __align__(16) unsigned short aggS[64*264];
    __shared__ __align__(16) unsigned short postS[16*136];

    const int tid = threadIdx.x;
    const int ob   = blockIdx.x;
    const int xcd  = ob & 7, slot = ob >> 3;
    const int gph  = ((slot >> 5) << 3) + xcd;
    const int sub  = slot & 31;
    const int base = gph*NPG + sub*16;

    if (tid < 112) nbrsS[tid] = nbr[base*7 + tid];
    for (int i = tid; i < 1024; i += 256) {
        int c = i & 63, n = i >> 6;
        float a = fmaxf(y1raw[base*64 + i]*sc1[c] + sh1[c], 0.f);
        a1S[n*72 + c] = f2h(a);
    }
    __syncthreads();
    {
        const int ns = tid >> 6, cg = tid & 63;
        const int t = cg >> 4, f0 = (cg & 15) * 4;
        const h2 inv7 = { (_Float16)(1.f/7.f), (_Float16)(1.f/7.f) };
#pragma unroll
        for (int it = 0; it < 4; ++it) {
            const int ln = it*4 + ns;
            uint2 uu = *(const uint2*)&uv2[(size_t)(base+ln)*512 + cg*4];
            h2 u01 = __builtin_bit_cast(h2, uu.x);
            h2 u23 = __builtin_bit_cast(h2, uu.y);
            h2 z = { (_Float16)0.f, (_Float16)0.f };
            h2 s01 = z, s23 = z, q01 = z, q23 = z;
            h2 mn01 = { (_Float16)65504.f, (_Float16)65504.f }, mn23 = mn01;
            h2 mx01 = { (_Float16)-65504.f, (_Float16)-65504.f }, mx23 = mx01;
#pragma unroll
            for (int e = 0; e < 7; ++e) {
                uint2 vv = *(const uint2*)&uv2[(size_t)nbrsS[ln*7+e]*512 + 256 + cg*4];
                h2 v01 = __builtin_bit_cast(h2, vv.x);
                h2 v23 = __builtin_bit_cast(h2, vv.y);
                s01 += v01; s23 += v23;
                q01 += v01*v01; q23 += v23*v23;
                mn01 = __builtin_elementwise_min(mn01, v01);
                mn23 = __builtin_elementwise_min(mn23, v23);
                mx01 = __builtin_elementwise_max(mx01, v01);
                mx23 = __builtin_elementwise_max(mx23, v23);
            }
            h2 me01 = s01*inv7, me23 = s23*inv7;
            h2 om01 = u01 + me01, om23 = u23 + me23;
            h2 on01 = u01 + mn01, on23 = u23 + mn23;
            h2 ox01 = u01 + mx01, ox23 = u23 + mx23;
            float m0 = (float)me01[0], m1 = (float)me01[1];
            float m2 = (float)me23[0], m3 = (float)me23[1];
            float sd0 = sqrtf(fmaxf(fmaf((float)q01[0], 1.f/7.f, -m0*m0), 0.f) + 1e-5f);
            float sd1 = sqrtf(fmaxf(fmaf((float)q01[1], 1.f/7.f, -m1*m1), 0.f) + 1e-5f);
            float sd2 = sqrtf(fmaxf(fmaf((float)q23[0], 1.f/7.f, -m2*m2), 0.f) + 1e-5f);
            float sd3 = sqrtf(fmaxf(fmaf((float)q23[1], 1.f/7.f, -m3*m3), 0.f) + 1e-5f);
            h2 sd01 = { (_Float16)sd0, (_Float16)sd1 };
            h2 sd23 = { (_Float16)sd2, (_Float16)sd3 };
            const int ro = (t*16 + ln)*264 + f0;
            *(uint2*)&aggS[ro      ] = make_uint2(__builtin_bit_cast(unsigned, om01), __builtin_bit_cast(unsigned, om23));
            *(uint2*)&aggS[ro +  64] = make_uint2(__builtin_bit_cast(unsigned, on01), __builtin_bit_cast(unsigned, on23));
            *(uint2*)&aggS[ro + 128] = make_uint2(__builtin_bit_cast(unsigned, ox01), __builtin_bit_cast(unsigned, ox23));
            *(uint2*)&aggS[ro + 192] = make_uint2(__builtin_bit_cast(unsigned, sd01), __builtin_bit_cast(unsigned, sd23));
        }
    }
    __syncthreads();
    const int l = tid & 63, w = tid >> 6;
    const int lr = l & 15, lk = l >> 4;
    f32x4 acc0 = {0.f,0.f,0.f,0.f}, acc1 = {0.f,0.f,0.f,0.f};
    {
        const f16x8* WB = (const f16x8*)Wfp;
#pragma unroll
        for (int kk = 0; kk < 10; ++kk) {
            f16x8 a;
            if (kk < 2) a = *(const f16x8*)&a1S[lr*72 + kk*32 + lk*8];
            else        a = *(const f16x8*)&aggS[(w*16 + lr)*264 + (kk-2)*32 + lk*8];
            f16x8 b0 = WB[((w*10 + kk)*2 + 0)*64 + l];
            f16x8 b1 = WB[((w*10 + kk)*2 + 1)*64 + l];
            acc0 = __builtin_amdgcn_mfma_f32_16x16x32_f16(a, b0, acc0, 0, 0, 0);
            acc1 = __builtin_amdgcn_mfma_f32_16x16x32_f16(a, b1, acc1, 0, 0, 0);
        }
    }
#pragma unroll
    for (int j = 0; j < 4; ++j) {
        const int row = lk*4 + j;
        postS[row*136 + w*32 +      lr] = f2h(acc0[j]);
        postS[row*136 + w*32 + 16 + lr] = f2h(acc1[j]);
    }
    __syncthreads();
    f32x4 d0 = {0.f,0.f,0.f,0.f}, d1 = {0.f,0.f,0.f,0.f};
    {
        const f16x8* WB = (const f16x8*)Wfl;
#pragma unroll
        for (int kk = 0; kk < 4; ++kk) {
            f16x8 a = *(const f16x8*)&postS[lr*136 + kk*32 + lk*8];
            f16x8 b0 = WB[(kk*8 + 2*w + 0)*64 + l];
            f16x8 b1 = WB[(kk*8 + 2*w + 1)*64 + l];
            d0 = __builtin_amdgcn_mfma_f32_16x16x32_f16(a, b0, d0, 0, 0, 0);
            d1 = __builtin_amdgcn_mfma_f32_16x16x32_f16(a, b1, d1, 0, 0, 0);
        }
    }
    const float be0 = blin_eff[w*32 +      lr];
    const float be1 = blin_eff[w*32 + 16 + lr];
#pragma unroll
    for (int j = 0; j < 4; ++j) {
        const int row = lk*4 + j;
        y2[(base + row)*128 + w*32 +      lr] = d0[j] + be0;
        y2[(base + row)*128 + w*32 + 16 + lr] = d1[j] + be1;
    }
}

// ---------------------------------------------------------------- pool part: BN2+relu+64-row partial sums (1024 blocks)
__global__ __launch_bounds__(128) void pool_part_kernel(
    const float* __restrict__ y2, const float* __restrict__ sc2, const float* __restrict__ sh2,
    float* __restrict__ Pp)
{
    const int c = threadIdx.x;
    const int b = blockIdx.x;
    const float sc = sc2[c];
    const float sh = sh2[c];
    float acc = 0.f;
    const size_t base = (size_t)b*64*128 + c;
#pragma unroll 4
    for (int i = 0; i < 64; ++i)
        acc += fmaxf(y2[base + (size_t)i*128]*sc + sh, 0.f);
    Pp[b*128 + c] = acc;
}

// ---------------------------------------------------------------- pool finalize: sum 8 chunks -> out [128,128]
__global__ __launch_bounds__(128) void pool_fin_kernel(
    const float* __restrict__ Pp, float* __restrict__ out)
{
    const int c = threadIdx.x, g = blockIdx.x;
    float acc = 0.f;
#pragma unroll
    for (int i = 0; i < 8; ++i) acc += Pp[(g*8 + i)*128 + c];
    out[g*128 + c] = acc * (1.f/(float)NPG);
}

// ---------------------------------------------------------------- launcher
extern "C" void kernel_launch(void* const* d_in, const int* in_sizes, int n_in,
                              void* d_out, int out_size, void* d_ws, size_t ws_size,
                              hipStream_t stream)
{
    const float* x      = (const float*)d_in[0];
    const float* pos    = (const float*)d_in[1];
    const float* Wpre1  = (const float*)d_in[2];
    const float* bpre1  = (const float*)d_in[3];
    const float* Wpost1 = (const float*)d_in[4];
    const float* bpost1 = (const float*)d_in[5];
    const float* Wlin1  = (const float*)d_in[6];
    const float* blin1  = (const float*)d_in[7];
    const float* bn1g   = (const float*)d_in[8];
    const float* bn1b   = (const float*)d_in[9];
    const float* Wpre2  = (const float*)d_in[10];
    const float* bpre2  = (const float*)d_in[11];
    const float* Wpost2 = (const float*)d_in[12];
    const float* bpost2 = (const float*)d_in[13];
    const float* Wlin2  = (const float*)d_in[14];
    const float* blin2  = (const float*)d_in[15];
    const float* bn2g   = (const float*)d_in[16];
    const float* bn2b   = (const float*)d_in[17];
    float* out = (float*)d_out;

    char* ws = (char*)d_ws;
    size_t off = 0;
    auto alloc = [&](size_t bytes) { void* p = ws + off; off += (bytes + 255) & ~(size_t)255; return p; };
    int*    nbr  = (int*)   alloc((size_t)NN*7*4);
    float2* part = (float2*)alloc((size_t)NN*28*8);           // 14.7 MB kNN partials
    float* u1    = (float*)alloc((size_t)NN*32*4);
    float* v1    = (float*)alloc((size_t)NN*32*4);
    float* y1    = (float*)alloc((size_t)NN*64*4);            // raw (pre-BN)
    unsigned short* uv2 = (unsigned short*)alloc((size_t)NN*512*2);   // f16 [u||v]
    float* y2    = (float*)alloc((size_t)NN*128*4);           // raw (pre-BN)
    unsigned short* Wf1p = (unsigned short*)alloc(4096*2);
    unsigned short* Wf1l = (unsigned short*)alloc(4096*2);
    float* blin1_eff = (float*)alloc(64*4);
    unsigned short* Wfuv = (unsigned short*)alloc(32768*2);
    unsigned short* Wfp  = (unsigned short*)alloc(40960*2);
    unsigned short* Wfl  = (unsigned short*)alloc(16384*2);
    float* blin_eff = (float*)alloc(128*4);
    float* P1s   = (float*)alloc(1024*64*4);
    float* P1q   = (float*)alloc(1024*64*4);
    float* A1s   = (float*)alloc(64*64*4);
    float* A1q   = (float*)alloc(64*64*4);
    float* sc1   = (float*)alloc(64*4);
    float* sh1   = (float*)alloc(64*4);
    float* P2s   = (float*)alloc(1024*128*4);
    float* P2q   = (float*)alloc(1024*128*4);
    float* A2s   = (float*)alloc(64*128*4);
    float* A2q   = (float*)alloc(64*128*4);
    float* sc2   = (float*)alloc(128*4);
    float* sh2   = (float*)alloc(128*4);
    float* Pp    = (float*)alloc(1024*128*4);

    prep_kernel<<<128, 256, 0, stream>>>(Wpost1, Wpost2, Wpre2, Wlin2, Wlin1, bpost1, blin1,
                                         bpost2, blin2,
                                         Wf1p, Wf1l, blin1_eff, Wfuv, Wfp, Wfl, blin_eff);
    knn_part_kernel<<<NGRAPH*8, 256, 0, stream>>>(pos, part);
    knn_merge_kernel<<<NN/256, 256, 0, stream>>>(part, nbr);
    a1_kernel<<<NN/8, 256, 0, stream>>>(x, Wpre1, bpre1, u1, v1);
    b1_kernel<<<NN/16, 256, 0, stream>>>(x, nbr, u1, v1, Wf1p, Wf1l, blin1_eff, y1);
    bn_stats_kernel<64><<<1024, 256, 0, stream>>>(y1, P1s, P1q);
    finA_kernel<64><<<64, 64, 0, stream>>>(P1s, P1q, A1s, A1q);
    fin_kernel<64><<<1, 64, 0, stream>>>(A1s, A1q, bn1g, bn1b, sc1, sh1);
    a2_kernel<<<NN/64, 256, 0, stream>>>(y1, sc1, sh1, Wfuv, bpre2, uv2);
    b2_kernel<<<NN/16, 256, 0, stream>>>(nbr, y1, sc1, sh1, uv2, Wfp, Wfl, blin_eff, y2);
    bn_stats_kernel<128><<<1024, 256, 0, stream>>>(y2, P2s, P2q);
    finA_kernel<128><<<64, 128, 0, stream>>>(P2s, P2q, A2s, A2q);
    fin_kernel<128><<<1, 128, 0, stream>>>(A2s, A2q, bn2g, bn2b, sc2, sh2);
    pool_part_kernel<<<1024, 128, 0, stream>>>(y2, sc2, sh2, Pp);
    pool_fin_kernel<<<NGRAPH, 128, 0, stream>>>(Pp, out);
}